// Round 4
// baseline (1201.244 us; speedup 1.0000x reference)
//
#include <hip/hip_runtime.h>
#include <hip/hip_bf16.h>
#include <math.h>

#define D16   16
#define NC    64      // channels C
#define NH    8       // heads
#define CHD   128     // (C/H)*D = 8*16
#define NLAY  2
#define CEXP  256     // C*FM
#define NK    8       // rotors
#define SEQ   1024
#define BATCH 2
#define VOCAB 32000

// ---- Cl(3,1) sign helpers (mirror the Python cayley construction) ----------
__device__ __forceinline__ float gp_sign(int a, int b) {
    int t = a >> 1, tot = 0;
    while (t) { tot += __popc(t & b); t >>= 1; }
    int neg = tot & 1;
    if ((a & b) & 8) neg ^= 1;   // METRIC[3] = -1 (e4^2 = -1)
    return neg ? -1.f : 1.f;
}
__device__ __forceinline__ float rev_sign(int j) {
    int g = __popc(j);
    return ((g * (g - 1) / 2) & 1) ? -1.f : 1.f;
}

// ---- embed gather + rotary bivector PE (sandwich R x R~) -------------------
__global__ void embed_pe_kernel(const int* __restrict__ tok,
                                const float* __restrict__ embed,
                                float* __restrict__ x) {
    int idx = blockIdx.x * blockDim.x + threadIdx.x;      // (b*L+l)*C + c
    if (idx >= BATCH * SEQ * NC) return;
    int c  = idx & (NC - 1);
    int bl = idx / NC;
    int l  = bl & (SEQ - 1);
    int t  = tok[bl];

    const float* e = embed + ((size_t)t * NC + c) * D16;
    float v[D16];
#pragma unroll
    for (int j = 0; j < D16; j++) v[j] = e[j];

    float freq = powf(10000.f, -(float)c / (float)NC);
    float theta = (float)l * freq;
    float sn, cs;
    sincosf(theta, &sn, &cs);

    float tmp[D16], out[D16];
#pragma unroll
    for (int k = 0; k < D16; k++)
        tmp[k] = cs * v[k] + sn * gp_sign(3, 3 ^ k) * v[3 ^ k];
#pragma unroll
    for (int k = 0; k < D16; k++)
        out[k] = cs * tmp[k] - sn * gp_sign(k ^ 3, 3) * tmp[k ^ 3];

    float* xp = x + (size_t)idx * D16;
#pragma unroll
    for (int j = 0; j < D16; j++) xp[j] = out[j];
}

// ---- fused CLN + q/k/v projection per (b,l) --------------------------------
__global__ void qkv_cln_kernel(const float* __restrict__ x,
                               const float* __restrict__ g,
                               const float* __restrict__ wq,
                               const float* __restrict__ wk,
                               const float* __restrict__ wv,
                               float* __restrict__ q, float* __restrict__ k,
                               float* __restrict__ v) {
    int bl = blockIdx.x;
    __shared__ float xs[NC * D16];
    __shared__ float red[256];
    float s = 0.f;
    for (int i = threadIdx.x; i < NC * D16; i += 256) {
        float vv = x[(size_t)bl * 1024 + i];
        xs[i] = vv; s += vv * vv;
    }
    red[threadIdx.x] = s; __syncthreads();
    for (int st = 128; st > 0; st >>= 1) {
        if (threadIdx.x < st) red[threadIdx.x] += red[threadIdx.x + st];
        __syncthreads();
    }
    float inv = 1.f / sqrtf(red[0] * (1.f / 1024.f) + 1e-6f);
    for (int i = threadIdx.x; i < NC * D16; i += 256) xs[i] *= inv * g[i >> 4];
    __syncthreads();

    int d  = threadIdx.x & 15;
    int og = threadIdx.x >> 4;
    const float* Ws[3] = { wq, wk, wv };
    float* Os[3] = { q, k, v };
#pragma unroll
    for (int m = 0; m < 3; m++) {
        const float* W = Ws[m];
        float* O = Os[m];
#pragma unroll
        for (int oo = 0; oo < 4; oo++) {
            int o = og * 4 + oo;
            float acc = 0.f;
#pragma unroll
            for (int c = 0; c < NC; c++) acc += W[o * NC + c] * xs[c * D16 + d];
            O[(size_t)bl * 1024 + o * D16 + d] = acc;
        }
    }
}

// ---- flash attention: Q-tile 32, K/V-tile 64, paired causal tasks ----------
__global__ __launch_bounds__(256) void flash_attn_kernel(
        const float* __restrict__ q, const float* __restrict__ k,
        const float* __restrict__ v, float* __restrict__ o) {
    int slot = blockIdx.x;
    int bh = blockIdx.y;
    int b = bh >> 3, h = bh & 7;
    int t = threadIdx.x;
    int rg = t >> 4, cg = t & 15;
    int jv_s = t & 31;                 // staging chunk col (fixed per thread)

    __shared__ float4 qs4[32 * 32];    // [row][chunk]  (plain)
    __shared__ float4 kv4[64 * 32];    // K swizzled / V plain (reused)
    __shared__ float4 ps4[32 * 17];    // P, row stride 17 float4

    const float scale = 0.088388347648318447f;  // 1/sqrt(128)

    float4 gm;
    {
        int d0 = (jv_s * 4) & 15;
        gm.x = gp_sign(d0, d0) * scale;
        gm.y = gp_sign(d0 + 1, d0 + 1) * scale;
        gm.z = gp_sign(d0 + 2, d0 + 2) * scale;
        gm.w = gp_sign(d0 + 3, d0 + 3) * scale;
    }

    for (int task = 0; task < 2; task++) {
        int qi = (task == 0) ? slot : (31 - slot);
        int T = (qi >> 1) + 1;

        __syncthreads();
        {
            const float* qb = q + (size_t)(b * SEQ + qi * 32) * 1024 + h * CHD;
#pragma unroll
            for (int it = 0; it < 4; it++) {
                int row = it * 8 + (t >> 5);
                float4 val = *(const float4*)(qb + (size_t)row * 1024 + jv_s * 4);
                float4 sv; sv.x = val.x * gm.x; sv.y = val.y * gm.y;
                sv.z = val.z * gm.z; sv.w = val.w * gm.w;
                qs4[row * 32 + jv_s] = sv;
            }
        }

        float m_run[2] = { -1e30f, -1e30f };
        float l_run[2] = { 0.f, 0.f };
        float oa[2][2][4];
#pragma unroll
        for (int a = 0; a < 2; a++)
#pragma unroll
            for (int bb = 0; bb < 2; bb++)
#pragma unroll
                for (int e = 0; e < 4; e++) oa[a][bb][e] = 0.f;

        for (int kt = 0; kt < T; kt++) {
            __syncthreads();
            {
                const float* kb = k + (size_t)(b * SEQ + kt * 64) * 1024 + h * CHD;
#pragma unroll
                for (int it = 0; it < 8; it++) {
                    int row = it * 8 + (t >> 5);
                    float4 val = *(const float4*)(kb + (size_t)row * 1024 + jv_s * 4);
                    kv4[row * 32 + (jv_s ^ ((row >> 2) & 7))] = val;
                }
            }
            __syncthreads();

            float acc[2][4];
#pragma unroll
            for (int ri = 0; ri < 2; ri++)
#pragma unroll
                for (int ci = 0; ci < 4; ci++) acc[ri][ci] = 0.f;
            int swz = cg & 7;
#pragma unroll 4
            for (int jv = 0; jv < 32; jv++) {
                float4 q0 = qs4[(rg * 2) * 32 + jv];
                float4 q1 = qs4[(rg * 2 + 1) * 32 + jv];
#pragma unroll
                for (int ci = 0; ci < 4; ci++) {
                    float4 kk = kv4[(cg * 4 + ci) * 32 + (jv ^ swz)];
                    acc[0][ci] += q0.x * kk.x + q0.y * kk.y + q0.z * kk.z + q0.w * kk.w;
                    acc[1][ci] += q1.x * kk.x + q1.y * kk.y + q1.z * kk.z + q1.w * kk.w;
                }
            }

            if (kt == T - 1) {
                int mb = kt * 64 + cg * 4;
                int rb = qi * 32 + rg * 2;
#pragma unroll
                for (int ri = 0; ri < 2; ri++)
#pragma unroll
                    for (int ci = 0; ci < 4; ci++)
                        if (mb + ci > rb + ri) acc[ri][ci] = -1e30f;
            }

#pragma unroll
            for (int ri = 0; ri < 2; ri++) {
                float tm = fmaxf(fmaxf(acc[ri][0], acc[ri][1]),
                                 fmaxf(acc[ri][2], acc[ri][3]));
                tm = fmaxf(tm, __shfl_xor(tm, 1, 16));
                tm = fmaxf(tm, __shfl_xor(tm, 2, 16));
                tm = fmaxf(tm, __shfl_xor(tm, 4, 16));
                tm = fmaxf(tm, __shfl_xor(tm, 8, 16));
                float mnew = fmaxf(m_run[ri], tm);
                float corr = __expf(m_run[ri] - mnew);
                float p0 = __expf(acc[ri][0] - mnew);
                float p1 = __expf(acc[ri][1] - mnew);
                float p2 = __expf(acc[ri][2] - mnew);
                float p3 = __expf(acc[ri][3] - mnew);
                float ts = p0 + p1 + p2 + p3;
                ts += __shfl_xor(ts, 1, 16);
                ts += __shfl_xor(ts, 2, 16);
                ts += __shfl_xor(ts, 4, 16);
                ts += __shfl_xor(ts, 8, 16);
                l_run[ri] = l_run[ri] * corr + ts;
                m_run[ri] = mnew;
#pragma unroll
                for (int bb = 0; bb < 2; bb++)
#pragma unroll
                    for (int e = 0; e < 4; e++) oa[ri][bb][e] *= corr;
                float4 pv; pv.x = p0; pv.y = p1; pv.z = p2; pv.w = p3;
                ps4[(rg * 2 + ri) * 17 + cg] = pv;
            }
            __syncthreads();

            {
                const float* vb = v + (size_t)(b * SEQ + kt * 64) * 1024 + h * CHD;
#pragma unroll
                for (int it = 0; it < 8; it++) {
                    int row = it * 8 + (t >> 5);
                    float4 val = *(const float4*)(vb + (size_t)row * 1024 + jv_s * 4);
                    kv4[row * 32 + jv_s] = val;
                }
            }
            __syncthreads();

#pragma unroll 2
            for (int mv = 0; mv < 16; mv++) {
                float4 p0 = ps4[(rg * 2) * 17 + mv];
                float4 p1 = ps4[(rg * 2 + 1) * 17 + mv];
                float pa[4] = { p0.x, p0.y, p0.z, p0.w };
                float pb[4] = { p1.x, p1.y, p1.z, p1.w };
#pragma unroll
                for (int e = 0; e < 4; e++) {
                    int m = mv * 4 + e;
                    float4 va = kv4[m * 32 + cg];
                    float4 vb4 = kv4[m * 32 + 16 + cg];
                    oa[0][0][0] += pa[e] * va.x;  oa[0][0][1] += pa[e] * va.y;
                    oa[0][0][2] += pa[e] * va.z;  oa[0][0][3] += pa[e] * va.w;
                    oa[0][1][0] += pa[e] * vb4.x; oa[0][1][1] += pa[e] * vb4.y;
                    oa[0][1][2] += pa[e] * vb4.z; oa[0][1][3] += pa[e] * vb4.w;
                    oa[1][0][0] += pb[e] * va.x;  oa[1][0][1] += pb[e] * va.y;
                    oa[1][0][2] += pb[e] * va.z;  oa[1][0][3] += pb[e] * va.w;
                    oa[1][1][0] += pb[e] * vb4.x; oa[1][1][1] += pb[e] * vb4.y;
                    oa[1][1][2] += pb[e] * vb4.z; oa[1][1][3] += pb[e] * vb4.w;
                }
            }
        }

#pragma unroll
        for (int ri = 0; ri < 2; ri++) {
            float inv = 1.f / l_run[ri];
            size_t row = (size_t)(b * SEQ + qi * 32 + rg * 2 + ri) * 1024 + h * CHD;
            float4 w0; w0.x = oa[ri][0][0] * inv; w0.y = oa[ri][0][1] * inv;
            w0.z = oa[ri][0][2] * inv; w0.w = oa[ri][0][3] * inv;
            float4 w1; w1.x = oa[ri][1][0] * inv; w1.y = oa[ri][1][1] * inv;
            w1.z = oa[ri][1][2] * inv; w1.w = oa[ri][1][3] * inv;
            *(float4*)(o + row + cg * 4)      = w0;
            *(float4*)(o + row + 64 + cg * 4) = w1;
        }
    }
}

// ---- wo projection + residual add ------------------------------------------
__global__ void proj_add_kernel(const float* __restrict__ in,
                                const float* __restrict__ W,
                                float* __restrict__ x) {
    int bl = blockIdx.x;
    __shared__ float xs[NC * D16];
    for (int i = threadIdx.x; i < NC * D16; i += 256) xs[i] = in[(size_t)bl * 1024 + i];
    __syncthreads();
    int d  = threadIdx.x & 15;
    int og = threadIdx.x >> 4;
#pragma unroll
    for (int oo = 0; oo < 4; oo++) {
        int o = og * 4 + oo;
        float acc = 0.f;
#pragma unroll
        for (int c = 0; c < NC; c++) acc += W[o * NC + c] * xs[c * D16 + d];
        x[(size_t)bl * 1024 + o * D16 + d] += acc;
    }
}

// ---- fused CLN + FFN up + rotor mix + gelu ---------------------------------
__global__ void ffn_up_gelu_kernel(const float* __restrict__ x,
                                   const float* __restrict__ g,
                                   const float* __restrict__ W,
                                   const float* __restrict__ Tmix,
                                   float* __restrict__ h) {
    int bl = blockIdx.x;
    __shared__ float xs[NC * D16];
    __shared__ float Ts[256];
    __shared__ float red[256];
    float s = 0.f;
    for (int i = threadIdx.x; i < NC * D16; i += 256) {
        float vv = x[(size_t)bl * 1024 + i];
        xs[i] = vv; s += vv * vv;
    }
    Ts[threadIdx.x] = Tmix[threadIdx.x];
    red[threadIdx.x] = s; __syncthreads();
    for (int st = 128; st > 0; st >>= 1) {
        if (threadIdx.x < st) red[threadIdx.x] += red[threadIdx.x + st];
        __syncthreads();
    }
    float inv = 1.f / sqrtf(red[0] * (1.f / 1024.f) + 1e-6f);
    for (int i = threadIdx.x; i < NC * D16; i += 256) xs[i] *= inv * g[i >> 4];
    __syncthreads();

    int e = threadIdx.x;
    float acc[D16];
#pragma unroll
    for (int dd = 0; dd < D16; dd++) acc[dd] = 0.f;
    for (int c = 0; c < NC; c++) {
        float w = W[e * NC + c];
#pragma unroll
        for (int dd = 0; dd < D16; dd++) acc[dd] += w * xs[c * D16 + dd];
    }
    float* hp = h + (size_t)bl * (CEXP * D16) + e * D16;
    const float kA = 0.7978845608028654f;
#pragma unroll
    for (int p = 0; p < D16; p++) {
        float s2 = 0.f;
#pragma unroll
        for (int j = 0; j < D16; j++) s2 += acc[j] * Ts[j * 16 + p];
        float gg = 0.5f * s2 * (1.f + tanhf(kA * (s2 + 0.044715f * s2 * s2 * s2)));
        hp[p] = gg;
    }
}

// ---- per-layer mixed rotor sandwich matrix Tmix[16][16] --------------------
__global__ void tmix_kernel(const float* __restrict__ rotor_biv,  // [NL,K,6]
                            const float* __restrict__ mixw,       // [NL,K]
                            float* __restrict__ Tmix) {           // [NL,16,16]
    int lay = blockIdx.x;
    __shared__ float rot[NK][D16];
    __shared__ float w[NK];
    int t = threadIdx.x;
    if (t < NK) {
        const int BIV[6] = { 3, 5, 6, 9, 10, 12 };
        float r[D16];
#pragma unroll
        for (int j = 0; j < D16; j++) r[j] = 0.f;
        r[0] = 1.f;
        float nrm = 1.f;
        for (int i = 0; i < 6; i++) {
            float bv = rotor_biv[(lay * NK + t) * 6 + i];
            r[BIV[i]] = bv; nrm += bv * bv;
        }
        nrm = sqrtf(nrm);
        for (int j = 0; j < D16; j++) rot[t][j] = r[j] / nrm;
    }
    if (t == 0) {
        float mx = -INFINITY;
        for (int kk = 0; kk < NK; kk++) mx = fmaxf(mx, mixw[lay * NK + kk]);
        float s = 0.f, e[NK];
        for (int kk = 0; kk < NK; kk++) { e[kk] = expf(mixw[lay * NK + kk] - mx); s += e[kk]; }
        for (int kk = 0; kk < NK; kk++) w[kk] = e[kk] / s;
    }
    __syncthreads();
    int j = t >> 4, p = t & 15;
    float acc = 0.f;
    for (int kk = 0; kk < NK; kk++) {
        float tk = 0.f;
        for (int i = 0; i < D16; i++) {
            int n = i ^ j ^ p;
            float rn = rot[kk][n] * rev_sign(n);          // rrev
            tk += rot[kk][i] * rn * gp_sign(i, j) * gp_sign(i ^ j, n);
        }
        acc += w[kk] * tk;
    }
    Tmix[lay * 256 + t] = acc;
}

// ---- FFN down + residual ---------------------------------------------------
__global__ void ffn_down_kernel(const float* __restrict__ h,
                                const float* __restrict__ W,   // [C][CE]
                                float* __restrict__ x) {
    int bl = blockIdx.x;
    __shared__ float hs[CEXP * D16];
    for (int i = threadIdx.x; i < CEXP * D16; i += 256) hs[i] = h[(size_t)bl * (CEXP * D16) + i];
    __syncthreads();
    int d = threadIdx.x & 15;
#pragma unroll
    for (int i = 0; i < 4; i++) {
        int c = (threadIdx.x >> 4) + i * 16;
        float acc = 0.f;
        for (int e = 0; e < CEXP; e++) acc += W[c * CEXP + e] * hs[e * D16 + d];
        x[(size_t)bl * 1024 + c * D16 + d] += acc;
    }
}

// ---- final norm + blade gate + grade-0 extract -----------------------------
__global__ void g0_kernel(const float* __restrict__ x,
                          const float* __restrict__ g,
                          const float* __restrict__ sel,
                          float* __restrict__ g0) {
    int bl = blockIdx.x;
    const float* xr = x + (size_t)bl * 1024;
    __shared__ float red[256];
    float s = 0.f;
    for (int i = threadIdx.x; i < 1024; i += 256) { float v = xr[i]; s += v * v; }
    red[threadIdx.x] = s; __syncthreads();
    for (int st = 128; st > 0; st >>= 1) {
        if (threadIdx.x < st) red[threadIdx.x] += red[threadIdx.x + st];
        __syncthreads();
    }
    float inv = 1.f / sqrtf(red[0] * (1.f / 1024.f) + 1e-6f);
    if (threadIdx.x < NC) {
        int c = threadIdx.x;
        float gate = 1.f / (1.f + expf(-sel[c * D16]));
        g0[(size_t)bl * NC + c] = xr[c * D16] * inv * g[c] * gate;
    }
}

// ---- head_w transpose ------------------------------------------------------
__global__ void transpose_hw(const float* __restrict__ hw, float* __restrict__ hwT) {
    int idx = blockIdx.x * blockDim.x + threadIdx.x;
    if (idx >= VOCAB * NC) return;
    int v = idx / NC, c = idx & (NC - 1);
    hwT[(size_t)c * VOCAB + v] = hw[idx];
}

// ---- head GEMM: per-thread column, weights in VGPRs ------------------------
// grid (125, 8): 256 vocab cols x 256 rows per block
__global__ __launch_bounds__(256) void head_kernel(
        const float* __restrict__ g0, const float* __restrict__ hwT,
        const float* __restrict__ hb, float* __restrict__ out) {
    int t = threadIdx.x;
    int v = blockIdx.x * 256 + t;
    int rbase = blockIdx.y * 256;

    float w[NC];
#pragma unroll
    for (int c = 0; c < NC; c++) w[c] = hwT[(size_t)c * VOCAB + v];
    float bb = hb[v];

    for (int r = 0; r < 256; r += 2) {
        const float4* g0r = (const float4*)(g0 + (size_t)(rbase + r) * NC);
        const float4* g1r = (const float4*)(g0 + (size_t)(rbase + r + 1) * NC);
        float a0 = 0.f, a1 = 0.f, a2 = 0.f, a3 = 0.f;
        float b0 = 0.f, b1 = 0.f, b2 = 0.f, b3 = 0.f;
#pragma unroll
        for (int c4 = 0; c4 < 16; c4 += 2) {
            float4 ga = g0r[c4], gb = g0r[c4 + 1];
            float4 ha = g1r[c4], hbv = g1r[c4 + 1];
            a0 += ga.x * w[c4 * 4 + 0]; a1 += ga.y * w[c4 * 4 + 1];
            a2 += ga.z * w[c4 * 4 + 2]; a3 += ga.w * w[c4 * 4 + 3];
            a0 += gb.x * w[c4 * 4 + 4]; a1 += gb.y * w[c4 * 4 + 5];
            a2 += gb.z * w[c4 * 4 + 6]; a3 += gb.w * w[c4 * 4 + 7];
            b0 += ha.x * w[c4 * 4 + 0]; b1 += ha.y * w[c4 * 4 + 1];
            b2 += ha.z * w[c4 * 4 + 2]; b3 += ha.w * w[c4 * 4 + 3];
            b0 += hbv.x * w[c4 * 4 + 4]; b1 += hbv.y * w[c4 * 4 + 5];
            b2 += hbv.z * w[c4 * 4 + 6]; b3 += hbv.w * w[c4 * 4 + 7];
        }
        out[(size_t)(rbase + r) * VOCAB + v]     = (a0 + a1) + (a2 + a3) + bb;
        out[(size_t)(rbase + r + 1) * VOCAB + v] = (b0 + b1) + (b2 + b3) + bb;
    }
}

extern "C" void kernel_launch(void* const* d_in, const int* in_sizes, int n_in,
                              void* d_out, int out_size, void* d_ws, size_t ws_size,
                              hipStream_t stream) {
    (void)in_sizes; (void)n_in; (void)out_size; (void)ws_size;
    const int*   tok      = (const int*)  d_in[0];
    const float* embed    = (const float*)d_in[1];
    const float* ln1_g    = (const float*)d_in[2];
    const float* ln2_g    = (const float*)d_in[3];
    const float* wq       = (const float*)d_in[4];
    const float* wk       = (const float*)d_in[5];
    const float* wv       = (const float*)d_in[6];
    const float* wo       = (const float*)d_in[7];
    const float* ffn_up   = (const float*)d_in[8];
    const float* ffn_down = (const float*)d_in[9];
    const float* rotor    = (const float*)d_in[10];
    const float* mixw     = (const float*)d_in[11];
    const float* out_ln_g = (const float*)d_in[12];
    const float* sel      = (const float*)d_in[13];
    const float* head_w   = (const float*)d_in[14];
    const float* head_b   = (const float*)d_in[15];
    float* out = (float*)d_out;

    float* ws  = (float*)d_ws;
    float* x    = ws;                 // 2,097,152
    float* q    = x    + 2097152;
    float* k    = q    + 2097152;
    float* v    = k    + 2097152;
    float* o    = v    + 2097152;
    float* h    = o    + 2097152;     // 8,388,608
    float* Tmx  = h    + 8388608;     // 512
    float* g0   = Tmx  + 512;         // 131,072
    float* hwT  = g0   + 131072;      // 2,048,000

    embed_pe_kernel<<<(BATCH * SEQ * NC + 255) / 256, 256, 0, stream>>>(tok, embed, x);
    tmix_kernel<<<NLAY, 256, 0, stream>>>(rotor, mixw, Tmx);
    transpose_hw<<<(VOCAB * NC + 255) / 256, 256, 0, stream>>>(head_w, hwT);

    for (int l = 0; l < NLAY; l++) {
        qkv_cln_kernel<<<BATCH * SEQ, 256, 0, stream>>>(x, ln1_g + l * NC,
                                                        wq + l * NC * NC, wk + l * NC * NC,
                                                        wv + l * NC * NC, q, k, v);
        dim3 ag(16, BATCH * NH);
        flash_attn_kernel<<<ag, 256, 0, stream>>>(q, k, v, o);
        proj_add_kernel<<<BATCH * SEQ, 256, 0, stream>>>(o, wo + l * NC * NC, x);
        ffn_up_gelu_kernel<<<BATCH * SEQ, 256, 0, stream>>>(x, ln2_g + l * NC,
                                                            ffn_up + l * CEXP * NC,
                                                            Tmx + l * 256, h);
        ffn_down_kernel<<<BATCH * SEQ, 256, 0, stream>>>(h, ffn_down + l * NC * CEXP, x);
    }

    g0_kernel<<<BATCH * SEQ, 256, 0, stream>>>(x, out_ln_g, sel, g0);
    dim3 hg(VOCAB / 256, (BATCH * SEQ) / 256);   // (125, 8) — 256 rows per block
    head_kernel<<<hg, 256, 0, stream>>>(g0, hwT, head_b, out);
}

// Round 6
// 908.578 us; speedup vs baseline: 1.3221x; 1.3221x over previous
//
#include <hip/hip_runtime.h>
#include <hip/hip_bf16.h>
#include <math.h>

#define D16   16
#define NC    64      // channels C
#define NH    8       // heads
#define CHD   128     // (C/H)*D = 8*16
#define NLAY  2
#define CEXP  256     // C*FM
#define NK    8       // rotors
#define SEQ   1024
#define BATCH 2
#define VOCAB 32000

// ---- Cl(3,1) sign helpers (mirror the Python cayley construction) ----------
__device__ __forceinline__ float gp_sign(int a, int b) {
    int t = a >> 1, tot = 0;
    while (t) { tot += __popc(t & b); t >>= 1; }
    int neg = tot & 1;
    if ((a & b) & 8) neg ^= 1;   // METRIC[3] = -1 (e4^2 = -1)
    return neg ? -1.f : 1.f;
}
__device__ __forceinline__ float rev_sign(int j) {
    int g = __popc(j);
    return ((g * (g - 1) / 2) & 1) ? -1.f : 1.f;
}

// ---- embed gather + rotary bivector PE (sandwich R x R~) -------------------
__global__ void embed_pe_kernel(const int* __restrict__ tok,
                                const float* __restrict__ embed,
                                float* __restrict__ x) {
    int idx = blockIdx.x * blockDim.x + threadIdx.x;      // (b*L+l)*C + c
    if (idx >= BATCH * SEQ * NC) return;
    int c  = idx & (NC - 1);
    int bl = idx / NC;
    int l  = bl & (SEQ - 1);
    int t  = tok[bl];

    const float* e = embed + ((size_t)t * NC + c) * D16;
    float v[D16];
#pragma unroll
    for (int j = 0; j < D16; j++) v[j] = e[j];

    float freq = exp2f(-(float)c * (13.287712379549449f / (float)NC));
    float theta = (float)l * freq;
    float sn, cs;
    __sincosf(theta, &sn, &cs);

    float tmp[D16], out[D16];
#pragma unroll
    for (int k = 0; k < D16; k++)
        tmp[k] = cs * v[k] + sn * gp_sign(3, 3 ^ k) * v[3 ^ k];
#pragma unroll
    for (int k = 0; k < D16; k++)
        out[k] = cs * tmp[k] - sn * gp_sign(k ^ 3, 3) * tmp[k ^ 3];

    float* xp = x + (size_t)idx * D16;
#pragma unroll
    for (int j = 0; j < D16; j++) xp[j] = out[j];
}

// ---- fused CLN + q/k/v projection; xsT transposed LDS, float4 reads --------
__global__ __launch_bounds__(256) void qkv_cln_kernel(
        const float* __restrict__ x, const float* __restrict__ g,
        const float* __restrict__ wq, const float* __restrict__ wk,
        const float* __restrict__ wv,
        float* __restrict__ q, float* __restrict__ k, float* __restrict__ v) {
    int bl = blockIdx.x;
    int t = threadIdx.x;
    __shared__ float xsT[16 * 68];     // [d][c] pad 68
    __shared__ float red[256];
    float s = 0.f;
#pragma unroll
    for (int it = 0; it < 4; it++) {
        int i = t + it * 256;
        float vv = x[(size_t)bl * 1024 + i];
        xsT[(i & 15) * 68 + (i >> 4)] = vv;
        s += vv * vv;
    }
    red[t] = s; __syncthreads();
    for (int st = 128; st > 0; st >>= 1) {
        if (t < st) red[t] += red[t + st];
        __syncthreads();
    }
    float inv = 1.f / sqrtf(red[0] * (1.f / 1024.f) + 1e-6f);
#pragma unroll
    for (int it = 0; it < 4; it++) {
        int i = t + it * 256;
        xsT[(i & 15) * 68 + (i >> 4)] *= inv * g[i >> 4];
    }
    __syncthreads();

    int d = t & 15, og = t >> 4;
    float4 xv[16];
#pragma unroll
    for (int c4 = 0; c4 < 16; c4++)
        xv[c4] = *(const float4*)&xsT[d * 68 + c4 * 4];

    const float* Ws[3] = { wq, wk, wv };
    float* Os[3] = { q, k, v };
#pragma unroll
    for (int m = 0; m < 3; m++) {
        const float* W = Ws[m];
        float* O = Os[m];
#pragma unroll
        for (int oo = 0; oo < 4; oo++) {
            int o = og * 4 + oo;
            float a0 = 0.f, a1 = 0.f, a2 = 0.f, a3 = 0.f;
#pragma unroll
            for (int c4 = 0; c4 < 16; c4++) {
                float4 w4 = *(const float4*)&W[o * NC + c4 * 4];
                a0 += xv[c4].x * w4.x; a1 += xv[c4].y * w4.y;
                a2 += xv[c4].z * w4.z; a3 += xv[c4].w * w4.w;
            }
            O[(size_t)bl * 1024 + o * 16 + d] = (a0 + a1) + (a2 + a3);
        }
    }
}

// ---- flash attention: Q-tile 32, K/V-tile 64, paired causal tasks ----------
__global__ __launch_bounds__(256) void flash_attn_kernel(
        const float* __restrict__ q, const float* __restrict__ k,
        const float* __restrict__ v, float* __restrict__ o) {
    int slot = blockIdx.x;
    int bh = blockIdx.y;
    int b = bh >> 3, h = bh & 7;
    int t = threadIdx.x;
    int rg = t >> 4, cg = t & 15;
    int jv_s = t & 31;

    __shared__ float4 qs4[32 * 32];
    __shared__ float4 kv4[64 * 32];
    __shared__ float4 ps4[32 * 17];

    const float scale = 0.088388347648318447f;  // 1/sqrt(128)

    float4 gm;
    {
        int d0 = (jv_s * 4) & 15;
        gm.x = gp_sign(d0, d0) * scale;
        gm.y = gp_sign(d0 + 1, d0 + 1) * scale;
        gm.z = gp_sign(d0 + 2, d0 + 2) * scale;
        gm.w = gp_sign(d0 + 3, d0 + 3) * scale;
    }

    for (int task = 0; task < 2; task++) {
        int qi = (task == 0) ? slot : (31 - slot);
        int T = (qi >> 1) + 1;

        __syncthreads();
        {
            const float* qb = q + (size_t)(b * SEQ + qi * 32) * 1024 + h * CHD;
#pragma unroll
            for (int it = 0; it < 4; it++) {
                int row = it * 8 + (t >> 5);
                float4 val = *(const float4*)(qb + (size_t)row * 1024 + jv_s * 4);
                float4 sv; sv.x = val.x * gm.x; sv.y = val.y * gm.y;
                sv.z = val.z * gm.z; sv.w = val.w * gm.w;
                qs4[row * 32 + jv_s] = sv;
            }
        }

        float m_run[2] = { -1e30f, -1e30f };
        float l_run[2] = { 0.f, 0.f };
        float oa[2][2][4];
#pragma unroll
        for (int a = 0; a < 2; a++)
#pragma unroll
            for (int bb = 0; bb < 2; bb++)
#pragma unroll
                for (int e = 0; e < 4; e++) oa[a][bb][e] = 0.f;

        for (int kt = 0; kt < T; kt++) {
            __syncthreads();
            {
                const float* kb = k + (size_t)(b * SEQ + kt * 64) * 1024 + h * CHD;
#pragma unroll
                for (int it = 0; it < 8; it++) {
                    int row = it * 8 + (t >> 5);
                    float4 val = *(const float4*)(kb + (size_t)row * 1024 + jv_s * 4);
                    kv4[row * 32 + (jv_s ^ ((row >> 2) & 7))] = val;
                }
            }
            __syncthreads();

            float acc[2][4];
#pragma unroll
            for (int ri = 0; ri < 2; ri++)
#pragma unroll
                for (int ci = 0; ci < 4; ci++) acc[ri][ci] = 0.f;
            int swz = cg & 7;
#pragma unroll 4
            for (int jv = 0; jv < 32; jv++) {
                float4 q0 = qs4[(rg * 2) * 32 + jv];
                float4 q1 = qs4[(rg * 2 + 1) * 32 + jv];
#pragma unroll
                for (int ci = 0; ci < 4; ci++) {
                    float4 kk = kv4[(cg * 4 + ci) * 32 + (jv ^ swz)];
                    acc[0][ci] += q0.x * kk.x + q0.y * kk.y + q0.z * kk.z + q0.w * kk.w;
                    acc[1][ci] += q1.x * kk.x + q1.y * kk.y + q1.z * kk.z + q1.w * kk.w;
                }
            }

            if (kt == T - 1) {
                int mb = kt * 64 + cg * 4;
                int rb = qi * 32 + rg * 2;
#pragma unroll
                for (int ri = 0; ri < 2; ri++)
#pragma unroll
                    for (int ci = 0; ci < 4; ci++)
                        if (mb + ci > rb + ri) acc[ri][ci] = -1e30f;
            }

#pragma unroll
            for (int ri = 0; ri < 2; ri++) {
                float tm = fmaxf(fmaxf(acc[ri][0], acc[ri][1]),
                                 fmaxf(acc[ri][2], acc[ri][3]));
                tm = fmaxf(tm, __shfl_xor(tm, 1, 16));
                tm = fmaxf(tm, __shfl_xor(tm, 2, 16));
                tm = fmaxf(tm, __shfl_xor(tm, 4, 16));
                tm = fmaxf(tm, __shfl_xor(tm, 8, 16));
                float mnew = fmaxf(m_run[ri], tm);
                float corr = __expf(m_run[ri] - mnew);
                float p0 = __expf(acc[ri][0] - mnew);
                float p1 = __expf(acc[ri][1] - mnew);
                float p2 = __expf(acc[ri][2] - mnew);
                float p3 = __expf(acc[ri][3] - mnew);
                float ts = p0 + p1 + p2 + p3;
                ts += __shfl_xor(ts, 1, 16);
                ts += __shfl_xor(ts, 2, 16);
                ts += __shfl_xor(ts, 4, 16);
                ts += __shfl_xor(ts, 8, 16);
                l_run[ri] = l_run[ri] * corr + ts;
                m_run[ri] = mnew;
#pragma unroll
                for (int bb = 0; bb < 2; bb++)
#pragma unroll
                    for (int e = 0; e < 4; e++) oa[ri][bb][e] *= corr;
                float4 pv; pv.x = p0; pv.y = p1; pv.z = p2; pv.w = p3;
                ps4[(rg * 2 + ri) * 17 + cg] = pv;
            }
            __syncthreads();

            {
                const float* vb = v + (size_t)(b * SEQ + kt * 64) * 1024 + h * CHD;
#pragma unroll
                for (int it = 0; it < 8; it++) {
                    int row = it * 8 + (t >> 5);
                    float4 val = *(const float4*)(vb + (size_t)row * 1024 + jv_s * 4);
                    kv4[row * 32 + jv_s] = val;
                }
            }
            __syncthreads();

#pragma unroll 2
            for (int mv = 0; mv < 16; mv++) {
                float4 p0 = ps4[(rg * 2) * 17 + mv];
                float4 p1 = ps4[(rg * 2 + 1) * 17 + mv];
                float pa[4] = { p0.x, p0.y, p0.z, p0.w };
                float pb[4] = { p1.x, p1.y, p1.z, p1.w };
#pragma unroll
                for (int e = 0; e < 4; e++) {
                    int m = mv * 4 + e;
                    float4 va = kv4[m * 32 + cg];
                    float4 vb4 = kv4[m * 32 + 16 + cg];
                    oa[0][0][0] += pa[e] * va.x;  oa[0][0][1] += pa[e] * va.y;
                    oa[0][0][2] += pa[e] * va.z;  oa[0][0][3] += pa[e] * va.w;
                    oa[0][1][0] += pa[e] * vb4.x; oa[0][1][1] += pa[e] * vb4.y;
                    oa[0][1][2] += pa[e] * vb4.z; oa[0][1][3] += pa[e] * vb4.w;
                    oa[1][0][0] += pb[e] * va.x;  oa[1][0][1] += pb[e] * va.y;
                    oa[1][0][2] += pb[e] * va.z;  oa[1][0][3] += pb[e] * va.w;
                    oa[1][1][0] += pb[e] * vb4.x; oa[1][1][1] += pb[e] * vb4.y;
                    oa[1][1][2] += pb[e] * vb4.z; oa[1][1][3] += pb[e] * vb4.w;
                }
            }
        }

#pragma unroll
        for (int ri = 0; ri < 2; ri++) {
            float inv = 1.f / l_run[ri];
            size_t row = (size_t)(b * SEQ + qi * 32 + rg * 2 + ri) * 1024 + h * CHD;
            float4 w0; w0.x = oa[ri][0][0] * inv; w0.y = oa[ri][0][1] * inv;
            w0.z = oa[ri][0][2] * inv; w0.w = oa[ri][0][3] * inv;
            float4 w1; w1.x = oa[ri][1][0] * inv; w1.y = oa[ri][1][1] * inv;
            w1.z = oa[ri][1][2] * inv; w1.w = oa[ri][1][3] * inv;
            *(float4*)(o + row + cg * 4)      = w0;
            *(float4*)(o + row + 64 + cg * 4) = w1;
        }
    }
}

// ---- fused: x += Wo*o; CLN; up*Tmix; gelu; x += Wdn*h ----------------------
__global__ __launch_bounds__(256) void proj_ffn_kernel(
        const float* __restrict__ o_in, const float* __restrict__ Wo,
        const float* __restrict__ g2, const float* __restrict__ Wup,
        const float* __restrict__ Tmix, const float* __restrict__ Wdn,
        float* __restrict__ x) {
    int bl = blockIdx.x;
    int t = threadIdx.x;
    __shared__ float osT[16 * 68];     // o transposed [d][c]
    __shared__ float xs[1024];         // x1 (pre-norm), [c][d]
    __shared__ float hsT[16 * 260];    // gelu(h) transposed [d][e]
    __shared__ float red[256];
    __shared__ float Ts[256];

    Ts[t] = Tmix[t];
#pragma unroll
    for (int it = 0; it < 4; it++) {
        int i = t + it * 256;
        osT[(i & 15) * 68 + (i >> 4)] = o_in[(size_t)bl * 1024 + i];
    }
    __syncthreads();

    int d = t & 15, og = t >> 4;
    float4 ov[16];
#pragma unroll
    for (int c4 = 0; c4 < 16; c4++)
        ov[c4] = *(const float4*)&osT[d * 68 + c4 * 4];

    float res[4];
    float s = 0.f;
#pragma unroll
    for (int oo = 0; oo < 4; oo++) {
        int oi = og * 4 + oo;
        float a0 = 0.f, a1 = 0.f, a2 = 0.f, a3 = 0.f;
#pragma unroll
        for (int c4 = 0; c4 < 16; c4++) {
            float4 w4 = *(const float4*)&Wo[oi * NC + c4 * 4];
            a0 += ov[c4].x * w4.x; a1 += ov[c4].y * w4.y;
            a2 += ov[c4].z * w4.z; a3 += ov[c4].w * w4.w;
        }
        float r = x[(size_t)bl * 1024 + oi * 16 + d] + (a0 + a1) + (a2 + a3);
        res[oo] = r;
        xs[oi * 16 + d] = r;
        s += r * r;
    }
    red[t] = s; __syncthreads();
    for (int st = 128; st > 0; st >>= 1) {
        if (t < st) red[t] += red[t + st];
        __syncthreads();
    }
    float inv = 1.f / sqrtf(red[0] * (1.f / 1024.f) + 1e-6f);

    // ---- up-proj (thread owns e), Tmix, gelu, write hsT ----
    {
        int e = t;
        float wrow[64];
#pragma unroll
        for (int c4 = 0; c4 < 16; c4++) {
            float4 w4 = *(const float4*)&Wup[e * NC + c4 * 4];
            wrow[c4 * 4 + 0] = w4.x * g2[c4 * 4 + 0];
            wrow[c4 * 4 + 1] = w4.y * g2[c4 * 4 + 1];
            wrow[c4 * 4 + 2] = w4.z * g2[c4 * 4 + 2];
            wrow[c4 * 4 + 3] = w4.w * g2[c4 * 4 + 3];
        }
        float hv[16];
#pragma unroll
        for (int dd = 0; dd < 16; dd++) hv[dd] = 0.f;
#pragma unroll 8
        for (int c = 0; c < 64; c++) {
            float wc = wrow[c];
            const float4* xr = (const float4*)&xs[c * 16];
#pragma unroll
            for (int d4 = 0; d4 < 4; d4++) {
                float4 x4 = xr[d4];
                hv[d4 * 4 + 0] += wc * x4.x; hv[d4 * 4 + 1] += wc * x4.y;
                hv[d4 * 4 + 2] += wc * x4.z; hv[d4 * 4 + 3] += wc * x4.w;
            }
        }
        float sv[16];
#pragma unroll
        for (int p = 0; p < 16; p++) sv[p] = 0.f;
#pragma unroll
        for (int j = 0; j < 16; j++) {
            float hj = hv[j];
            const float4* tr = (const float4*)&Ts[j * 16];
#pragma unroll
            for (int p4 = 0; p4 < 4; p4++) {
                float4 t4 = tr[p4];
                sv[p4 * 4 + 0] += hj * t4.x; sv[p4 * 4 + 1] += hj * t4.y;
                sv[p4 * 4 + 2] += hj * t4.z; sv[p4 * 4 + 3] += hj * t4.w;
            }
        }
        const float kA = 0.7978845608028654f;
#pragma unroll
        for (int p = 0; p < 16; p++) {
            float u = sv[p] * inv;
            float z = kA * (u + 0.044715f * u * u * u);
            float ex = __expf(2.f * z);
            float gg = u - u * (1.f / (ex + 1.f));   // u * ex/(ex+1) = gelu(u)
            hsT[p * 260 + e] = gg;
        }
    }
    __syncthreads();

    // ---- down-proj + residual ----
#pragma unroll
    for (int oo = 0; oo < 4; oo++) {
        int c = og * 4 + oo;
        float a0 = 0.f, a1 = 0.f, a2 = 0.f, a3 = 0.f;
#pragma unroll 16
        for (int e4 = 0; e4 < 64; e4++) {
            float4 w4 = *(const float4*)&Wdn[c * CEXP + e4 * 4];
            float4 h4 = *(const float4*)&hsT[d * 260 + e4 * 4];
            a0 += w4.x * h4.x; a1 += w4.y * h4.y;
            a2 += w4.z * h4.z; a3 += w4.w * h4.w;
        }
        x[(size_t)bl * 1024 + c * 16 + d] = res[oo] + (a0 + a1) + (a2 + a3);
    }
}

// ---- per-layer mixed rotor sandwich matrix Tmix[16][16] --------------------
__global__ void tmix_kernel(const float* __restrict__ rotor_biv,  // [NL,K,6]
                            const float* __restrict__ mixw,       // [NL,K]
                            float* __restrict__ Tmix) {           // [NL,16,16]
    int lay = blockIdx.x;
    __shared__ float rot[NK][D16];
    __shared__ float w[NK];
    int t = threadIdx.x;
    if (t < NK) {
        const int BIV[6] = { 3, 5, 6, 9, 10, 12 };
        float r[D16];
#pragma unroll
        for (int j = 0; j < D16; j++) r[j] = 0.f;
        r[0] = 1.f;
        float nrm = 1.f;
        for (int i = 0; i < 6; i++) {
            float bv = rotor_biv[(lay * NK + t) * 6 + i];
            r[BIV[i]] = bv; nrm += bv * bv;
        }
        nrm = sqrtf(nrm);
        for (int j = 0; j < D16; j++) rot[t][j] = r[j] / nrm;
    }
    if (t == 0) {
        float mx = -INFINITY;
        for (int kk = 0; kk < NK; kk++) mx = fmaxf(mx, mixw[lay * NK + kk]);
        float s = 0.f, e[NK];
        for (int kk = 0; kk < NK; kk++) { e[kk] = expf(mixw[lay * NK + kk] - mx); s += e[kk]; }
        for (int kk = 0; kk < NK; kk++) w[kk] = e[kk] / s;
    }
    __syncthreads();
    int j = t >> 4, p = t & 15;
    float acc = 0.f;
    for (int kk = 0; kk < NK; kk++) {
        float tk = 0.f;
        for (int i = 0; i < D16; i++) {
            int n = i ^ j ^ p;
            float rn = rot[kk][n] * rev_sign(n);          // rrev
            tk += rot[kk][i] * rn * gp_sign(i, j) * gp_sign(i ^ j, n);
        }
        acc += w[kk] * tk;
    }
    Tmix[lay * 256 + t] = acc;
}

// ---- final norm + blade gate + grade-0 extract -----------------------------
__global__ void g0_kernel(const float* __restrict__ x,
                          const float* __restrict__ g,
                          const float* __restrict__ sel,
                          float* __restrict__ g0) {
    int bl = blockIdx.x;
    const float* xr = x + (size_t)bl * 1024;
    __shared__ float red[256];
    float s = 0.f;
    for (int i = threadIdx.x; i < 1024; i += 256) { float v = xr[i]; s += v * v; }
    red[threadIdx.x] = s; __syncthreads();
    for (int st = 128; st > 0; st >>= 1) {
        if (threadIdx.x < st) red[threadIdx.x] += red[threadIdx.x + st];
        __syncthreads();
    }
    float inv = 1.f / sqrtf(red[0] * (1.f / 1024.f) + 1e-6f);
    if (threadIdx.x < NC) {
        int c = threadIdx.x;
        float gate = 1.f / (1.f + expf(-sel[c * D16]));
        g0[(size_t)bl * NC + c] = xr[c * D16] * inv * g[c] * gate;
    }
}

// ---- head_w transpose ------------------------------------------------------
__global__ void transpose_hw(const float* __restrict__ hw, float* __restrict__ hwT) {
    int idx = blockIdx.x * blockDim.x + threadIdx.x;
    if (idx >= VOCAB * NC) return;
    int v = idx / NC, c = idx & (NC - 1);
    hwT[(size_t)c * VOCAB + v] = hw[idx];
}

// ---- head GEMM: g0 tile in LDS (broadcast reads), weights in VGPRs ---------
// grid (125, 16): 256 vocab cols x 128 rows per block
__global__ __launch_bounds__(256) void head_kernel(
        const float* __restrict__ g0, const float* __restrict__ hwT,
        const float* __restrict__ hb, float* __restrict__ out) {
    int t = threadIdx.x;
    int v = blockIdx.x * 256 + t;
    int rbase = blockIdx.y * 128;
    __shared__ float4 gs[128 * 16];   // 128 rows x 64 c

    for (int i = t; i < 128 * 16; i += 256)
        gs[i] = ((const float4*)g0)[(size_t)rbase * 16 + i];

    float w[NC];
#pragma unroll
    for (int c = 0; c < NC; c++) w[c] = hwT[(size_t)c * VOCAB + v];
    float bb = hb[v];
    __syncthreads();

    for (int r = 0; r < 128; r++) {
        float a0 = 0.f, a1 = 0.f, a2 = 0.f, a3 = 0.f;
#pragma unroll
        for (int c4 = 0; c4 < 16; c4++) {
            float4 gv = gs[r * 16 + c4];
            a0 += gv.x * w[c4 * 4 + 0];
            a1 += gv.y * w[c4 * 4 + 1];
            a2 += gv.z * w[c4 * 4 + 2];
            a3 += gv.w * w[c4 * 4 + 3];
        }
        out[(size_t)(rbase + r) * VOCAB + v] = (a0 + a1) + (a2 + a3) + bb;
    }
}

extern "C" void kernel_launch(void* const* d_in, const int* in_sizes, int n_in,
                              void* d_out, int out_size, void* d_ws, size_t ws_size,
                              hipStream_t stream) {
    (void)in_sizes; (void)n_in; (void)out_size; (void)ws_size;
    const int*   tok      = (const int*)  d_in[0];
    const float* embed    = (const float*)d_in[1];
    const float* ln1_g    = (const float*)d_in[2];
    const float* ln2_g    = (const float*)d_in[3];
    const float* wq       = (const float*)d_in[4];
    const float* wk       = (const float*)d_in[5];
    const float* wv       = (const float*)d_in[6];
    const float* wo       = (const float*)d_in[7];
    const float* ffn_up   = (const float*)d_in[8];
    const float* ffn_down = (const float*)d_in[9];
    const float* rotor    = (const float*)d_in[10];
    const float* mixw     = (const float*)d_in[11];
    const float* out_ln_g = (const float*)d_in[12];
    const float* sel      = (const float*)d_in[13];
    const float* head_w   = (const float*)d_in[14];
    const float* head_b   = (const float*)d_in[15];
    float* out = (float*)d_out;

    float* ws  = (float*)d_ws;
    float* x    = ws;                 // 2,097,152
    float* q    = x    + 2097152;
    float* k    = q    + 2097152;
    float* v    = k    + 2097152;
    float* o    = v    + 2097152;
    float* Tmx  = o    + 2097152;     // 512
    float* g0   = Tmx  + 512;         // 131,072
    float* hwT  = g0   + 131072;      // 2,048,000

    embed_pe_kernel<<<(BATCH * SEQ * NC + 255) / 256, 256, 0, stream>>>(tok, embed, x);
    tmix_kernel<<<NLAY, 256, 0, stream>>>(rotor, mixw, Tmx);
    transpose_hw<<<(VOCAB * NC + 255) / 256, 256, 0, stream>>>(head_w, hwT);

    for (int l = 0; l < NLAY; l++) {
        qkv_cln_kernel<<<BATCH * SEQ, 256, 0, stream>>>(x, ln1_g + l * NC,
                                                        wq + l * NC * NC, wk + l * NC * NC,
                                                        wv + l * NC * NC, q, k, v);
        dim3 ag(16, BATCH * NH);
        flash_attn_kernel<<<ag, 256, 0, stream>>>(q, k, v, o);
        proj_ffn_kernel<<<BATCH * SEQ, 256, 0, stream>>>(o, wo + l * NC * NC,
                                                         ln2_g + l * NC,
                                                         ffn_up + l * CEXP * NC,
                                                         Tmx + l * 256,
                                                         ffn_down + l * NC * CEXP, x);
    }

    g0_kernel<<<BATCH * SEQ, 256, 0, stream>>>(x, out_ln_g, sel, g0);
    dim3 hg(VOCAB / 256, (BATCH * SEQ) / 128);   // (125, 16)
    head_kernel<<<hg, 256, 0, stream>>>(g0, hwT, head_b, out);
}

// Round 7
// 844.444 us; speedup vs baseline: 1.4225x; 1.0759x over previous
//
#include <hip/hip_runtime.h>
#include <hip/hip_bf16.h>
#include <math.h>

#define D16   16
#define NC    64      // channels C
#define NH    8       // heads
#define CHD   128     // (C/H)*D = 8*16
#define NLAY  2
#define CEXP  256     // C*FM
#define NK    8       // rotors
#define SEQ   1024
#define BATCH 2
#define VOCAB 32000

typedef __attribute__((ext_vector_type(8))) short short8;
typedef __attribute__((ext_vector_type(4))) float f32x4;

// ---- Cl(3,1) sign helpers (mirror the Python cayley construction) ----------
__device__ __forceinline__ float gp_sign(int a, int b) {
    int t = a >> 1, tot = 0;
    while (t) { tot += __popc(t & b); t >>= 1; }
    int neg = tot & 1;
    if ((a & b) & 8) neg ^= 1;   // METRIC[3] = -1 (e4^2 = -1)
    return neg ? -1.f : 1.f;
}
__device__ __forceinline__ float rev_sign(int j) {
    int g = __popc(j);
    return ((g * (g - 1) / 2) & 1) ? -1.f : 1.f;
}

// bf16 round-to-nearest-even from f32
__device__ __forceinline__ unsigned short f2bf(float f) {
    unsigned int u = __float_as_uint(f);
    unsigned int r = (u + 0x7FFFu + ((u >> 16) & 1u)) >> 16;
    return (unsigned short)r;
}

// ---- embed gather + rotary bivector PE (sandwich R x R~) -------------------
__global__ void embed_pe_kernel(const int* __restrict__ tok,
                                const float* __restrict__ embed,
                                float* __restrict__ x) {
    int idx = blockIdx.x * blockDim.x + threadIdx.x;      // (b*L+l)*C + c
    if (idx >= BATCH * SEQ * NC) return;
    int c  = idx & (NC - 1);
    int bl = idx / NC;
    int l  = bl & (SEQ - 1);
    int t  = tok[bl];

    const float* e = embed + ((size_t)t * NC + c) * D16;
    float v[D16];
#pragma unroll
    for (int j = 0; j < D16; j++) v[j] = e[j];

    float freq = exp2f(-(float)c * (13.287712379549449f / (float)NC));
    float theta = (float)l * freq;
    float sn, cs;
    __sincosf(theta, &sn, &cs);

    float tmp[D16], out[D16];
#pragma unroll
    for (int k = 0; k < D16; k++)
        tmp[k] = cs * v[k] + sn * gp_sign(3, 3 ^ k) * v[3 ^ k];
#pragma unroll
    for (int k = 0; k < D16; k++)
        out[k] = cs * tmp[k] - sn * gp_sign(k ^ 3, 3) * tmp[k ^ 3];

    float* xp = x + (size_t)idx * D16;
#pragma unroll
    for (int j = 0; j < D16; j++) xp[j] = out[j];
}

// ---- fused CLN + q/k/v projection; xsT transposed LDS, float4 reads --------
__global__ __launch_bounds__(256) void qkv_cln_kernel(
        const float* __restrict__ x, const float* __restrict__ g,
        const float* __restrict__ wq, const float* __restrict__ wk,
        const float* __restrict__ wv,
        float* __restrict__ q, float* __restrict__ k, float* __restrict__ v) {
    int bl = blockIdx.x;
    int t = threadIdx.x;
    __shared__ float xsT[16 * 68];     // [d][c] pad 68
    __shared__ float red[256];
    float s = 0.f;
#pragma unroll
    for (int it = 0; it < 4; it++) {
        int i = t + it * 256;
        float vv = x[(size_t)bl * 1024 + i];
        xsT[(i & 15) * 68 + (i >> 4)] = vv;
        s += vv * vv;
    }
    red[t] = s; __syncthreads();
    for (int st = 128; st > 0; st >>= 1) {
        if (t < st) red[t] += red[t + st];
        __syncthreads();
    }
    float inv = 1.f / sqrtf(red[0] * (1.f / 1024.f) + 1e-6f);
#pragma unroll
    for (int it = 0; it < 4; it++) {
        int i = t + it * 256;
        xsT[(i & 15) * 68 + (i >> 4)] *= inv * g[i >> 4];
    }
    __syncthreads();

    int d = t & 15, og = t >> 4;
    float4 xv[16];
#pragma unroll
    for (int c4 = 0; c4 < 16; c4++)
        xv[c4] = *(const float4*)&xsT[d * 68 + c4 * 4];

    const float* Ws[3] = { wq, wk, wv };
    float* Os[3] = { q, k, v };
#pragma unroll
    for (int m = 0; m < 3; m++) {
        const float* W = Ws[m];
        float* O = Os[m];
#pragma unroll
        for (int oo = 0; oo < 4; oo++) {
            int o = og * 4 + oo;
            float a0 = 0.f, a1 = 0.f, a2 = 0.f, a3 = 0.f;
#pragma unroll
            for (int c4 = 0; c4 < 16; c4++) {
                float4 w4 = *(const float4*)&W[o * NC + c4 * 4];
                a0 += xv[c4].x * w4.x; a1 += xv[c4].y * w4.y;
                a2 += xv[c4].z * w4.z; a3 += xv[c4].w * w4.w;
            }
            O[(size_t)bl * 1024 + o * 16 + d] = (a0 + a1) + (a2 + a3);
        }
    }
}

// ---- flash attention: Q-tile 32, K/V-tile 64, paired causal tasks ----------
__global__ __launch_bounds__(256) void flash_attn_kernel(
        const float* __restrict__ q, const float* __restrict__ k,
        const float* __restrict__ v, float* __restrict__ o) {
    int slot = blockIdx.x;
    int bh = blockIdx.y;
    int b = bh >> 3, h = bh & 7;
    int t = threadIdx.x;
    int rg = t >> 4, cg = t & 15;
    int jv_s = t & 31;

    __shared__ float4 qs4[32 * 32];
    __shared__ float4 kv4[64 * 32];
    __shared__ float4 ps4[32 * 17];

    const float scale = 0.088388347648318447f;  // 1/sqrt(128)

    float4 gm;
    {
        int d0 = (jv_s * 4) & 15;
        gm.x = gp_sign(d0, d0) * scale;
        gm.y = gp_sign(d0 + 1, d0 + 1) * scale;
        gm.z = gp_sign(d0 + 2, d0 + 2) * scale;
        gm.w = gp_sign(d0 + 3, d0 + 3) * scale;
    }

    for (int task = 0; task < 2; task++) {
        int qi = (task == 0) ? slot : (31 - slot);
        int T = (qi >> 1) + 1;

        __syncthreads();
        {
            const float* qb = q + (size_t)(b * SEQ + qi * 32) * 1024 + h * CHD;
#pragma unroll
            for (int it = 0; it < 4; it++) {
                int row = it * 8 + (t >> 5);
                float4 val = *(const float4*)(qb + (size_t)row * 1024 + jv_s * 4);
                float4 sv; sv.x = val.x * gm.x; sv.y = val.y * gm.y;
                sv.z = val.z * gm.z; sv.w = val.w * gm.w;
                qs4[row * 32 + jv_s] = sv;
            }
        }

        float m_run[2] = { -1e30f, -1e30f };
        float l_run[2] = { 0.f, 0.f };
        float oa[2][2][4];
#pragma unroll
        for (int a = 0; a < 2; a++)
#pragma unroll
            for (int bb = 0; bb < 2; bb++)
#pragma unroll
                for (int e = 0; e < 4; e++) oa[a][bb][e] = 0.f;

        for (int kt = 0; kt < T; kt++) {
            __syncthreads();
            {
                const float* kb = k + (size_t)(b * SEQ + kt * 64) * 1024 + h * CHD;
#pragma unroll
                for (int it = 0; it < 8; it++) {
                    int row = it * 8 + (t >> 5);
                    float4 val = *(const float4*)(kb + (size_t)row * 1024 + jv_s * 4);
                    kv4[row * 32 + (jv_s ^ ((row >> 2) & 7))] = val;
                }
            }
            __syncthreads();

            float acc[2][4];
#pragma unroll
            for (int ri = 0; ri < 2; ri++)
#pragma unroll
                for (int ci = 0; ci < 4; ci++) acc[ri][ci] = 0.f;
            int swz = cg & 7;
#pragma unroll 4
            for (int jv = 0; jv < 32; jv++) {
                float4 q0 = qs4[(rg * 2) * 32 + jv];
                float4 q1 = qs4[(rg * 2 + 1) * 32 + jv];
#pragma unroll
                for (int ci = 0; ci < 4; ci++) {
                    float4 kk = kv4[(cg * 4 + ci) * 32 + (jv ^ swz)];
                    acc[0][ci] += q0.x * kk.x + q0.y * kk.y + q0.z * kk.z + q0.w * kk.w;
                    acc[1][ci] += q1.x * kk.x + q1.y * kk.y + q1.z * kk.z + q1.w * kk.w;
                }
            }

            if (kt == T - 1) {
                int mb = kt * 64 + cg * 4;
                int rb = qi * 32 + rg * 2;
#pragma unroll
                for (int ri = 0; ri < 2; ri++)
#pragma unroll
                    for (int ci = 0; ci < 4; ci++)
                        if (mb + ci > rb + ri) acc[ri][ci] = -1e30f;
            }

#pragma unroll
            for (int ri = 0; ri < 2; ri++) {
                float tm = fmaxf(fmaxf(acc[ri][0], acc[ri][1]),
                                 fmaxf(acc[ri][2], acc[ri][3]));
                tm = fmaxf(tm, __shfl_xor(tm, 1, 16));
                tm = fmaxf(tm, __shfl_xor(tm, 2, 16));
                tm = fmaxf(tm, __shfl_xor(tm, 4, 16));
                tm = fmaxf(tm, __shfl_xor(tm, 8, 16));
                float mnew = fmaxf(m_run[ri], tm);
                float corr = __expf(m_run[ri] - mnew);
                float p0 = __expf(acc[ri][0] - mnew);
                float p1 = __expf(acc[ri][1] - mnew);
                float p2 = __expf(acc[ri][2] - mnew);
                float p3 = __expf(acc[ri][3] - mnew);
                float ts = p0 + p1 + p2 + p3;
                ts += __shfl_xor(ts, 1, 16);
                ts += __shfl_xor(ts, 2, 16);
                ts += __shfl_xor(ts, 4, 16);
                ts += __shfl_xor(ts, 8, 16);
                l_run[ri] = l_run[ri] * corr + ts;
                m_run[ri] = mnew;
#pragma unroll
                for (int bb = 0; bb < 2; bb++)
#pragma unroll
                    for (int e = 0; e < 4; e++) oa[ri][bb][e] *= corr;
                float4 pv; pv.x = p0; pv.y = p1; pv.z = p2; pv.w = p3;
                ps4[(rg * 2 + ri) * 17 + cg] = pv;
            }
            __syncthreads();

            {
                const float* vb = v + (size_t)(b * SEQ + kt * 64) * 1024 + h * CHD;
#pragma unroll
                for (int it = 0; it < 8; it++) {
                    int row = it * 8 + (t >> 5);
                    float4 val = *(const float4*)(vb + (size_t)row * 1024 + jv_s * 4);
                    kv4[row * 32 + jv_s] = val;
                }
            }
            __syncthreads();

#pragma unroll 2
            for (int mv = 0; mv < 16; mv++) {
                float4 p0 = ps4[(rg * 2) * 17 + mv];
                float4 p1 = ps4[(rg * 2 + 1) * 17 + mv];
                float pa[4] = { p0.x, p0.y, p0.z, p0.w };
                float pb[4] = { p1.x, p1.y, p1.z, p1.w };
#pragma unroll
                for (int e = 0; e < 4; e++) {
                    int m = mv * 4 + e;
                    float4 va = kv4[m * 32 + cg];
                    float4 vb4 = kv4[m * 32 + 16 + cg];
                    oa[0][0][0] += pa[e] * va.x;  oa[0][0][1] += pa[e] * va.y;
                    oa[0][0][2] += pa[e] * va.z;  oa[0][0][3] += pa[e] * va.w;
                    oa[0][1][0] += pa[e] * vb4.x; oa[0][1][1] += pa[e] * vb4.y;
                    oa[0][1][2] += pa[e] * vb4.z; oa[0][1][3] += pa[e] * vb4.w;
                    oa[1][0][0] += pb[e] * va.x;  oa[1][0][1] += pb[e] * va.y;
                    oa[1][0][2] += pb[e] * va.z;  oa[1][0][3] += pb[e] * va.w;
                    oa[1][1][0] += pb[e] * vb4.x; oa[1][1][1] += pb[e] * vb4.y;
                    oa[1][1][2] += pb[e] * vb4.z; oa[1][1][3] += pb[e] * vb4.w;
                }
            }
        }

#pragma unroll
        for (int ri = 0; ri < 2; ri++) {
            float inv = 1.f / l_run[ri];
            size_t row = (size_t)(b * SEQ + qi * 32 + rg * 2 + ri) * 1024 + h * CHD;
            float4 w0; w0.x = oa[ri][0][0] * inv; w0.y = oa[ri][0][1] * inv;
            w0.z = oa[ri][0][2] * inv; w0.w = oa[ri][0][3] * inv;
            float4 w1; w1.x = oa[ri][1][0] * inv; w1.y = oa[ri][1][1] * inv;
            w1.z = oa[ri][1][2] * inv; w1.w = oa[ri][1][3] * inv;
            *(float4*)(o + row + cg * 4)      = w0;
            *(float4*)(o + row + 64 + cg * 4) = w1;
        }
    }
}

// ---- fused: x += Wo*o; CLN; up*Tmix; gelu; x += Wdn*h ----------------------
__global__ __launch_bounds__(256) void proj_ffn_kernel(
        const float* __restrict__ o_in, const float* __restrict__ Wo,
        const float* __restrict__ g2, const float* __restrict__ Wup,
        const float* __restrict__ Tmix, const float* __restrict__ Wdn,
        float* __restrict__ x) {
    int bl = blockIdx.x;
    int t = threadIdx.x;
    __shared__ float osT[16 * 68];     // o transposed [d][c]
    __shared__ float xs[1024];         // x1 (pre-norm), [c][d]
    __shared__ float hsT[16 * 260];    // gelu(h) transposed [d][e]
    __shared__ float red[256];
    __shared__ float Ts[256];

    Ts[t] = Tmix[t];
#pragma unroll
    for (int it = 0; it < 4; it++) {
        int i = t + it * 256;
        osT[(i & 15) * 68 + (i >> 4)] = o_in[(size_t)bl * 1024 + i];
    }
    __syncthreads();

    int d = t & 15, og = t >> 4;
    float4 ov[16];
#pragma unroll
    for (int c4 = 0; c4 < 16; c4++)
        ov[c4] = *(const float4*)&osT[d * 68 + c4 * 4];

    float res[4];
    float s = 0.f;
#pragma unroll
    for (int oo = 0; oo < 4; oo++) {
        int oi = og * 4 + oo;
        float a0 = 0.f, a1 = 0.f, a2 = 0.f, a3 = 0.f;
#pragma unroll
        for (int c4 = 0; c4 < 16; c4++) {
            float4 w4 = *(const float4*)&Wo[oi * NC + c4 * 4];
            a0 += ov[c4].x * w4.x; a1 += ov[c4].y * w4.y;
            a2 += ov[c4].z * w4.z; a3 += ov[c4].w * w4.w;
        }
        float r = x[(size_t)bl * 1024 + oi * 16 + d] + (a0 + a1) + (a2 + a3);
        res[oo] = r;
        xs[oi * 16 + d] = r;
        s += r * r;
    }
    red[t] = s; __syncthreads();
    for (int st = 128; st > 0; st >>= 1) {
        if (t < st) red[t] += red[t + st];
        __syncthreads();
    }
    float inv = 1.f / sqrtf(red[0] * (1.f / 1024.f) + 1e-6f);

    // ---- up-proj (thread owns e), Tmix, gelu, write hsT ----
    {
        int e = t;
        float wrow[64];
#pragma unroll
        for (int c4 = 0; c4 < 16; c4++) {
            float4 w4 = *(const float4*)&Wup[e * NC + c4 * 4];
            wrow[c4 * 4 + 0] = w4.x * g2[c4 * 4 + 0];
            wrow[c4 * 4 + 1] = w4.y * g2[c4 * 4 + 1];
            wrow[c4 * 4 + 2] = w4.z * g2[c4 * 4 + 2];
            wrow[c4 * 4 + 3] = w4.w * g2[c4 * 4 + 3];
        }
        float hv[16];
#pragma unroll
        for (int dd = 0; dd < 16; dd++) hv[dd] = 0.f;
#pragma unroll 8
        for (int c = 0; c < 64; c++) {
            float wc = wrow[c];
            const float4* xr = (const float4*)&xs[c * 16];
#pragma unroll
            for (int d4 = 0; d4 < 4; d4++) {
                float4 x4 = xr[d4];
                hv[d4 * 4 + 0] += wc * x4.x; hv[d4 * 4 + 1] += wc * x4.y;
                hv[d4 * 4 + 2] += wc * x4.z; hv[d4 * 4 + 3] += wc * x4.w;
            }
        }
        float sv[16];
#pragma unroll
        for (int p = 0; p < 16; p++) sv[p] = 0.f;
#pragma unroll
        for (int j = 0; j < 16; j++) {
            float hj = hv[j];
            const float4* tr = (const float4*)&Ts[j * 16];
#pragma unroll
            for (int p4 = 0; p4 < 4; p4++) {
                float4 t4 = tr[p4];
                sv[p4 * 4 + 0] += hj * t4.x; sv[p4 * 4 + 1] += hj * t4.y;
                sv[p4 * 4 + 2] += hj * t4.z; sv[p4 * 4 + 3] += hj * t4.w;
            }
        }
        const float kA = 0.7978845608028654f;
#pragma unroll
        for (int p = 0; p < 16; p++) {
            float u = sv[p] * inv;
            float z = kA * (u + 0.044715f * u * u * u);
            float ex = __expf(2.f * z);
            float gg = u - u * (1.f / (ex + 1.f));   // u * ex/(ex+1) = gelu(u)
            hsT[p * 260 + e] = gg;
        }
    }
    __syncthreads();

    // ---- down-proj + residual ----
#pragma unroll
    for (int oo = 0; oo < 4; oo++) {
        int c = og * 4 + oo;
        float a0 = 0.f, a1 = 0.f, a2 = 0.f, a3 = 0.f;
#pragma unroll 16
        for (int e4 = 0; e4 < 64; e4++) {
            float4 w4 = *(const float4*)&Wdn[c * CEXP + e4 * 4];
            float4 h4 = *(const float4*)&hsT[d * 260 + e4 * 4];
            a0 += w4.x * h4.x; a1 += w4.y * h4.y;
            a2 += w4.z * h4.z; a3 += w4.w * h4.w;
        }
        x[(size_t)bl * 1024 + c * 16 + d] = res[oo] + (a0 + a1) + (a2 + a3);
    }
}

// ---- per-layer mixed rotor sandwich matrix Tmix[16][16] --------------------
__global__ void tmix_kernel(const float* __restrict__ rotor_biv,  // [NL,K,6]
                            const float* __restrict__ mixw,       // [NL,K]
                            float* __restrict__ Tmix) {           // [NL,16,16]
    int lay = blockIdx.x;
    __shared__ float rot[NK][D16];
    __shared__ float w[NK];
    int t = threadIdx.x;
    if (t < NK) {
        const int BIV[6] = { 3, 5, 6, 9, 10, 12 };
        float r[D16];
#pragma unroll
        for (int j = 0; j < D16; j++) r[j] = 0.f;
        r[0] = 1.f;
        float nrm = 1.f;
        for (int i = 0; i < 6; i++) {
            float bv = rotor_biv[(lay * NK + t) * 6 + i];
            r[BIV[i]] = bv; nrm += bv * bv;
        }
        nrm = sqrtf(nrm);
        for (int j = 0; j < D16; j++) rot[t][j] = r[j] / nrm;
    }
    if (t == 0) {
        float mx = -INFINITY;
        for (int kk = 0; kk < NK; kk++) mx = fmaxf(mx, mixw[lay * NK + kk]);
        float s = 0.f, e[NK];
        for (int kk = 0; kk < NK; kk++) { e[kk] = expf(mixw[lay * NK + kk] - mx); s += e[kk]; }
        for (int kk = 0; kk < NK; kk++) w[kk] = e[kk] / s;
    }
    __syncthreads();
    int j = t >> 4, p = t & 15;
    float acc = 0.f;
    for (int kk = 0; kk < NK; kk++) {
        float tk = 0.f;
        for (int i = 0; i < D16; i++) {
            int n = i ^ j ^ p;
            float rn = rot[kk][n] * rev_sign(n);          // rrev
            tk += rot[kk][i] * rn * gp_sign(i, j) * gp_sign(i ^ j, n);
        }
        acc += w[kk] * tk;
    }
    Tmix[lay * 256 + t] = acc;
}

// ---- final norm + blade gate + grade-0 extract; emit bf16 hi/lo ------------
__global__ void g0_kernel(const float* __restrict__ x,
                          const float* __restrict__ g,
                          const float* __restrict__ sel,
                          unsigned short* __restrict__ g0h,
                          unsigned short* __restrict__ g0l) {
    int bl = blockIdx.x;
    const float* xr = x + (size_t)bl * 1024;
    __shared__ float red[256];
    float s = 0.f;
    for (int i = threadIdx.x; i < 1024; i += 256) { float v = xr[i]; s += v * v; }
    red[threadIdx.x] = s; __syncthreads();
    for (int st = 128; st > 0; st >>= 1) {
        if (threadIdx.x < st) red[threadIdx.x] += red[threadIdx.x + st];
        __syncthreads();
    }
    float inv = 1.f / sqrtf(red[0] * (1.f / 1024.f) + 1e-6f);
    if (threadIdx.x < NC) {
        int c = threadIdx.x;
        float gate = 1.f / (1.f + expf(-sel[c * D16]));
        float val = xr[c * D16] * inv * g[c] * gate;
        unsigned short hi = f2bf(val);
        float fh = __uint_as_float((unsigned int)hi << 16);
        g0h[(size_t)bl * NC + c] = hi;
        g0l[(size_t)bl * NC + c] = f2bf(val - fh);
    }
}

// ---- head_w split into bf16 hi/lo ([v][c] layout kept) ---------------------
__global__ void split_hw(const float* __restrict__ hw,
                         unsigned short* __restrict__ hwh,
                         unsigned short* __restrict__ hwl) {
    int idx = blockIdx.x * blockDim.x + threadIdx.x;
    if (idx >= VOCAB * NC) return;
    float f = hw[idx];
    unsigned short hi = f2bf(f);
    float fh = __uint_as_float((unsigned int)hi << 16);
    hwh[idx] = hi;
    hwl[idx] = f2bf(f - fh);
}

// ---- head GEMM via bf16-split MFMA: [2048,64]@[64,32000] + bias ------------
// grid (500, 32); block 256 = 4 waves; wave computes 16 rows x 64 cols
__global__ __launch_bounds__(256) void head_mfma_kernel(
        const unsigned short* __restrict__ g0h, const unsigned short* __restrict__ g0l,
        const unsigned short* __restrict__ hwh, const unsigned short* __restrict__ hwl,
        const float* __restrict__ hb, float* __restrict__ out) {
    int t = threadIdx.x;
    int wave = t >> 6, lane = t & 63;
    int lr = lane & 15, lk = lane >> 4;
    int rowbase = blockIdx.y * 64 + wave * 16;
    int vbase = blockIdx.x * 64;

    short8 ah[2], al[2];
#pragma unroll
    for (int ks = 0; ks < 2; ks++) {
        size_t off = (size_t)(rowbase + lr) * NC + ks * 32 + lk * 8;
        ah[ks] = *(const short8*)(g0h + off);
        al[ks] = *(const short8*)(g0l + off);
    }
    f32x4 acc[4];
#pragma unroll
    for (int nt = 0; nt < 4; nt++) acc[nt] = (f32x4){0.f, 0.f, 0.f, 0.f};

#pragma unroll
    for (int ks = 0; ks < 2; ks++) {
#pragma unroll
        for (int nt = 0; nt < 4; nt++) {
            size_t boff = (size_t)(vbase + nt * 16 + lr) * NC + ks * 32 + lk * 8;
            short8 bh = *(const short8*)(hwh + boff);
            short8 bl = *(const short8*)(hwl + boff);
            acc[nt] = __builtin_amdgcn_mfma_f32_16x16x32_bf16(ah[ks], bh, acc[nt], 0, 0, 0);
            acc[nt] = __builtin_amdgcn_mfma_f32_16x16x32_bf16(ah[ks], bl, acc[nt], 0, 0, 0);
            acc[nt] = __builtin_amdgcn_mfma_f32_16x16x32_bf16(al[ks], bh, acc[nt], 0, 0, 0);
        }
    }

#pragma unroll
    for (int nt = 0; nt < 4; nt++) {
        int vcol = vbase + nt * 16 + lr;
        float bias = hb[vcol];
#pragma unroll
        for (int r = 0; r < 4; r++)
            out[(size_t)(rowbase + lk * 4 + r) * VOCAB + vcol] = acc[nt][r] + bias;
    }
}

extern "C" void kernel_launch(void* const* d_in, const int* in_sizes, int n_in,
                              void* d_out, int out_size, void* d_ws, size_t ws_size,
                              hipStream_t stream) {
    (void)in_sizes; (void)n_in; (void)out_size; (void)ws_size;
    const int*   tok      = (const int*)  d_in[0];
    const float* embed    = (const float*)d_in[1];
    const float* ln1_g    = (const float*)d_in[2];
    const float* ln2_g    = (const float*)d_in[3];
    const float* wq       = (const float*)d_in[4];
    const float* wk       = (const float*)d_in[5];
    const float* wv       = (const float*)d_in[6];
    const float* wo       = (const float*)d_in[7];
    const float* ffn_up   = (const float*)d_in[8];
    const float* ffn_down = (const float*)d_in[9];
    const float* rotor    = (const float*)d_in[10];
    const float* mixw     = (const float*)d_in[11];
    const float* out_ln_g = (const float*)d_in[12];
    const float* sel      = (const float*)d_in[13];
    const float* head_w   = (const float*)d_in[14];
    const float* head_b   = (const float*)d_in[15];
    float* out = (float*)d_out;

    float* ws  = (float*)d_ws;
    float* x    = ws;                 // 2,097,152 floats
    float* q    = x    + 2097152;
    float* k    = q    + 2097152;
    float* v    = k    + 2097152;
    float* o    = v    + 2097152;
    float* Tmx  = o    + 2097152;     // 512
    unsigned short* g0h = (unsigned short*)(Tmx + 512);        // 131072 ushort
    unsigned short* g0l = g0h + 131072;                        // 131072 ushort
    unsigned short* hwh = g0l + 131072;                        // 2,048,000 ushort
    unsigned short* hwl = hwh + 2048000;                       // 2,048,000 ushort

    embed_pe_kernel<<<(BATCH * SEQ * NC + 255) / 256, 256, 0, stream>>>(tok, embed, x);
    tmix_kernel<<<NLAY, 256, 0, stream>>>(rotor, mixw, Tmx);
    split_hw<<<(VOCAB * NC + 255) / 256, 256, 0, stream>>>(head_w, hwh, hwl);

    for (int l = 0; l < NLAY; l++) {
        qkv_cln_kernel<<<BATCH * SEQ, 256, 0, stream>>>(x, ln1_g + l * NC,
                                                        wq + l * NC * NC, wk + l * NC * NC,
                                                        wv + l * NC * NC, q, k, v);
        dim3 ag(16, BATCH * NH);
        flash_attn_kernel<<<ag, 256, 0, stream>>>(q, k, v, o);
        proj_ffn_kernel<<<BATCH * SEQ, 256, 0, stream>>>(o, wo + l * NC * NC,
                                                         ln2_g + l * NC,
                                                         ffn_up + l * CEXP * NC,
                                                         Tmx + l * 256,
                                                         ffn_down + l * NC * CEXP, x);
    }

    g0_kernel<<<BATCH * SEQ, 256, 0, stream>>>(x, out_ln_g, sel, g0h, g0l);
    dim3 hg(VOCAB / 64, (BATCH * SEQ) / 64);   // (500, 32)
    head_mfma_kernel<<<hg, 256, 0, stream>>>(g0h, g0l, hwh, hwl, head_b, out);
}

// Round 8
// 809.108 us; speedup vs baseline: 1.4847x; 1.0437x over previous
//
#include <hip/hip_runtime.h>
#include <hip/hip_bf16.h>
#include <math.h>

#define D16   16
#define NC    64      // channels C
#define NH    8       // heads
#define CHD   128     // (C/H)*D = 8*16
#define NLAY  2
#define CEXP  256     // C*FM
#define NK    8       // rotors
#define SEQ   1024
#define BATCH 2
#define VOCAB 32000

typedef __attribute__((ext_vector_type(8))) short short8;
typedef __attribute__((ext_vector_type(4))) float f32x4;

// ---- Cl(3,1) sign helpers (mirror the Python cayley construction) ----------
__device__ __forceinline__ float gp_sign(int a, int b) {
    int t = a >> 1, tot = 0;
    while (t) { tot += __popc(t & b); t >>= 1; }
    int neg = tot & 1;
    if ((a & b) & 8) neg ^= 1;   // METRIC[3] = -1 (e4^2 = -1)
    return neg ? -1.f : 1.f;
}
__device__ __forceinline__ float rev_sign(int j) {
    int g = __popc(j);
    return ((g * (g - 1) / 2) & 1) ? -1.f : 1.f;
}

// bf16 round-to-nearest-even from f32
__device__ __forceinline__ unsigned short f2bf(float f) {
    unsigned int u = __float_as_uint(f);
    unsigned int r = (u + 0x7FFFu + ((u >> 16) & 1u)) >> 16;
    return (unsigned short)r;
}

// ---- embed gather + rotary bivector PE (sandwich R x R~) -------------------
__global__ void embed_pe_kernel(const int* __restrict__ tok,
                                const float* __restrict__ embed,
                                float* __restrict__ x) {
    int idx = blockIdx.x * blockDim.x + threadIdx.x;      // (b*L+l)*C + c
    if (idx >= BATCH * SEQ * NC) return;
    int c  = idx & (NC - 1);
    int bl = idx / NC;
    int l  = bl & (SEQ - 1);
    int t  = tok[bl];

    const float* e = embed + ((size_t)t * NC + c) * D16;
    float v[D16];
#pragma unroll
    for (int j = 0; j < D16; j++) v[j] = e[j];

    float freq = exp2f(-(float)c * (13.287712379549449f / (float)NC));
    float theta = (float)l * freq;
    float sn, cs;
    __sincosf(theta, &sn, &cs);

    float tmp[D16], out[D16];
#pragma unroll
    for (int k = 0; k < D16; k++)
        tmp[k] = cs * v[k] + sn * gp_sign(3, 3 ^ k) * v[3 ^ k];
#pragma unroll
    for (int k = 0; k < D16; k++)
        out[k] = cs * tmp[k] - sn * gp_sign(k ^ 3, 3) * tmp[k ^ 3];

    float* xp = x + (size_t)idx * D16;
#pragma unroll
    for (int j = 0; j < D16; j++) xp[j] = out[j];
}

// ---- fused CLN + q/k/v projection; xsT transposed LDS, float4 reads --------
__global__ __launch_bounds__(256, 4) void qkv_cln_kernel(
        const float* __restrict__ x, const float* __restrict__ g,
        const float* __restrict__ wq, const float* __restrict__ wk,
        const float* __restrict__ wv,
        float* __restrict__ q, float* __restrict__ k, float* __restrict__ v) {
    int bl = blockIdx.x;
    int t = threadIdx.x;
    __shared__ float xsT[16 * 68];     // [d][c] pad 68
    __shared__ float red[256];
    float s = 0.f;
#pragma unroll
    for (int it = 0; it < 4; it++) {
        int i = t + it * 256;
        float vv = x[(size_t)bl * 1024 + i];
        xsT[(i & 15) * 68 + (i >> 4)] = vv;
        s += vv * vv;
    }
    red[t] = s; __syncthreads();
    for (int st = 128; st > 0; st >>= 1) {
        if (t < st) red[t] += red[t + st];
        __syncthreads();
    }
    float inv = 1.f / sqrtf(red[0] * (1.f / 1024.f) + 1e-6f);
#pragma unroll
    for (int it = 0; it < 4; it++) {
        int i = t + it * 256;
        xsT[(i & 15) * 68 + (i >> 4)] *= inv * g[i >> 4];
    }
    __syncthreads();

    int d = t & 15, og = t >> 4;
    float4 xv[16];
#pragma unroll
    for (int c4 = 0; c4 < 16; c4++)
        xv[c4] = *(const float4*)&xsT[d * 68 + c4 * 4];

    const float* Ws[3] = { wq, wk, wv };
    float* Os[3] = { q, k, v };
#pragma unroll
    for (int m = 0; m < 3; m++) {
        const float* W = Ws[m];
        float* O = Os[m];
#pragma unroll
        for (int oo = 0; oo < 4; oo++) {
            int o = og * 4 + oo;
            float a0 = 0.f, a1 = 0.f, a2 = 0.f, a3 = 0.f;
#pragma unroll
            for (int c4 = 0; c4 < 16; c4++) {
                float4 w4 = *(const float4*)&W[o * NC + c4 * 4];
                a0 += xv[c4].x * w4.x; a1 += xv[c4].y * w4.y;
                a2 += xv[c4].z * w4.z; a3 += xv[c4].w * w4.w;
            }
            O[(size_t)bl * 1024 + o * 16 + d] = (a0 + a1) + (a2 + a3);
        }
    }
}

// ---- flash attention: Q-tile 32, K/V-tile 64, paired causal tasks ----------
__global__ __launch_bounds__(256) void flash_attn_kernel(
        const float* __restrict__ q, const float* __restrict__ k,
        const float* __restrict__ v, float* __restrict__ o) {
    int slot = blockIdx.x;
    int bh = blockIdx.y;
    int b = bh >> 3, h = bh & 7;
    int t = threadIdx.x;
    int rg = t >> 4, cg = t & 15;
    int jv_s = t & 31;

    __shared__ float4 qs4[32 * 32];
    __shared__ float4 kv4[64 * 32];
    __shared__ float4 ps4[32 * 17];

    const float scale = 0.088388347648318447f;  // 1/sqrt(128)

    float4 gm;
    {
        int d0 = (jv_s * 4) & 15;
        gm.x = gp_sign(d0, d0) * scale;
        gm.y = gp_sign(d0 + 1, d0 + 1) * scale;
        gm.z = gp_sign(d0 + 2, d0 + 2) * scale;
        gm.w = gp_sign(d0 + 3, d0 + 3) * scale;
    }

    for (int task = 0; task < 2; task++) {
        int qi = (task == 0) ? slot : (31 - slot);
        int T = (qi >> 1) + 1;

        __syncthreads();
        {
            const float* qb = q + (size_t)(b * SEQ + qi * 32) * 1024 + h * CHD;
#pragma unroll
            for (int it = 0; it < 4; it++) {
                int row = it * 8 + (t >> 5);
                float4 val = *(const float4*)(qb + (size_t)row * 1024 + jv_s * 4);
                float4 sv; sv.x = val.x * gm.x; sv.y = val.y * gm.y;
                sv.z = val.z * gm.z; sv.w = val.w * gm.w;
                qs4[row * 32 + jv_s] = sv;
            }
        }

        float m_run[2] = { -1e30f, -1e30f };
        float l_run[2] = { 0.f, 0.f };
        float oa[2][2][4];
#pragma unroll
        for (int a = 0; a < 2; a++)
#pragma unroll
            for (int bb = 0; bb < 2; bb++)
#pragma unroll
                for (int e = 0; e < 4; e++) oa[a][bb][e] = 0.f;

        for (int kt = 0; kt < T; kt++) {
            __syncthreads();
            {
                const float* kb = k + (size_t)(b * SEQ + kt * 64) * 1024 + h * CHD;
#pragma unroll
                for (int it = 0; it < 8; it++) {
                    int row = it * 8 + (t >> 5);
                    float4 val = *(const float4*)(kb + (size_t)row * 1024 + jv_s * 4);
                    kv4[row * 32 + (jv_s ^ ((row >> 2) & 7))] = val;
                }
            }
            __syncthreads();

            float acc[2][4];
#pragma unroll
            for (int ri = 0; ri < 2; ri++)
#pragma unroll
                for (int ci = 0; ci < 4; ci++) acc[ri][ci] = 0.f;
            int swz = cg & 7;
#pragma unroll 4
            for (int jv = 0; jv < 32; jv++) {
                float4 q0 = qs4[(rg * 2) * 32 + jv];
                float4 q1 = qs4[(rg * 2 + 1) * 32 + jv];
#pragma unroll
                for (int ci = 0; ci < 4; ci++) {
                    float4 kk = kv4[(cg * 4 + ci) * 32 + (jv ^ swz)];
                    acc[0][ci] += q0.x * kk.x + q0.y * kk.y + q0.z * kk.z + q0.w * kk.w;
                    acc[1][ci] += q1.x * kk.x + q1.y * kk.y + q1.z * kk.z + q1.w * kk.w;
                }
            }

            if (kt == T - 1) {
                int mb = kt * 64 + cg * 4;
                int rb = qi * 32 + rg * 2;
#pragma unroll
                for (int ri = 0; ri < 2; ri++)
#pragma unroll
                    for (int ci = 0; ci < 4; ci++)
                        if (mb + ci > rb + ri) acc[ri][ci] = -1e30f;
            }

#pragma unroll
            for (int ri = 0; ri < 2; ri++) {
                float tm = fmaxf(fmaxf(acc[ri][0], acc[ri][1]),
                                 fmaxf(acc[ri][2], acc[ri][3]));
                tm = fmaxf(tm, __shfl_xor(tm, 1, 16));
                tm = fmaxf(tm, __shfl_xor(tm, 2, 16));
                tm = fmaxf(tm, __shfl_xor(tm, 4, 16));
                tm = fmaxf(tm, __shfl_xor(tm, 8, 16));
                float mnew = fmaxf(m_run[ri], tm);
                float corr = __expf(m_run[ri] - mnew);
                float p0 = __expf(acc[ri][0] - mnew);
                float p1 = __expf(acc[ri][1] - mnew);
                float p2 = __expf(acc[ri][2] - mnew);
                float p3 = __expf(acc[ri][3] - mnew);
                float ts = p0 + p1 + p2 + p3;
                ts += __shfl_xor(ts, 1, 16);
                ts += __shfl_xor(ts, 2, 16);
                ts += __shfl_xor(ts, 4, 16);
                ts += __shfl_xor(ts, 8, 16);
                l_run[ri] = l_run[ri] * corr + ts;
                m_run[ri] = mnew;
#pragma unroll
                for (int bb = 0; bb < 2; bb++)
#pragma unroll
                    for (int e = 0; e < 4; e++) oa[ri][bb][e] *= corr;
                float4 pv; pv.x = p0; pv.y = p1; pv.z = p2; pv.w = p3;
                ps4[(rg * 2 + ri) * 17 + cg] = pv;
            }
            __syncthreads();

            {
                const float* vb = v + (size_t)(b * SEQ + kt * 64) * 1024 + h * CHD;
#pragma unroll
                for (int it = 0; it < 8; it++) {
                    int row = it * 8 + (t >> 5);
                    float4 val = *(const float4*)(vb + (size_t)row * 1024 + jv_s * 4);
                    kv4[row * 32 + jv_s] = val;
                }
            }
            __syncthreads();

#pragma unroll 2
            for (int mv = 0; mv < 16; mv++) {
                float4 p0 = ps4[(rg * 2) * 17 + mv];
                float4 p1 = ps4[(rg * 2 + 1) * 17 + mv];
                float pa[4] = { p0.x, p0.y, p0.z, p0.w };
                float pb[4] = { p1.x, p1.y, p1.z, p1.w };
#pragma unroll
                for (int e = 0; e < 4; e++) {
                    int m = mv * 4 + e;
                    float4 va = kv4[m * 32 + cg];
                    float4 vb4 = kv4[m * 32 + 16 + cg];
                    oa[0][0][0] += pa[e] * va.x;  oa[0][0][1] += pa[e] * va.y;
                    oa[0][0][2] += pa[e] * va.z;  oa[0][0][3] += pa[e] * va.w;
                    oa[0][1][0] += pa[e] * vb4.x; oa[0][1][1] += pa[e] * vb4.y;
                    oa[0][1][2] += pa[e] * vb4.z; oa[0][1][3] += pa[e] * vb4.w;
                    oa[1][0][0] += pb[e] * va.x;  oa[1][0][1] += pb[e] * va.y;
                    oa[1][0][2] += pb[e] * va.z;  oa[1][0][3] += pb[e] * va.w;
                    oa[1][1][0] += pb[e] * vb4.x; oa[1][1][1] += pb[e] * vb4.y;
                    oa[1][1][2] += pb[e] * vb4.z; oa[1][1][3] += pb[e] * vb4.w;
                }
            }
        }

#pragma unroll
        for (int ri = 0; ri < 2; ri++) {
            float inv = 1.f / l_run[ri];
            size_t row = (size_t)(b * SEQ + qi * 32 + rg * 2 + ri) * 1024 + h * CHD;
            float4 w0; w0.x = oa[ri][0][0] * inv; w0.y = oa[ri][0][1] * inv;
            w0.z = oa[ri][0][2] * inv; w0.w = oa[ri][0][3] * inv;
            float4 w1; w1.x = oa[ri][1][0] * inv; w1.y = oa[ri][1][1] * inv;
            w1.z = oa[ri][1][2] * inv; w1.w = oa[ri][1][3] * inv;
            *(float4*)(o + row + cg * 4)      = w0;
            *(float4*)(o + row + 64 + cg * 4) = w1;
        }
    }
}

// ---- fused: x += Wo*o; CLN; up*Tmix; gelu; x += Wdn*h ----------------------
// register-lean: xs normalized in LDS (folds g2*inv), Wup streamed not cached
__global__ __launch_bounds__(256, 4) void proj_ffn_kernel(
        const float* __restrict__ o_in, const float* __restrict__ Wo,
        const float* __restrict__ g2, const float* __restrict__ Wup,
        const float* __restrict__ Tmix, const float* __restrict__ Wdn,
        float* __restrict__ x) {
    int bl = blockIdx.x;
    int t = threadIdx.x;
    __shared__ float osT[16 * 68];     // o transposed [d][c]
    __shared__ float xs[1024];         // x1; then normalized x1 (* inv * g2)
    __shared__ float hsT[16 * 260];    // gelu(h) transposed [d][e]
    __shared__ float red[256];
    __shared__ float Ts[256];

    Ts[t] = Tmix[t];
#pragma unroll
    for (int it = 0; it < 4; it++) {
        int i = t + it * 256;
        osT[(i & 15) * 68 + (i >> 4)] = o_in[(size_t)bl * 1024 + i];
    }
    __syncthreads();

    int d = t & 15, og = t >> 4;

    float res[4];
    float s = 0.f;
#pragma unroll
    for (int oo = 0; oo < 4; oo++) {
        int oi = og * 4 + oo;
        float a0 = 0.f, a1 = 0.f, a2 = 0.f, a3 = 0.f;
#pragma unroll
        for (int c4 = 0; c4 < 16; c4++) {
            float4 ov = *(const float4*)&osT[d * 68 + c4 * 4];
            float4 w4 = *(const float4*)&Wo[oi * NC + c4 * 4];
            a0 += ov.x * w4.x; a1 += ov.y * w4.y;
            a2 += ov.z * w4.z; a3 += ov.w * w4.w;
        }
        float r = x[(size_t)bl * 1024 + oi * 16 + d] + (a0 + a1) + (a2 + a3);
        res[oo] = r;
        xs[oi * 16 + d] = r;
        s += r * r;
    }
    red[t] = s; __syncthreads();
    for (int st = 128; st > 0; st >>= 1) {
        if (t < st) red[t] += red[t + st];
        __syncthreads();
    }
    float inv = 1.f / sqrtf(red[0] * (1.f / 1024.f) + 1e-6f);

    // normalize xs in place (fold inv * g2)
#pragma unroll
    for (int it = 0; it < 4; it++) {
        int i = t + it * 256;
        xs[i] *= inv * g2[i >> 4];
    }
    __syncthreads();

    // ---- up-proj (thread owns e), Tmix, gelu, write hsT ----
    {
        int e = t;
        float hv[16];
#pragma unroll
        for (int dd = 0; dd < 16; dd++) hv[dd] = 0.f;
#pragma unroll 4
        for (int c4 = 0; c4 < 16; c4++) {
            float4 w4 = *(const float4*)&Wup[e * NC + c4 * 4];
#pragma unroll
            for (int j = 0; j < 4; j++) {
                float wc = (j == 0) ? w4.x : (j == 1) ? w4.y : (j == 2) ? w4.z : w4.w;
                const float4* xr = (const float4*)&xs[(c4 * 4 + j) * 16];
#pragma unroll
                for (int d4 = 0; d4 < 4; d4++) {
                    float4 x4 = xr[d4];
                    hv[d4 * 4 + 0] += wc * x4.x; hv[d4 * 4 + 1] += wc * x4.y;
                    hv[d4 * 4 + 2] += wc * x4.z; hv[d4 * 4 + 3] += wc * x4.w;
                }
            }
        }
        float sv[16];
#pragma unroll
        for (int p = 0; p < 16; p++) sv[p] = 0.f;
#pragma unroll
        for (int j = 0; j < 16; j++) {
            float hj = hv[j];
            const float4* tr = (const float4*)&Ts[j * 16];
#pragma unroll
            for (int p4 = 0; p4 < 4; p4++) {
                float4 t4 = tr[p4];
                sv[p4 * 4 + 0] += hj * t4.x; sv[p4 * 4 + 1] += hj * t4.y;
                sv[p4 * 4 + 2] += hj * t4.z; sv[p4 * 4 + 3] += hj * t4.w;
            }
        }
        const float kA = 0.7978845608028654f;
#pragma unroll
        for (int p = 0; p < 16; p++) {
            float u = sv[p];
            float z = kA * (u + 0.044715f * u * u * u);
            float ex = __expf(2.f * z);
            float gg = u - u * (1.f / (ex + 1.f));   // gelu(u)
            hsT[p * 260 + e] = gg;
        }
    }
    __syncthreads();

    // ---- down-proj + residual ----
#pragma unroll
    for (int oo = 0; oo < 4; oo++) {
        int c = og * 4 + oo;
        float a0 = 0.f, a1 = 0.f, a2 = 0.f, a3 = 0.f;
#pragma unroll 16
        for (int e4 = 0; e4 < 64; e4++) {
            float4 w4 = *(const float4*)&Wdn[c * CEXP + e4 * 4];
            float4 h4 = *(const float4*)&hsT[d * 260 + e4 * 4];
            a0 += w4.x * h4.x; a1 += w4.y * h4.y;
            a2 += w4.z * h4.z; a3 += w4.w * h4.w;
        }
        x[(size_t)bl * 1024 + c * 16 + d] = res[oo] + (a0 + a1) + (a2 + a3);
    }
}

// ---- per-layer mixed rotor sandwich matrix Tmix[16][16] --------------------
__global__ void tmix_kernel(const float* __restrict__ rotor_biv,  // [NL,K,6]
                            const float* __restrict__ mixw,       // [NL,K]
                            float* __restrict__ Tmix) {           // [NL,16,16]
    int lay = blockIdx.x;
    __shared__ float rot[NK][D16];
    __shared__ float w[NK];
    int t = threadIdx.x;
    if (t < NK) {
        const int BIV[6] = { 3, 5, 6, 9, 10, 12 };
        float r[D16];
#pragma unroll
        for (int j = 0; j < D16; j++) r[j] = 0.f;
        r[0] = 1.f;
        float nrm = 1.f;
        for (int i = 0; i < 6; i++) {
            float bv = rotor_biv[(lay * NK + t) * 6 + i];
            r[BIV[i]] = bv; nrm += bv * bv;
        }
        nrm = sqrtf(nrm);
        for (int j = 0; j < D16; j++) rot[t][j] = r[j] / nrm;
    }
    if (t == 0) {
        float mx = -INFINITY;
        for (int kk = 0; kk < NK; kk++) mx = fmaxf(mx, mixw[lay * NK + kk]);
        float s = 0.f, e[NK];
        for (int kk = 0; kk < NK; kk++) { e[kk] = expf(mixw[lay * NK + kk] - mx); s += e[kk]; }
        for (int kk = 0; kk < NK; kk++) w[kk] = e[kk] / s;
    }
    __syncthreads();
    int j = t >> 4, p = t & 15;
    float acc = 0.f;
    for (int kk = 0; kk < NK; kk++) {
        float tk = 0.f;
        for (int i = 0; i < D16; i++) {
            int n = i ^ j ^ p;
            float rn = rot[kk][n] * rev_sign(n);          // rrev
            tk += rot[kk][i] * rn * gp_sign(i, j) * gp_sign(i ^ j, n);
        }
        acc += w[kk] * tk;
    }
    Tmix[lay * 256 + t] = acc;
}

// ---- final norm + blade gate + grade-0 extract; emit bf16 hi/lo ------------
__global__ void g0_kernel(const float* __restrict__ x,
                          const float* __restrict__ g,
                          const float* __restrict__ sel,
                          unsigned short* __restrict__ g0h,
                          unsigned short* __restrict__ g0l) {
    int bl = blockIdx.x;
    const float* xr = x + (size_t)bl * 1024;
    __shared__ float red[256];
    float s = 0.f;
    for (int i = threadIdx.x; i < 1024; i += 256) { float v = xr[i]; s += v * v; }
    red[threadIdx.x] = s; __syncthreads();
    for (int st = 128; st > 0; st >>= 1) {
        if (threadIdx.x < st) red[threadIdx.x] += red[threadIdx.x + st];
        __syncthreads();
    }
    float inv = 1.f / sqrtf(red[0] * (1.f / 1024.f) + 1e-6f);
    if (threadIdx.x < NC) {
        int c = threadIdx.x;
        float gate = 1.f / (1.f + expf(-sel[c * D16]));
        float val = xr[c * D16] * inv * g[c] * gate;
        unsigned short hi = f2bf(val);
        float fh = __uint_as_float((unsigned int)hi << 16);
        g0h[(size_t)bl * NC + c] = hi;
        g0l[(size_t)bl * NC + c] = f2bf(val - fh);
    }
}

// ---- head_w split into bf16 hi/lo ([v][c] layout kept) ---------------------
__global__ void split_hw(const float* __restrict__ hw,
                         unsigned short* __restrict__ hwh,
                         unsigned short* __restrict__ hwl) {
    int idx = blockIdx.x * blockDim.x + threadIdx.x;
    if (idx >= VOCAB * NC) return;
    float f = hw[idx];
    unsigned short hi = f2bf(f);
    float fh = __uint_as_float((unsigned int)hi << 16);
    hwh[idx] = hi;
    hwl[idx] = f2bf(f - fh);
}

// ---- head GEMM via bf16-split MFMA + LDS-staged coalesced stores -----------
// grid (500, 32); block 256 = 4 waves; wave computes 16 rows x 64 cols
__global__ __launch_bounds__(256) void head_mfma_kernel(
        const unsigned short* __restrict__ g0h, const unsigned short* __restrict__ g0l,
        const unsigned short* __restrict__ hwh, const unsigned short* __restrict__ hwl,
        const float* __restrict__ hb, float* __restrict__ out) {
    int t = threadIdx.x;
    int wave = t >> 6, lane = t & 63;
    int lr = lane & 15, lk = lane >> 4;
    int rowbase = blockIdx.y * 64 + wave * 16;
    int vbase = blockIdx.x * 64;

    __shared__ float tile[64 * 68];    // block's 64x64 f32 output, stride 68

    short8 ah[2], al[2];
#pragma unroll
    for (int ks = 0; ks < 2; ks++) {
        size_t off = (size_t)(rowbase + lr) * NC + ks * 32 + lk * 8;
        ah[ks] = *(const short8*)(g0h + off);
        al[ks] = *(const short8*)(g0l + off);
    }
    f32x4 acc[4];
#pragma unroll
    for (int nt = 0; nt < 4; nt++) acc[nt] = (f32x4){0.f, 0.f, 0.f, 0.f};

#pragma unroll
    for (int ks = 0; ks < 2; ks++) {
#pragma unroll
        for (int nt = 0; nt < 4; nt++) {
            size_t boff = (size_t)(vbase + nt * 16 + lr) * NC + ks * 32 + lk * 8;
            short8 bh = *(const short8*)(hwh + boff);
            short8 bl = *(const short8*)(hwl + boff);
            acc[nt] = __builtin_amdgcn_mfma_f32_16x16x32_bf16(ah[ks], bh, acc[nt], 0, 0, 0);
            acc[nt] = __builtin_amdgcn_mfma_f32_16x16x32_bf16(ah[ks], bl, acc[nt], 0, 0, 0);
            acc[nt] = __builtin_amdgcn_mfma_f32_16x16x32_bf16(al[ks], bh, acc[nt], 0, 0, 0);
        }
    }

    // stage to LDS: row = wave*16 + lk*4 + r, col = nt*16 + lr
#pragma unroll
    for (int nt = 0; nt < 4; nt++)
#pragma unroll
        for (int r = 0; r < 4; r++)
            tile[(wave * 16 + lk * 4 + r) * 68 + nt * 16 + lr] = acc[nt][r];
    __syncthreads();

    // coalesced write-out: 4 iters x (16 rows x 16 float4 cols)
    int col4 = t & 15, rw = t >> 4;
    float4 bias4 = *(const float4*)(hb + vbase + col4 * 4);
#pragma unroll
    for (int iter = 0; iter < 4; iter++) {
        int row = iter * 16 + rw;
        float4 vv = *(const float4*)&tile[row * 68 + col4 * 4];
        vv.x += bias4.x; vv.y += bias4.y; vv.z += bias4.z; vv.w += bias4.w;
        *(float4*)(out + (size_t)(blockIdx.y * 64 + row) * VOCAB + vbase + col4 * 4) = vv;
    }
}

extern "C" void kernel_launch(void* const* d_in, const int* in_sizes, int n_in,
                              void* d_out, int out_size, void* d_ws, size_t ws_size,
                              hipStream_t stream) {
    (void)in_sizes; (void)n_in; (void)out_size; (void)ws_size;
    const int*   tok      = (const int*)  d_in[0];
    const float* embed    = (const float*)d_in[1];
    const float* ln1_g    = (const float*)d_in[2];
    const float* ln2_g    = (const float*)d_in[3];
    const float* wq       = (const float*)d_in[4];
    const float* wk       = (const float*)d_in[5];
    const float* wv       = (const float*)d_in[6];
    const float* wo       = (const float*)d_in[7];
    const float* ffn_up   = (const float*)d_in[8];
    const float* ffn_down = (const float*)d_in[9];
    const float* rotor    = (const float*)d_in[10];
    const float* mixw     = (const float*)d_in[11];
    const float* out_ln_g = (const float*)d_in[12];
    const float* sel      = (const float*)d_in[13];
    const float* head_w   = (const float*)d_in[14];
    const float* head_b   = (const float*)d_in[15];
    float* out = (float*)d_out;

    float* ws  = (float*)d_ws;
    float* x    = ws;                 // 2,097,152 floats
    float* q    = x    + 2097152;
    float* k    = q    + 2097152;
    float* v    = k    + 2097152;
    float* o    = v    + 2097152;
    float* Tmx  = o    + 2097152;     // 512
    unsigned short* g0h = (unsigned short*)(Tmx + 512);        // 131072 ushort
    unsigned short* g0l = g0h + 131072;                        // 131072 ushort
    unsigned short* hwh = g0l + 131072;                        // 2,048,000 ushort
    unsigned short* hwl = hwh + 2048000;                       // 2,048,000 ushort

    embed_pe_kernel<<<(BATCH * SEQ * NC + 255) / 256, 256, 0, stream>>>(tok, embed, x);
    tmix_kernel<<<NLAY, 256, 0, stream>>>(rotor, mixw, Tmx);
    split_hw<<<(VOCAB * NC + 255) / 256, 256, 0, stream>>>(head_w, hwh, hwl);

    for (int l = 0; l < NLAY; l++) {
        qkv_cln_kernel<<<BATCH * SEQ, 256, 0, stream>>>(x, ln1_g + l * NC,
                                                        wq + l * NC * NC, wk + l * NC * NC,
                                                        wv + l * NC * NC, q, k, v);
        dim3 ag(16, BATCH * NH);
        flash_attn_kernel<<<ag, 256, 0, stream>>>(q, k, v, o);
        proj_ffn_kernel<<<BATCH * SEQ, 256, 0, stream>>>(o, wo + l * NC * NC,
                                                         ln2_g + l * NC,
                                                         ffn_up + l * CEXP * NC,
                                                         Tmx + l * 256,
                                                         ffn_down + l * NC * CEXP, x);
    }

    g0_kernel<<<BATCH * SEQ, 256, 0, stream>>>(x, out_ln_g, sel, g0h, g0l);
    dim3 hg(VOCAB / 64, (BATCH * SEQ) / 64);   // (500, 32)
    head_mfma_kernel<<<hg, 256, 0, stream>>>(g0h, g0l, hwh, hwl, head_b, out);
}

// Round 10
// 694.974 us; speedup vs baseline: 1.7285x; 1.1642x over previous
//
#include <hip/hip_runtime.h>
#include <hip/hip_bf16.h>
#include <math.h>

#define D16   16
#define NC    64      // channels C
#define NH    8       // heads
#define CHD   128     // (C/H)*D = 8*16
#define NLAY  2
#define CEXP  256     // C*FM
#define NK    8       // rotors
#define SEQ   1024
#define BATCH 2
#define VOCAB 32000

typedef unsigned short ushort;
typedef __attribute__((ext_vector_type(8))) short short8;
typedef __attribute__((ext_vector_type(4))) short short4v;
typedef __attribute__((ext_vector_type(4))) float f32x4;

// ---- Cl(3,1) sign helpers --------------------------------------------------
__device__ __forceinline__ float gp_sign(int a, int b) {
    int t = a >> 1, tot = 0;
    while (t) { tot += __popc(t & b); t >>= 1; }
    int neg = tot & 1;
    if ((a & b) & 8) neg ^= 1;   // METRIC[3] = -1
    return neg ? -1.f : 1.f;
}
__device__ __forceinline__ float rev_sign(int j) {
    int g = __popc(j);
    return ((g * (g - 1) / 2) & 1) ? -1.f : 1.f;
}
__device__ __forceinline__ ushort f2bf(float f) {
    unsigned int u = __float_as_uint(f);
    unsigned int r = (u + 0x7FFFu + ((u >> 16) & 1u)) >> 16;
    return (ushort)r;
}
__device__ __forceinline__ float bf2f(ushort h) {
    return __uint_as_float((unsigned int)h << 16);
}

// ---- embed gather + rotary bivector PE -------------------------------------
__global__ void embed_pe_kernel(const int* __restrict__ tok,
                                const float* __restrict__ embed,
                                float* __restrict__ x) {
    int idx = blockIdx.x * blockDim.x + threadIdx.x;
    if (idx >= BATCH * SEQ * NC) return;
    int c  = idx & (NC - 1);
    int bl = idx / NC;
    int l  = bl & (SEQ - 1);
    int t  = tok[bl];

    const float* e = embed + ((size_t)t * NC + c) * D16;
    float v[D16];
#pragma unroll
    for (int j = 0; j < D16; j++) v[j] = e[j];

    float freq = exp2f(-(float)c * (13.287712379549449f / (float)NC));
    float theta = (float)l * freq;
    float sn, cs;
    __sincosf(theta, &sn, &cs);

    float tmp[D16], out[D16];
#pragma unroll
    for (int k = 0; k < D16; k++)
        tmp[k] = cs * v[k] + sn * gp_sign(3, 3 ^ k) * v[3 ^ k];
#pragma unroll
    for (int k = 0; k < D16; k++)
        out[k] = cs * tmp[k] - sn * gp_sign(k ^ 3, 3) * tmp[k ^ 3];

    float* xp = x + (size_t)idx * D16;
#pragma unroll
    for (int j = 0; j < D16; j++) xp[j] = out[j];
}

// ---- fused CLN + q/k/v; q,k -> bf16 hi/lo (gmet*scale in q), v -> f32 ------
__global__ __launch_bounds__(256, 4) void qkv_cln_kernel(
        const float* __restrict__ x, const float* __restrict__ g,
        const float* __restrict__ wq, const float* __restrict__ wk,
        const float* __restrict__ wv,
        ushort* __restrict__ qh_, ushort* __restrict__ ql_,
        ushort* __restrict__ kh_, ushort* __restrict__ kl_,
        float* __restrict__ v) {
    int bl = blockIdx.x;
    int t = threadIdx.x;
    __shared__ float xsT[16 * 68];
    __shared__ float red[256];
    float s = 0.f;
#pragma unroll
    for (int it = 0; it < 4; it++) {
        int i = t + it * 256;
        float vv = x[(size_t)bl * 1024 + i];
        xsT[(i & 15) * 68 + (i >> 4)] = vv;
        s += vv * vv;
    }
    red[t] = s; __syncthreads();
    for (int st = 128; st > 0; st >>= 1) {
        if (t < st) red[t] += red[t + st];
        __syncthreads();
    }
    float inv = 1.f / sqrtf(red[0] * (1.f / 1024.f) + 1e-6f);
#pragma unroll
    for (int it = 0; it < 4; it++) {
        int i = t + it * 256;
        xsT[(i & 15) * 68 + (i >> 4)] *= inv * g[i >> 4];
    }
    __syncthreads();

    int d = t & 15, og = t >> 4;
    float4 xv[16];
#pragma unroll
    for (int c4 = 0; c4 < 16; c4++)
        xv[c4] = *(const float4*)&xsT[d * 68 + c4 * 4];

    float gs = gp_sign(d, d) * 0.088388347648318447f;   // gmet * 1/sqrt(128)

    const float* Ws[3] = { wq, wk, wv };
#pragma unroll
    for (int m = 0; m < 3; m++) {
        const float* W = Ws[m];
#pragma unroll
        for (int oo = 0; oo < 4; oo++) {
            int o = og * 4 + oo;
            float a0 = 0.f, a1 = 0.f, a2 = 0.f, a3 = 0.f;
#pragma unroll
            for (int c4 = 0; c4 < 16; c4++) {
                float4 w4 = *(const float4*)&W[o * NC + c4 * 4];
                a0 += xv[c4].x * w4.x; a1 += xv[c4].y * w4.y;
                a2 += xv[c4].z * w4.z; a3 += xv[c4].w * w4.w;
            }
            float val = (a0 + a1) + (a2 + a3);
            size_t oi = (size_t)bl * 1024 + o * 16 + d;
            if (m == 0) {
                float qv = val * gs;
                ushort hi = f2bf(qv);
                qh_[oi] = hi; ql_[oi] = f2bf(qv - bf2f(hi));
            } else if (m == 1) {
                ushort hi = f2bf(val);
                kh_[oi] = hi; kl_[oi] = f2bf(val - bf2f(hi));
            } else {
                v[oi] = val;
            }
        }
    }
}

// ---- V transpose + bf16 split: v[bl][chd] -> vT[(bh)*128+chd][L] -----------
__global__ __launch_bounds__(256) void vtrans_kernel(
        const float* __restrict__ v,
        ushort* __restrict__ vth, ushort* __restrict__ vtl) {
    int bh = blockIdx.x;     // 0..15
    int lt = blockIdx.y;     // 0..15
    int b = bh >> 3, h = bh & 7;
    int t = threadIdx.x;
    __shared__ float tile[64 * 132];

    {
        int r = t >> 2, cb = (t & 3) * 32;
        const float* src = v + (size_t)(b * SEQ + lt * 64 + r) * 1024 + h * CHD + cb;
#pragma unroll
        for (int j = 0; j < 8; j++)
            *(float4*)&tile[r * 132 + cb + j * 4] = *(const float4*)(src + j * 4);
    }
    __syncthreads();

    int j = t >> 1, ib = (t & 1) * 32;
    size_t dst = (size_t)((b * 8 + h) * 128 + j) * 1024 + lt * 64 + ib;
#pragma unroll
    for (int u = 0; u < 4; u++) {
        short8 sh, sl;
#pragma unroll
        for (int e = 0; e < 8; e++) {
            float f = tile[(ib + u * 8 + e) * 132 + j];
            ushort hi = f2bf(f);
            sh[e] = (short)hi;
            sl[e] = (short)f2bf(f - bf2f(hi));
        }
        *(short8*)(vth + dst + u * 8) = sh;
        *(short8*)(vtl + dst + u * 8) = sl;
    }
}

// ---- MFMA flash attention: S^T = K·Q^T, online softmax, O^T = V^T·P^T ------
// grid (16 qi, 16 bh); block 256 = 4 waves; wave owns 16 q rows
__global__ __launch_bounds__(256, 1) void attn_mfma_kernel(
        const ushort* __restrict__ qh_, const ushort* __restrict__ ql_,
        const ushort* __restrict__ kh_, const ushort* __restrict__ kl_,
        const ushort* __restrict__ vth, const ushort* __restrict__ vtl,
        float* __restrict__ o) {
    int qi = blockIdx.x;
    int bh = blockIdx.y;
    int b = bh >> 3, h = bh & 7;
    int t = threadIdx.x;
    int wave = t >> 6, lane = t & 63;
    int lq = lane & 15, lk4 = lane >> 4;

    __shared__ __align__(16) ushort Kh[64 * 128], Kl[64 * 128];
    __shared__ __align__(16) ushort Vh[128 * 64], Vl[128 * 64];
    __shared__ __align__(16) ushort Ph[4][16 * 80], Pl[4][16 * 80];

    int qrow = qi * 64 + wave * 16 + lq;

    // Q B-frags, resident whole kernel
    short8 qfh[4], qfl[4];
    {
        const ushort* qb = qh_ + (size_t)(b * SEQ + qrow) * 1024 + h * CHD;
        const ushort* qb2 = ql_ + (size_t)(b * SEQ + qrow) * 1024 + h * CHD;
#pragma unroll
        for (int ks = 0; ks < 4; ks++) {
            qfh[ks] = *(const short8*)(qb + ks * 32 + lk4 * 8);
            qfl[ks] = *(const short8*)(qb2 + ks * 32 + lk4 * 8);
        }
    }

    float m_run = -1e30f, l_run = 0.f;
    f32x4 oacc[8];
#pragma unroll
    for (int m = 0; m < 8; m++) oacc[m] = (f32x4){0.f, 0.f, 0.f, 0.f};

    int T = qi + 1;
    for (int kti = 0; kti < T; kti++) {
        __syncthreads();
        // stage K tile (64 k x 128 chd), swizzled
        {
            int r = t >> 2, cb = (t & 3) * 32;
            const ushort* sh_ = kh_ + (size_t)(b * SEQ + kti * 64 + r) * 1024 + h * CHD + cb;
            const ushort* sl_ = kl_ + (size_t)(b * SEQ + kti * 64 + r) * 1024 + h * CHD + cb;
            int swz = (r & 7) << 3;
#pragma unroll
            for (int j = 0; j < 4; j++) {
                int c8 = cb + j * 8;
                *(short8*)&Kh[r * 128 + (c8 ^ swz)] = *(const short8*)(sh_ + j * 8);
                *(short8*)&Kl[r * 128 + (c8 ^ swz)] = *(const short8*)(sl_ + j * 8);
            }
        }
        // stage V^T tile (128 d x 64 k), swizzled
        {
            int r = t >> 1, cb = (t & 1) * 32;
            const ushort* sh_ = vth + (size_t)((b * 8 + h) * 128 + r) * 1024 + kti * 64 + cb;
            const ushort* sl_ = vtl + (size_t)((b * 8 + h) * 128 + r) * 1024 + kti * 64 + cb;
            int swz = (r & 7) << 3;
#pragma unroll
            for (int j = 0; j < 4; j++) {
                int c8 = cb + j * 8;
                *(short8*)&Vh[r * 64 + (c8 ^ swz)] = *(const short8*)(sh_ + j * 8);
                *(short8*)&Vl[r * 64 + (c8 ^ swz)] = *(const short8*)(sl_ + j * 8);
            }
        }
        __syncthreads();

        // ---- scores: S^T tiles (16 k x 16 q), K as A, Q as B ----
        f32x4 s[4];
#pragma unroll
        for (int kt = 0; kt < 4; kt++) s[kt] = (f32x4){0.f, 0.f, 0.f, 0.f};
#pragma unroll
        for (int kt = 0; kt < 4; kt++) {
            int rr = kt * 16 + lq;
            int rswz = (rr & 7) << 3;
#pragma unroll
            for (int ks = 0; ks < 4; ks++) {
                int idx = rr * 128 + ((ks * 32 + lk4 * 8) ^ rswz);
                short8 kfh = *(const short8*)&Kh[idx];
                short8 kfl = *(const short8*)&Kl[idx];
                s[kt] = __builtin_amdgcn_mfma_f32_16x16x32_bf16(kfh, qfh[ks], s[kt], 0, 0, 0);
                s[kt] = __builtin_amdgcn_mfma_f32_16x16x32_bf16(kfl, qfh[ks], s[kt], 0, 0, 0);
                s[kt] = __builtin_amdgcn_mfma_f32_16x16x32_bf16(kfh, qfl[ks], s[kt], 0, 0, 0);
            }
        }

        // causal mask on diagonal tile
        if (kti == qi) {
#pragma unroll
            for (int kt = 0; kt < 4; kt++)
#pragma unroll
                for (int r = 0; r < 4; r++) {
                    int kg = kti * 64 + kt * 16 + lk4 * 4 + r;
                    if (kg > qrow) s[kt][r] = -1e30f;
                }
        }

        // ---- online softmax (per lane: 16 k-scores for q-col lq) ----
        float tm = -1e30f;
#pragma unroll
        for (int kt = 0; kt < 4; kt++)
#pragma unroll
            for (int r = 0; r < 4; r++) tm = fmaxf(tm, s[kt][r]);
        tm = fmaxf(tm, __shfl_xor(tm, 16));
        tm = fmaxf(tm, __shfl_xor(tm, 32));
        float mnew = fmaxf(m_run, tm);
        float corr = __expf(m_run - mnew);
        float ts = 0.f;
#pragma unroll
        for (int kt = 0; kt < 4; kt++) {
            float p0 = __expf(s[kt][0] - mnew);
            float p1 = __expf(s[kt][1] - mnew);
            float p2 = __expf(s[kt][2] - mnew);
            float p3 = __expf(s[kt][3] - mnew);
            ts += (p0 + p1) + (p2 + p3);
            short4v hi4, lo4;
            ushort u0 = f2bf(p0); hi4[0] = (short)u0; lo4[0] = (short)f2bf(p0 - bf2f(u0));
            ushort u1 = f2bf(p1); hi4[1] = (short)u1; lo4[1] = (short)f2bf(p1 - bf2f(u1));
            ushort u2 = f2bf(p2); hi4[2] = (short)u2; lo4[2] = (short)f2bf(p2 - bf2f(u2));
            ushort u3 = f2bf(p3); hi4[3] = (short)u3; lo4[3] = (short)f2bf(p3 - bf2f(u3));
            int pidx = lq * 80 + kt * 16 + lk4 * 4;
            *(short4v*)&Ph[wave][pidx] = hi4;
            *(short4v*)&Pl[wave][pidx] = lo4;
        }
        ts += __shfl_xor(ts, 16);
        ts += __shfl_xor(ts, 32);
        l_run = l_run * corr + ts;
        m_run = mnew;
#pragma unroll
        for (int m = 0; m < 8; m++) oacc[m] *= corr;

        // ---- PV: O^T tiles (16 d x 16 q), V^T as A, P as B ----
        short8 pfh[2], pfl[2];
#pragma unroll
        for (int ks = 0; ks < 2; ks++) {
            int pidx = lq * 80 + ks * 32 + lk4 * 8;
            pfh[ks] = *(const short8*)&Ph[wave][pidx];
            pfl[ks] = *(const short8*)&Pl[wave][pidx];
        }
#pragma unroll
        for (int m = 0; m < 8; m++) {
            int vr = m * 16 + lq;
            int vswz = (vr & 7) << 3;
#pragma unroll
            for (int ks = 0; ks < 2; ks++) {
                int idx = vr * 64 + ((ks * 32 + lk4 * 8) ^ vswz);
                short8 vfh = *(const short8*)&Vh[idx];
                short8 vfl = *(const short8*)&Vl[idx];
                oacc[m] = __builtin_amdgcn_mfma_f32_16x16x32_bf16(vfh, pfh[ks], oacc[m], 0, 0, 0);
                oacc[m] = __builtin_amdgcn_mfma_f32_16x16x32_bf16(vfl, pfh[ks], oacc[m], 0, 0, 0);
                oacc[m] = __builtin_amdgcn_mfma_f32_16x16x32_bf16(vfh, pfl[ks], oacc[m], 0, 0, 0);
            }
        }
    }

    // ---- write O (divide by l) ----
    float invl = 1.f / l_run;
    float* ob = o + (size_t)(b * SEQ + qrow) * 1024 + h * CHD;
#pragma unroll
    for (int m = 0; m < 8; m++) {
        float4 w;
        w.x = oacc[m][0] * invl; w.y = oacc[m][1] * invl;
        w.z = oacc[m][2] * invl; w.w = oacc[m][3] * invl;
        *(float4*)(ob + m * 16 + lk4 * 4) = w;
    }
}

// ---- fused: x += Wo*o; CLN; up*Tmix; gelu; x += Wdn*h ----------------------
__global__ __launch_bounds__(256, 4) void proj_ffn_kernel(
        const float* __restrict__ o_in, const float* __restrict__ Wo,
        const float* __restrict__ g2, const float* __restrict__ Wup,
        const float* __restrict__ Tmix, const float* __restrict__ Wdn,
        float* __restrict__ x) {
    int bl = blockIdx.x;
    int t = threadIdx.x;
    __shared__ float osT[16 * 68];
    __shared__ float xs[1024];
    __shared__ float hsT[16 * 260];
    __shared__ float red[256];
    __shared__ float Ts[256];

    Ts[t] = Tmix[t];
#pragma unroll
    for (int it = 0; it < 4; it++) {
        int i = t + it * 256;
        osT[(i & 15) * 68 + (i >> 4)] = o_in[(size_t)bl * 1024 + i];
    }
    __syncthreads();

    int d = t & 15, og = t >> 4;

    float res[4];
    float s = 0.f;
#pragma unroll
    for (int oo = 0; oo < 4; oo++) {
        int oi = og * 4 + oo;
        float a0 = 0.f, a1 = 0.f, a2 = 0.f, a3 = 0.f;
#pragma unroll
        for (int c4 = 0; c4 < 16; c4++) {
            float4 ov = *(const float4*)&osT[d * 68 + c4 * 4];
            float4 w4 = *(const float4*)&Wo[oi * NC + c4 * 4];
            a0 += ov.x * w4.x; a1 += ov.y * w4.y;
            a2 += ov.z * w4.z; a3 += ov.w * w4.w;
        }
        float r = x[(size_t)bl * 1024 + oi * 16 + d] + (a0 + a1) + (a2 + a3);
        res[oo] = r;
        xs[oi * 16 + d] = r;
        s += r * r;
    }
    red[t] = s; __syncthreads();
    for (int st = 128; st > 0; st >>= 1) {
        if (t < st) red[t] += red[t + st];
        __syncthreads();
    }
    float inv = 1.f / sqrtf(red[0] * (1.f / 1024.f) + 1e-6f);

#pragma unroll
    for (int it = 0; it < 4; it++) {
        int i = t + it * 256;
        xs[i] *= inv * g2[i >> 4];
    }
    __syncthreads();

    {
        int e = t;
        float hv[16];
#pragma unroll
        for (int dd = 0; dd < 16; dd++) hv[dd] = 0.f;
#pragma unroll 4
        for (int c4 = 0; c4 < 16; c4++) {
            float4 w4 = *(const float4*)&Wup[e * NC + c4 * 4];
#pragma unroll
            for (int j = 0; j < 4; j++) {
                float wc = (j == 0) ? w4.x : (j == 1) ? w4.y : (j == 2) ? w4.z : w4.w;
                const float4* xr = (const float4*)&xs[(c4 * 4 + j) * 16];
#pragma unroll
                for (int d4 = 0; d4 < 4; d4++) {
                    float4 x4 = xr[d4];
                    hv[d4 * 4 + 0] += wc * x4.x; hv[d4 * 4 + 1] += wc * x4.y;
                    hv[d4 * 4 + 2] += wc * x4.z; hv[d4 * 4 + 3] += wc * x4.w;
                }
            }
        }
        float sv[16];
#pragma unroll
        for (int p = 0; p < 16; p++) sv[p] = 0.f;
#pragma unroll
        for (int j = 0; j < 16; j++) {
            float hj = hv[j];
            const float4* tr = (const float4*)&Ts[j * 16];
#pragma unroll
            for (int p4 = 0; p4 < 4; p4++) {
                float4 t4 = tr[p4];
                sv[p4 * 4 + 0] += hj * t4.x; sv[p4 * 4 + 1] += hj * t4.y;
                sv[p4 * 4 + 2] += hj * t4.z; sv[p4 * 4 + 3] += hj * t4.w;
            }
        }
        const float kA = 0.7978845608028654f;
#pragma unroll
        for (int p = 0; p < 16; p++) {
            float u = sv[p];
            float z = kA * (u + 0.044715f * u * u * u);
            float ex = __expf(2.f * z);
            float gg = u - u * (1.f / (ex + 1.f));
            hsT[p * 260 + e] = gg;
        }
    }
    __syncthreads();

#pragma unroll
    for (int oo = 0; oo < 4; oo++) {
        int c = og * 4 + oo;
        float a0 = 0.f, a1 = 0.f, a2 = 0.f, a3 = 0.f;
#pragma unroll 16
        for (int e4 = 0; e4 < 64; e4++) {
            float4 w4 = *(const float4*)&Wdn[c * CEXP + e4 * 4];
            float4 h4 = *(const float4*)&hsT[d * 260 + e4 * 4];
            a0 += w4.x * h4.x; a1 += w4.y * h4.y;
            a2 += w4.z * h4.z; a3 += w4.w * h4.w;
        }
        x[(size_t)bl * 1024 + c * 16 + d] = res[oo] + (a0 + a1) + (a2 + a3);
    }
}

// ---- per-layer mixed rotor sandwich matrix Tmix[16][16] --------------------
__global__ void tmix_kernel(const float* __restrict__ rotor_biv,
                            const float* __restrict__ mixw,
                            float* __restrict__ Tmix) {
    int lay = blockIdx.x;
    __shared__ float rot[NK][D16];
    __shared__ float w[NK];
    int t = threadIdx.x;
    if (t < NK) {
        const int BIV[6] = { 3, 5, 6, 9, 10, 12 };
        float r[D16];
#pragma unroll
        for (int j = 0; j < D16; j++) r[j] = 0.f;
        r[0] = 1.f;
        float nrm = 1.f;
        for (int i = 0; i < 6; i++) {
            float bv = rotor_biv[(lay * NK + t) * 6 + i];
            r[BIV[i]] = bv; nrm += bv * bv;
        }
        nrm = sqrtf(nrm);
        for (int j = 0; j < D16; j++) rot[t][j] = r[j] / nrm;
    }
    if (t == 0) {
        float mx = -INFINITY;
        for (int kk = 0; kk < NK; kk++) mx = fmaxf(mx, mixw[lay * NK + kk]);
        float s = 0.f, e[NK];
        for (int kk = 0; kk < NK; kk++) { e[kk] = expf(mixw[lay * NK + kk] - mx); s += e[kk]; }
        for (int kk = 0; kk < NK; kk++) w[kk] = e[kk] / s;
    }
    __syncthreads();
    int j = t >> 4, p = t & 15;
    float acc = 0.f;
    for (int kk = 0; kk < NK; kk++) {
        float tk = 0.f;
        for (int i = 0; i < D16; i++) {
            int n = i ^ j ^ p;
            float rn = rot[kk][n] * rev_sign(n);
            tk += rot[kk][i] * rn * gp_sign(i, j) * gp_sign(i ^ j, n);
        }
        acc += w[kk] * tk;
    }
    Tmix[lay * 256 + t] = acc;
}

// ---- final norm + blade gate + grade-0; emit bf16 hi/lo --------------------
__global__ void g0_kernel(const float* __restrict__ x,
                          const float* __restrict__ g,
                          const float* __restrict__ sel,
                          ushort* __restrict__ g0h,
                          ushort* __restrict__ g0l) {
    int bl = blockIdx.x;
    const float* xr = x + (size_t)bl * 1024;
    __shared__ float red[256];
    float s = 0.f;
    for (int i = threadIdx.x; i < 1024; i += 256) { float v = xr[i]; s += v * v; }
    red[threadIdx.x] = s; __syncthreads();
    for (int st = 128; st > 0; st >>= 1) {
        if (threadIdx.x < st) red[threadIdx.x] += red[threadIdx.x + st];
        __syncthreads();
    }
    float inv = 1.f / sqrtf(red[0] * (1.f / 1024.f) + 1e-6f);
    if (threadIdx.x < NC) {
        int c = threadIdx.x;
        float gate = 1.f / (1.f + expf(-sel[c * D16]));
        float val = xr[c * D16] * inv * g[c] * gate;
        ushort hi = f2bf(val);
        g0h[(size_t)bl * NC + c] = hi;
        g0l[(size_t)bl * NC + c] = f2bf(val - bf2f(hi));
    }
}

// ---- head_w split into bf16 hi/lo ------------------------------------------
__global__ void split_hw(const float* __restrict__ hw,
                         ushort* __restrict__ hwh,
                         ushort* __restrict__ hwl) {
    int idx = blockIdx.x * blockDim.x + threadIdx.x;
    if (idx >= VOCAB * NC) return;
    float f = hw[idx];
    ushort hi = f2bf(f);
    hwh[idx] = hi;
    hwl[idx] = f2bf(f - bf2f(hi));
}

// ---- head GEMM via bf16-split MFMA + LDS stage + nontemporal stores --------
__global__ __launch_bounds__(256) void head_mfma_kernel(
        const ushort* __restrict__ g0h, const ushort* __restrict__ g0l,
        const ushort* __restrict__ hwh, const ushort* __restrict__ hwl,
        const float* __restrict__ hb, float* __restrict__ out) {
    int t = threadIdx.x;
    int wave = t >> 6, lane = t & 63;
    int lr = lane & 15, lk = lane >> 4;
    int rowbase = blockIdx.y * 64 + wave * 16;
    int vbase = blockIdx.x * 64;

    __shared__ float tile[64 * 68];

    short8 ah[2], al[2];
#pragma unroll
    for (int ks = 0; ks < 2; ks++) {
        size_t off = (size_t)(rowbase + lr) * NC + ks * 32 + lk * 8;
        ah[ks] = *(const short8*)(g0h + off);
        al[ks] = *(const short8*)(g0l + off);
    }
    f32x4 acc[4];
#pragma unroll
    for (int nt = 0; nt < 4; nt++) acc[nt] = (f32x4){0.f, 0.f, 0.f, 0.f};

#pragma unroll
    for (int ks = 0; ks < 2; ks++) {
#pragma unroll
        for (int nt = 0; nt < 4; nt++) {
            size_t boff = (size_t)(vbase + nt * 16 + lr) * NC + ks * 32 + lk * 8;
            short8 bh = *(const short8*)(hwh + boff);
            short8 bl = *(const short8*)(hwl + boff);
            acc[nt] = __builtin_amdgcn_mfma_f32_16x16x32_bf16(ah[ks], bh, acc[nt], 0, 0, 0);
            acc[nt] = __builtin_amdgcn_mfma_f32_16x16x32_bf16(ah[ks], bl, acc[nt], 0, 0, 0);
            acc[nt] = __builtin_amdgcn_mfma_f32_16x16x32_bf16(al[ks], bh, acc[nt], 0, 0, 0);
        }
    }

#pragma unroll
    for (int nt = 0; nt < 4; nt++)
#pragma unroll
        for (int r = 0; r < 4; r++)
            tile[(wave * 16 + lk * 4 + r) * 68 + nt * 16 + lr] = acc[nt][r];
    __syncthreads();

    int col4 = t & 15, rw = t >> 4;
    float4 bias4 = *(const float4*)(hb + vbase + col4 * 4);
#pragma unroll
    for (int iter = 0; iter < 4; iter++) {
        int row = iter * 16 + rw;
        float4 vv = *(const float4*)&tile[row * 68 + col4 * 4];
        f32x4 sv;
        sv[0] = vv.x + bias4.x; sv[1] = vv.y + bias4.y;
        sv[2] = vv.z + bias4.z; sv[3] = vv.w + bias4.w;
        __builtin_nontemporal_store(sv,
            (f32x4*)(out + (size_t)(blockIdx.y * 64 + row) * VOCAB + vbase + col4 * 4));
    }
}

extern "C" void kernel_launch(void* const* d_in, const int* in_sizes, int n_in,
                              void* d_out, int out_size, void* d_ws, size_t ws_size,
                              hipStream_t stream) {
    (void)in_sizes; (void)n_in; (void)out_size; (void)ws_size;
    const int*   tok      = (const int*)  d_in[0];
    const float* embed    = (const float*)d_in[1];
    const float* ln1_g    = (const float*)d_in[2];
    const float* ln2_g    = (const float*)d_in[3];
    const float* wq       = (const float*)d_in[4];
    const float* wk       = (const float*)d_in[5];
    const float* wv       = (const float*)d_in[6];
    const float* wo       = (const float*)d_in[7];
    const float* ffn_up   = (const float*)d_in[8];
    const float* ffn_down = (const float*)d_in[9];
    const float* rotor    = (const float*)d_in[10];
    const float* mixw     = (const float*)d_in[11];
    const float* out_ln_g = (const float*)d_in[12];
    const float* sel      = (const float*)d_in[13];
    const float* head_w   = (const float*)d_in[14];
    const float* head_b   = (const float*)d_in[15];
    float* out = (float*)d_out;

    float* ws  = (float*)d_ws;
    float* x    = ws;                         // 2,097,152 f
    float* o    = x + 2097152;                // 2,097,152 f
    float* vbuf = o + 2097152;                // 2,097,152 f
    float* Tmx  = vbuf + 2097152;             // 512 f
    ushort* qh = (ushort*)(Tmx + 512);        // 2,097,152 us
    ushort* ql = qh + 2097152;
    ushort* kh = ql + 2097152;
    ushort* kl = kh + 2097152;
    ushort* vth = kl + 2097152;               // 2,097,152 us
    ushort* vtl = vth + 2097152;
    ushort* g0h = vtl + 2097152;              // 131,072 us
    ushort* g0l = g0h + 131072;
    ushort* hwh = g0l + 131072;               // 2,048,000 us
    ushort* hwl = hwh + 2048000;

    embed_pe_kernel<<<(BATCH * SEQ * NC + 255) / 256, 256, 0, stream>>>(tok, embed, x);
    tmix_kernel<<<NLAY, 256, 0, stream>>>(rotor, mixw, Tmx);
    split_hw<<<(VOCAB * NC + 255) / 256, 256, 0, stream>>>(head_w, hwh, hwl);

    for (int l = 0; l < NLAY; l++) {
        qkv_cln_kernel<<<BATCH * SEQ, 256, 0, stream>>>(x, ln1_g + l * NC,
                                                        wq + l * NC * NC, wk + l * NC * NC,
                                                        wv + l * NC * NC,
                                                        qh, ql, kh, kl, vbuf);
        dim3 vg(16, 16);
        vtrans_kernel<<<vg, 256, 0, stream>>>(vbuf, vth, vtl);
        dim3 ag(16, 16);
        attn_mfma_kernel<<<ag, 256, 0, stream>>>(qh, ql, kh, kl, vth, vtl, o);
        proj_ffn_kernel<<<BATCH * SEQ, 256, 0, stream>>>(o, wo + l * NC * NC,
                                                         ln2_g + l * NC,
                                                         ffn_up + l * CEXP * NC,
                                                         Tmx + l * 256,
                                                         ffn_down + l * NC * CEXP, x);
    }

    g0_kernel<<<BATCH * SEQ, 256, 0, stream>>>(x, out_ln_g, sel, g0h, g0l);
    dim3 hg(VOCAB / 64, (BATCH * SEQ) / 64);   // (500, 32)
    head_mfma_kernel<<<hg, 256, 0, stream>>>(g0h, g0l, hwh, hwl, head_b, out);
}

// Round 11
// 447.332 us; speedup vs baseline: 2.6854x; 1.5536x over previous
//
#include <hip/hip_runtime.h>
#include <hip/hip_bf16.h>
#include <math.h>

#define D16   16
#define NC    64      // channels C
#define NH    8       // heads
#define CHD   128     // (C/H)*D = 8*16
#define NLAY  2
#define CEXP  256     // C*FM
#define NK    8       // rotors
#define SEQ   1024
#define BATCH 2
#define VOCAB 32000

typedef unsigned short ushort;
typedef __attribute__((ext_vector_type(8))) short short8;
typedef __attribute__((ext_vector_type(4))) short short4v;
typedef __attribute__((ext_vector_type(4))) float f32x4;

// ---- Cl(3,1) sign helpers --------------------------------------------------
__device__ __forceinline__ float gp_sign(int a, int b) {
    int t = a >> 1, tot = 0;
    while (t) { tot += __popc(t & b); t >>= 1; }
    int neg = tot & 1;
    if ((a & b) & 8) neg ^= 1;   // METRIC[3] = -1
    return neg ? -1.f : 1.f;
}
__device__ __forceinline__ float rev_sign(int j) {
    int g = __popc(j);
    return ((g * (g - 1) / 2) & 1) ? -1.f : 1.f;
}
__device__ __forceinline__ ushort f2bf(float f) {
    unsigned int u = __float_as_uint(f);
    unsigned int r = (u + 0x7FFFu + ((u >> 16) & 1u)) >> 16;
    return (ushort)r;
}
__device__ __forceinline__ float bf2f(ushort h) {
    return __uint_as_float((unsigned int)h << 16);
}

// ---- embed gather + rotary bivector PE -------------------------------------
__global__ void embed_pe_kernel(const int* __restrict__ tok,
                                const float* __restrict__ embed,
                                float* __restrict__ x) {
    int idx = blockIdx.x * blockDim.x + threadIdx.x;
    if (idx >= BATCH * SEQ * NC) return;
    int c  = idx & (NC - 1);
    int bl = idx / NC;
    int l  = bl & (SEQ - 1);
    int t  = tok[bl];

    const float* e = embed + ((size_t)t * NC + c) * D16;
    float v[D16];
#pragma unroll
    for (int j = 0; j < D16; j++) v[j] = e[j];

    float freq = exp2f(-(float)c * (13.287712379549449f / (float)NC));
    float theta = (float)l * freq;
    float sn, cs;
    __sincosf(theta, &sn, &cs);

    float tmp[D16], out[D16];
#pragma unroll
    for (int k = 0; k < D16; k++)
        tmp[k] = cs * v[k] + sn * gp_sign(3, 3 ^ k) * v[3 ^ k];
#pragma unroll
    for (int k = 0; k < D16; k++)
        out[k] = cs * tmp[k] - sn * gp_sign(k ^ 3, 3) * tmp[k ^ 3];

    float* xp = x + (size_t)idx * D16;
#pragma unroll
    for (int j = 0; j < D16; j++) xp[j] = out[j];
}

// ---- split layer weights into bf16 hi/lo -----------------------------------
// wsp layout (ushort offsets): wqh 0, wql 8192, wkh 16384, wkl 24576,
// wvh 32768, wvl 40960, woh 49152, wol 57344, uph 65536, upl 98304,
// dnh 131072, dnl 163840  (total 196608)
__global__ void split_lw(const float* __restrict__ wq, const float* __restrict__ wk,
                         const float* __restrict__ wv, const float* __restrict__ wo,
                         const float* __restrict__ up, const float* __restrict__ dn,
                         ushort* __restrict__ wsp) {
    int idx = blockIdx.x * 256 + threadIdx.x;
    if (idx >= 98304) return;
    const float* src; ushort *dh, *dl; int off;
    if (idx < 8192)       { src = wq; off = idx;         dh = wsp;          dl = wsp + 8192; }
    else if (idx < 16384) { src = wk; off = idx - 8192;  dh = wsp + 16384;  dl = wsp + 24576; }
    else if (idx < 24576) { src = wv; off = idx - 16384; dh = wsp + 32768;  dl = wsp + 40960; }
    else if (idx < 32768) { src = wo; off = idx - 24576; dh = wsp + 49152;  dl = wsp + 57344; }
    else if (idx < 65536) { src = up; off = idx - 32768; dh = wsp + 65536;  dl = wsp + 98304; }
    else                  { src = dn; off = idx - 65536; dh = wsp + 131072; dl = wsp + 163840; }
    float f = src[off];
    ushort hi = f2bf(f);
    dh[off] = hi;
    dl[off] = f2bf(f - bf2f(hi));
}

// ---- MFMA qkv: per-token [64o x 64c] x [64c x 16d]; CLN fused --------------
// grid 512; block 256 = 4 waves = 4 tokens
__global__ __launch_bounds__(256) void qkv_mfma_kernel(
        const float* __restrict__ x, const float* __restrict__ g,
        const ushort* __restrict__ wqh, const ushort* __restrict__ wql,
        const ushort* __restrict__ wkh, const ushort* __restrict__ wkl,
        const ushort* __restrict__ wvh, const ushort* __restrict__ wvl,
        ushort* __restrict__ qh_, ushort* __restrict__ ql_,
        ushort* __restrict__ kh_, ushort* __restrict__ kl_,
        float* __restrict__ v) {
    __shared__ float xlds[4][1024];
    __shared__ float glds[64];
    int t = threadIdx.x, wave = t >> 6, lane = t & 63;
    int tok = blockIdx.x * 4 + wave;
    if (t < 64) glds[t] = g[t];
    float ssum = 0.f;
    {
        const float* src = x + (size_t)tok * 1024 + lane * 16;
        float* dst = &xlds[wave][lane * 16];
#pragma unroll
        for (int i = 0; i < 4; i++) {
            float4 vv = *(const float4*)(src + i * 4);
            *(float4*)(dst + i * 4) = vv;
            ssum += vv.x * vv.x + vv.y * vv.y + vv.z * vv.z + vv.w * vv.w;
        }
    }
#pragma unroll
    for (int off = 32; off > 0; off >>= 1) ssum += __shfl_xor(ssum, off);
    float inv = 1.f / sqrtf(ssum * (1.f / 1024.f) + 1e-6f);
    __syncthreads();

    int dn = lane & 15, kg = lane >> 4;
    short8 bfh[2], bfl[2];
#pragma unroll
    for (int ks = 0; ks < 2; ks++) {
        int c0 = ks * 32 + kg * 8;
#pragma unroll
        for (int i = 0; i < 8; i++) {
            float val = xlds[wave][(c0 + i) * 16 + dn] * inv * glds[c0 + i];
            ushort hi = f2bf(val);
            bfh[ks][i] = (short)hi;
            bfl[ks][i] = (short)f2bf(val - bf2f(hi));
        }
    }
    float gs = gp_sign(dn, dn) * 0.088388347648318447f;

    const ushort* Wh[3] = { wqh, wkh, wvh };
    const ushort* Wl[3] = { wql, wkl, wvl };
#pragma unroll
    for (int m = 0; m < 3; m++) {
#pragma unroll
        for (int Mt = 0; Mt < 4; Mt++) {
            f32x4 acc = (f32x4){0.f, 0.f, 0.f, 0.f};
#pragma unroll
            for (int ks = 0; ks < 2; ks++) {
                size_t aoff = (size_t)(Mt * 16 + dn) * 64 + ks * 32 + kg * 8;
                short8 ah = *(const short8*)(Wh[m] + aoff);
                short8 al = *(const short8*)(Wl[m] + aoff);
                acc = __builtin_amdgcn_mfma_f32_16x16x32_bf16(ah, bfh[ks], acc, 0, 0, 0);
                acc = __builtin_amdgcn_mfma_f32_16x16x32_bf16(ah, bfl[ks], acc, 0, 0, 0);
                acc = __builtin_amdgcn_mfma_f32_16x16x32_bf16(al, bfh[ks], acc, 0, 0, 0);
            }
#pragma unroll
            for (int j = 0; j < 4; j++) {
                int o = Mt * 16 + kg * 4 + j;
                size_t oi = (size_t)tok * 1024 + o * 16 + dn;
                if (m == 0) {
                    float qv = acc[j] * gs;
                    ushort hi = f2bf(qv);
                    qh_[oi] = hi; ql_[oi] = f2bf(qv - bf2f(hi));
                } else if (m == 1) {
                    ushort hi = f2bf(acc[j]);
                    kh_[oi] = hi; kl_[oi] = f2bf(acc[j] - bf2f(hi));
                } else {
                    v[oi] = acc[j];
                }
            }
        }
    }
}

// ---- V transpose + bf16 split ----------------------------------------------
__global__ __launch_bounds__(256) void vtrans_kernel(
        const float* __restrict__ v,
        ushort* __restrict__ vth, ushort* __restrict__ vtl) {
    int bh = blockIdx.x;
    int lt = blockIdx.y;
    int b = bh >> 3, h = bh & 7;
    int t = threadIdx.x;
    __shared__ float tile[64 * 132];

    {
        int r = t >> 2, cb = (t & 3) * 32;
        const float* src = v + (size_t)(b * SEQ + lt * 64 + r) * 1024 + h * CHD + cb;
#pragma unroll
        for (int j = 0; j < 8; j++)
            *(float4*)&tile[r * 132 + cb + j * 4] = *(const float4*)(src + j * 4);
    }
    __syncthreads();

    int j = t >> 1, ib = (t & 1) * 32;
    size_t dst = (size_t)((b * 8 + h) * 128 + j) * 1024 + lt * 64 + ib;
#pragma unroll
    for (int u = 0; u < 4; u++) {
        short8 sh, sl;
#pragma unroll
        for (int e = 0; e < 8; e++) {
            float f = tile[(ib + u * 8 + e) * 132 + j];
            ushort hi = f2bf(f);
            sh[e] = (short)hi;
            sl[e] = (short)f2bf(f - bf2f(hi));
        }
        *(short8*)(vth + dst + u * 8) = sh;
        *(short8*)(vtl + dst + u * 8) = sl;
    }
}

// ---- MFMA flash attention ---------------------------------------------------
__global__ __launch_bounds__(256, 1) void attn_mfma_kernel(
        const ushort* __restrict__ qh_, const ushort* __restrict__ ql_,
        const ushort* __restrict__ kh_, const ushort* __restrict__ kl_,
        const ushort* __restrict__ vth, const ushort* __restrict__ vtl,
        float* __restrict__ o) {
    int qi = blockIdx.x;
    int bh = blockIdx.y;
    int b = bh >> 3, h = bh & 7;
    int t = threadIdx.x;
    int wave = t >> 6, lane = t & 63;
    int lq = lane & 15, lk4 = lane >> 4;

    __shared__ __align__(16) ushort Kh[64 * 128], Kl[64 * 128];
    __shared__ __align__(16) ushort Vh[128 * 64], Vl[128 * 64];
    __shared__ __align__(16) ushort Ph[4][16 * 80], Pl[4][16 * 80];

    int qrow = qi * 64 + wave * 16 + lq;

    short8 qfh[4], qfl[4];
    {
        const ushort* qb = qh_ + (size_t)(b * SEQ + qrow) * 1024 + h * CHD;
        const ushort* qb2 = ql_ + (size_t)(b * SEQ + qrow) * 1024 + h * CHD;
#pragma unroll
        for (int ks = 0; ks < 4; ks++) {
            qfh[ks] = *(const short8*)(qb + ks * 32 + lk4 * 8);
            qfl[ks] = *(const short8*)(qb2 + ks * 32 + lk4 * 8);
        }
    }

    float m_run = -1e30f, l_run = 0.f;
    f32x4 oacc[8];
#pragma unroll
    for (int m = 0; m < 8; m++) oacc[m] = (f32x4){0.f, 0.f, 0.f, 0.f};

    int T = qi + 1;
    for (int kti = 0; kti < T; kti++) {
        __syncthreads();
        {
            int r = t >> 2, cb = (t & 3) * 32;
            const ushort* sh_ = kh_ + (size_t)(b * SEQ + kti * 64 + r) * 1024 + h * CHD + cb;
            const ushort* sl_ = kl_ + (size_t)(b * SEQ + kti * 64 + r) * 1024 + h * CHD + cb;
            int swz = (r & 7) << 3;
#pragma unroll
            for (int j = 0; j < 4; j++) {
                int c8 = cb + j * 8;
                *(short8*)&Kh[r * 128 + (c8 ^ swz)] = *(const short8*)(sh_ + j * 8);
                *(short8*)&Kl[r * 128 + (c8 ^ swz)] = *(const short8*)(sl_ + j * 8);
            }
        }
        {
            int r = t >> 1, cb = (t & 1) * 32;
            const ushort* sh_ = vth + (size_t)((b * 8 + h) * 128 + r) * 1024 + kti * 64 + cb;
            const ushort* sl_ = vtl + (size_t)((b * 8 + h) * 128 + r) * 1024 + kti * 64 + cb;
            int swz = (r & 7) << 3;
#pragma unroll
            for (int j = 0; j < 4; j++) {
                int c8 = cb + j * 8;
                *(short8*)&Vh[r * 64 + (c8 ^ swz)] = *(const short8*)(sh_ + j * 8);
                *(short8*)&Vl[r * 64 + (c8 ^ swz)] = *(const short8*)(sl_ + j * 8);
            }
        }
        __syncthreads();

        f32x4 s[4];
#pragma unroll
        for (int kt = 0; kt < 4; kt++) s[kt] = (f32x4){0.f, 0.f, 0.f, 0.f};
#pragma unroll
        for (int kt = 0; kt < 4; kt++) {
            int rr = kt * 16 + lq;
            int rswz = (rr & 7) << 3;
#pragma unroll
            for (int ks = 0; ks < 4; ks++) {
                int idx = rr * 128 + ((ks * 32 + lk4 * 8) ^ rswz);
                short8 kfh = *(const short8*)&Kh[idx];
                short8 kfl = *(const short8*)&Kl[idx];
                s[kt] = __builtin_amdgcn_mfma_f32_16x16x32_bf16(kfh, qfh[ks], s[kt], 0, 0, 0);
                s[kt] = __builtin_amdgcn_mfma_f32_16x16x32_bf16(kfl, qfh[ks], s[kt], 0, 0, 0);
                s[kt] = __builtin_amdgcn_mfma_f32_16x16x32_bf16(kfh, qfl[ks], s[kt], 0, 0, 0);
            }
        }

        if (kti == qi) {
#pragma unroll
            for (int kt = 0; kt < 4; kt++)
#pragma unroll
                for (int r = 0; r < 4; r++) {
                    int kg = kti * 64 + kt * 16 + lk4 * 4 + r;
                    if (kg > qrow) s[kt][r] = -1e30f;
                }
        }

        float tm = -1e30f;
#pragma unroll
        for (int kt = 0; kt < 4; kt++)
#pragma unroll
            for (int r = 0; r < 4; r++) tm = fmaxf(tm, s[kt][r]);
        tm = fmaxf(tm, __shfl_xor(tm, 16));
        tm = fmaxf(tm, __shfl_xor(tm, 32));
        float mnew = fmaxf(m_run, tm);
        float corr = __expf(m_run - mnew);
        float ts = 0.f;
#pragma unroll
        for (int kt = 0; kt < 4; kt++) {
            float p0 = __expf(s[kt][0] - mnew);
            float p1 = __expf(s[kt][1] - mnew);
            float p2 = __expf(s[kt][2] - mnew);
            float p3 = __expf(s[kt][3] - mnew);
            ts += (p0 + p1) + (p2 + p3);
            short4v hi4, lo4;
            ushort u0 = f2bf(p0); hi4[0] = (short)u0; lo4[0] = (short)f2bf(p0 - bf2f(u0));
            ushort u1 = f2bf(p1); hi4[1] = (short)u1; lo4[1] = (short)f2bf(p1 - bf2f(u1));
            ushort u2 = f2bf(p2); hi4[2] = (short)u2; lo4[2] = (short)f2bf(p2 - bf2f(u2));
            ushort u3 = f2bf(p3); hi4[3] = (short)u3; lo4[3] = (short)f2bf(p3 - bf2f(u3));
            int pidx = lq * 80 + kt * 16 + lk4 * 4;
            *(short4v*)&Ph[wave][pidx] = hi4;
            *(short4v*)&Pl[wave][pidx] = lo4;
        }
        ts += __shfl_xor(ts, 16);
        ts += __shfl_xor(ts, 32);
        l_run = l_run * corr + ts;
        m_run = mnew;
#pragma unroll
        for (int m = 0; m < 8; m++) oacc[m] *= corr;

        short8 pfh[2], pfl[2];
#pragma unroll
        for (int ks = 0; ks < 2; ks++) {
            int pidx = lq * 80 + ks * 32 + lk4 * 8;
            pfh[ks] = *(const short8*)&Ph[wave][pidx];
            pfl[ks] = *(const short8*)&Pl[wave][pidx];
        }
#pragma unroll
        for (int m = 0; m < 8; m++) {
            int vr = m * 16 + lq;
            int vswz = (vr & 7) << 3;
#pragma unroll
            for (int ks = 0; ks < 2; ks++) {
                int idx = vr * 64 + ((ks * 32 + lk4 * 8) ^ vswz);
                short8 vfh = *(const short8*)&Vh[idx];
                short8 vfl = *(const short8*)&Vl[idx];
                oacc[m] = __builtin_amdgcn_mfma_f32_16x16x32_bf16(vfh, pfh[ks], oacc[m], 0, 0, 0);
                oacc[m] = __builtin_amdgcn_mfma_f32_16x16x32_bf16(vfl, pfh[ks], oacc[m], 0, 0, 0);
                oacc[m] = __builtin_amdgcn_mfma_f32_16x16x32_bf16(vfh, pfl[ks], oacc[m], 0, 0, 0);
            }
        }
    }

    float invl = 1.f / l_run;
    float* ob = o + (size_t)(b * SEQ + qrow) * 1024 + h * CHD;
#pragma unroll
    for (int m = 0; m < 8; m++) {
        float4 w;
        w.x = oacc[m][0] * invl; w.y = oacc[m][1] * invl;
        w.z = oacc[m][2] * invl; w.w = oacc[m][3] * invl;
        *(float4*)(ob + m * 16 + lk4 * 4) = w;
    }
}

// ---- MFMA wo-proj + residual + rms2 + Tmix-fold (xmix) ---------------------
// grid 512; block 256 = 4 waves = 4 tokens
__global__ __launch_bounds__(256) void proj_rms_mix_kernel(
        const float* __restrict__ o_in,
        const ushort* __restrict__ woh, const ushort* __restrict__ wol,
        const float* __restrict__ g2, const float* __restrict__ Tmix,
        float* __restrict__ x,
        ushort* __restrict__ xmh_, ushort* __restrict__ xml_) {
    __shared__ float olds[4][1024];
    __shared__ float xnlds[4][1024];
    __shared__ float g2lds[64];
    __shared__ float Ttlds[256];   // Tt[p*16+j] = Tmix[j*16+p]
    int t = threadIdx.x, wave = t >> 6, lane = t & 63;
    int tok = blockIdx.x * 4 + wave;
    if (t < 64) g2lds[t] = g2[t];
    Ttlds[t] = Tmix[(t & 15) * 16 + (t >> 4)];
    {
        const float* src = o_in + (size_t)tok * 1024 + lane * 16;
        float* dst = &olds[wave][lane * 16];
#pragma unroll
        for (int i = 0; i < 4; i++)
            *(float4*)(dst + i * 4) = *(const float4*)(src + i * 4);
    }
    __syncthreads();

    int dn = lane & 15, kg = lane >> 4;
    short8 bfh[2], bfl[2];
#pragma unroll
    for (int ks = 0; ks < 2; ks++) {
        int c0 = ks * 32 + kg * 8;
#pragma unroll
        for (int i = 0; i < 8; i++) {
            float val = olds[wave][(c0 + i) * 16 + dn];
            ushort hi = f2bf(val);
            bfh[ks][i] = (short)hi;
            bfl[ks][i] = (short)f2bf(val - bf2f(hi));
        }
    }

    f32x4 C1[4];
#pragma unroll
    for (int Mt = 0; Mt < 4; Mt++) {
        f32x4 acc = (f32x4){0.f, 0.f, 0.f, 0.f};
#pragma unroll
        for (int ks = 0; ks < 2; ks++) {
            size_t aoff = (size_t)(Mt * 16 + dn) * 64 + ks * 32 + kg * 8;
            short8 ah = *(const short8*)(woh + aoff);
            short8 al = *(const short8*)(wol + aoff);
            acc = __builtin_amdgcn_mfma_f32_16x16x32_bf16(ah, bfh[ks], acc, 0, 0, 0);
            acc = __builtin_amdgcn_mfma_f32_16x16x32_bf16(ah, bfl[ks], acc, 0, 0, 0);
            acc = __builtin_amdgcn_mfma_f32_16x16x32_bf16(al, bfh[ks], acc, 0, 0, 0);
        }
        C1[Mt] = acc;
    }

    float ssum = 0.f;
#pragma unroll
    for (int Mt = 0; Mt < 4; Mt++) {
#pragma unroll
        for (int j = 0; j < 4; j++) {
            int o = Mt * 16 + kg * 4 + j;
            int idx = o * 16 + dn;
            float r = x[(size_t)tok * 1024 + idx] + C1[Mt][j];
            x[(size_t)tok * 1024 + idx] = r;
            xnlds[wave][idx] = r;
            ssum += r * r;
        }
    }
#pragma unroll
    for (int off = 32; off > 0; off >>= 1) ssum += __shfl_xor(ssum, off);
    float inv2 = 1.f / sqrtf(ssum * (1.f / 1024.f) + 1e-6f);
    __syncthreads();

    // xmix[p][c] = inv2*g2[c]*sum_j xn[c][j]*T[j][p]; lane: p=dn, c = kg*16..+16
    const float4* tr = (const float4*)&Ttlds[dn * 16];
    float4 t0 = tr[0], t1 = tr[1], t2 = tr[2], t3 = tr[3];
#pragma unroll
    for (int half = 0; half < 2; half++) {
        short8 xh, xl;
#pragma unroll
        for (int cc = 0; cc < 8; cc++) {
            int c = kg * 16 + half * 8 + cc;
            const float4* xr = (const float4*)&xnlds[wave][c * 16];
            float4 x0 = xr[0], x1 = xr[1], x2 = xr[2], x3 = xr[3];
            float dot = x0.x * t0.x + x0.y * t0.y + x0.z * t0.z + x0.w * t0.w
                      + x1.x * t1.x + x1.y * t1.y + x1.z * t1.z + x1.w * t1.w
                      + x2.x * t2.x + x2.y * t2.y + x2.z * t2.z + x2.w * t2.w
                      + x3.x * t3.x + x3.y * t3.y + x3.z * t3.z + x3.w * t3.w;
            float xm = dot * inv2 * g2lds[c];
            ushort hi = f2bf(xm);
            xh[cc] = (short)hi;
            xl[cc] = (short)f2bf(xm - bf2f(hi));
        }
        size_t oi = (size_t)tok * 1024 + dn * 64 + kg * 16 + half * 8;
        *(short8*)(xmh_ + oi) = xh;
        *(short8*)(xml_ + oi) = xl;
    }
}

// ---- MFMA FFN: up + gelu + down + residual, e-chunked ----------------------
// grid 512; block 256 = 4 waves = 4 tokens
__global__ __launch_bounds__(256) void ffn_mfma_kernel(
        const ushort* __restrict__ xmh_, const ushort* __restrict__ xml_,
        const ushort* __restrict__ uph, const ushort* __restrict__ upl,
        const ushort* __restrict__ dnh, const ushort* __restrict__ dnl,
        float* __restrict__ x) {
    __shared__ ushort xmh[4][16][72], xml[4][16][72];
    __shared__ ushort ghh[4][16][72], ghl[4][16][72];
    int t = threadIdx.x, wave = t >> 6, lane = t & 63;
    int tok = blockIdx.x * 4 + wave;

    {
        int idx = t * 16;                 // 0..4095
        int tt = idx >> 10, rem = idx & 1023;
        int p = rem >> 6, c = rem & 63;
        const ushort* sh = xmh_ + (size_t)(blockIdx.x * 4 + tt) * 1024 + rem;
        const ushort* sl = xml_ + (size_t)(blockIdx.x * 4 + tt) * 1024 + rem;
        *(short8*)&xmh[tt][p][c]     = *(const short8*)(sh);
        *(short8*)&xmh[tt][p][c + 8] = *(const short8*)(sh + 8);
        *(short8*)&xml[tt][p][c]     = *(const short8*)(sl);
        *(short8*)&xml[tt][p][c + 8] = *(const short8*)(sl + 8);
    }
    __syncthreads();

    int p = lane & 15, kg = lane >> 4;
    short8 bxh[2], bxl[2];
#pragma unroll
    for (int ks = 0; ks < 2; ks++) {
        bxh[ks] = *(const short8*)&xmh[wave][p][ks * 32 + kg * 8];
        bxl[ks] = *(const short8*)&xml[wave][p][ks * 32 + kg * 8];
    }

    f32x4 Cout[4];
#pragma unroll
    for (int m = 0; m < 4; m++) Cout[m] = (f32x4){0.f, 0.f, 0.f, 0.f};

    const float kA = 0.7978845608028654f;
#pragma unroll
    for (int ec = 0; ec < 4; ec++) {
        f32x4 accU[4];
#pragma unroll
        for (int mt = 0; mt < 4; mt++) {
            f32x4 acc = (f32x4){0.f, 0.f, 0.f, 0.f};
#pragma unroll
            for (int ks = 0; ks < 2; ks++) {
                size_t aoff = (size_t)(ec * 64 + mt * 16 + p) * 64 + ks * 32 + kg * 8;
                short8 ah = *(const short8*)(uph + aoff);
                short8 al = *(const short8*)(upl + aoff);
                acc = __builtin_amdgcn_mfma_f32_16x16x32_bf16(ah, bxh[ks], acc, 0, 0, 0);
                acc = __builtin_amdgcn_mfma_f32_16x16x32_bf16(ah, bxl[ks], acc, 0, 0, 0);
                acc = __builtin_amdgcn_mfma_f32_16x16x32_bf16(al, bxh[ks], acc, 0, 0, 0);
            }
            accU[mt] = acc;
        }
        __syncthreads();   // previous chunk's ghT fully consumed
#pragma unroll
        for (int mt = 0; mt < 4; mt++) {
#pragma unroll
            for (int j = 0; j < 4; j++) {
                int eloc = mt * 16 + kg * 4 + j;
                float u = accU[mt][j];
                float z = kA * (u + 0.044715f * u * u * u);
                float ex = __expf(2.f * z);
                float gg = u - u * (1.f / (ex + 1.f));
                ushort hi = f2bf(gg);
                ghh[wave][p][eloc] = hi;
                ghl[wave][p][eloc] = f2bf(gg - bf2f(hi));
            }
        }
        __syncthreads();
#pragma unroll
        for (int mto = 0; mto < 4; mto++) {
#pragma unroll
            for (int ks2 = 0; ks2 < 2; ks2++) {
                size_t aoff = (size_t)(mto * 16 + p) * 256 + ec * 64 + ks2 * 32 + kg * 8;
                short8 ah = *(const short8*)(dnh + aoff);
                short8 al = *(const short8*)(dnl + aoff);
                short8 bgh = *(const short8*)&ghh[wave][p][ks2 * 32 + kg * 8];
                short8 bgl = *(const short8*)&ghl[wave][p][ks2 * 32 + kg * 8];
                Cout[mto] = __builtin_amdgcn_mfma_f32_16x16x32_bf16(ah, bgh, Cout[mto], 0, 0, 0);
                Cout[mto] = __builtin_amdgcn_mfma_f32_16x16x32_bf16(ah, bgl, Cout[mto], 0, 0, 0);
                Cout[mto] = __builtin_amdgcn_mfma_f32_16x16x32_bf16(al, bgh, Cout[mto], 0, 0, 0);
            }
        }
    }

#pragma unroll
    for (int mto = 0; mto < 4; mto++) {
#pragma unroll
        for (int j = 0; j < 4; j++) {
            int o = mto * 16 + kg * 4 + j;
            size_t idx = (size_t)tok * 1024 + o * 16 + p;
            x[idx] = x[idx] + Cout[mto][j];
        }
    }
}

// ---- per-layer mixed rotor sandwich matrix Tmix[16][16] --------------------
__global__ void tmix_kernel(const float* __restrict__ rotor_biv,
                            const float* __restrict__ mixw,
                            float* __restrict__ Tmix) {
    int lay = blockIdx.x;
    __shared__ float rot[NK][D16];
    __shared__ float w[NK];
    int t = threadIdx.x;
    if (t < NK) {
        const int BIV[6] = { 3, 5, 6, 9, 10, 12 };
        float r[D16];
#pragma unroll
        for (int j = 0; j < D16; j++) r[j] = 0.f;
        r[0] = 1.f;
        float nrm = 1.f;
        for (int i = 0; i < 6; i++) {
            float bv = rotor_biv[(lay * NK + t) * 6 + i];
            r[BIV[i]] = bv; nrm += bv * bv;
        }
        nrm = sqrtf(nrm);
        for (int j = 0; j < D16; j++) rot[t][j] = r[j] / nrm;
    }
    if (t == 0) {
        float mx = -INFINITY;
        for (int kk = 0; kk < NK; kk++) mx = fmaxf(mx, mixw[lay * NK + kk]);
        float s = 0.f, e[NK];
        for (int kk = 0; kk < NK; kk++) { e[kk] = expf(mixw[lay * NK + kk] - mx); s += e[kk]; }
        for (int kk = 0; kk < NK; kk++) w[kk] = e[kk] / s;
    }
    __syncthreads();
    int j = t >> 4, p = t & 15;
    float acc = 0.f;
    for (int kk = 0; kk < NK; kk++) {
        float tk = 0.f;
        for (int i = 0; i < D16; i++) {
            int n = i ^ j ^ p;
            float rn = rot[kk][n] * rev_sign(n);
            tk += rot[kk][i] * rn * gp_sign(i, j) * gp_sign(i ^ j, n);
        }
        acc += w[kk] * tk;
    }
    Tmix[lay * 256 + t] = acc;
}

// ---- final norm + blade gate + grade-0; emit bf16 hi/lo --------------------
__global__ void g0_kernel(const float* __restrict__ x,
                          const float* __restrict__ g,
                          const float* __restrict__ sel,
                          ushort* __restrict__ g0h,
                          ushort* __restrict__ g0l) {
    int bl = blockIdx.x;
    const float* xr = x + (size_t)bl * 1024;
    __shared__ float red[256];
    float s = 0.f;
    for (int i = threadIdx.x; i < 1024; i += 256) { float v = xr[i]; s += v * v; }
    red[threadIdx.x] = s; __syncthreads();
    for (int st = 128; st > 0; st >>= 1) {
        if (threadIdx.x < st) red[threadIdx.x] += red[threadIdx.x + st];
        __syncthreads();
    }
    float inv = 1.f / sqrtf(red[0] * (1.f / 1024.f) + 1e-6f);
    if (threadIdx.x < NC) {
        int c = threadIdx.x;
        float gate = 1.f / (1.f + expf(-sel[c * D16]));
        float val = xr[c * D16] * inv * g[c] * gate;
        ushort hi = f2bf(val);
        g0h[(size_t)bl * NC + c] = hi;
        g0l[(size_t)bl * NC + c] = f2bf(val - bf2f(hi));
    }
}

// ---- head_w split into bf16 hi/lo ------------------------------------------
__global__ void split_hw(const float* __restrict__ hw,
                         ushort* __restrict__ hwh,
                         ushort* __restrict__ hwl) {
    int idx = blockIdx.x * blockDim.x + threadIdx.x;
    if (idx >= VOCAB * NC) return;
    float f = hw[idx];
    ushort hi = f2bf(f);
    hwh[idx] = hi;
    hwl[idx] = f2bf(f - bf2f(hi));
}

// ---- head GEMM via bf16-split MFMA + LDS stage + nontemporal stores --------
__global__ __launch_bounds__(256) void head_mfma_kernel(
        const ushort* __restrict__ g0h, const ushort* __restrict__ g0l,
        const ushort* __restrict__ hwh, const ushort* __restrict__ hwl,
        const float* __restrict__ hb, float* __restrict__ out) {
    int t = threadIdx.x;
    int wave = t >> 6, lane = t & 63;
    int lr = lane & 15, lk = lane >> 4;
    int rowbase = blockIdx.y * 64 + wave * 16;
    int vbase = blockIdx.x * 64;

    __shared__ float tile[64 * 68];

    short8 ah[2], al[2];
#pragma unroll
    for (int ks = 0; ks < 2; ks++) {
        size_t off = (size_t)(rowbase + lr) * NC + ks * 32 + lk * 8;
        ah[ks] = *(const short8*)(g0h + off);
        al[ks] = *(const short8*)(g0l + off);
    }
    f32x4 acc[4];
#pragma unroll
    for (int nt = 0; nt < 4; nt++) acc[nt] = (f32x4){0.f, 0.f, 0.f, 0.f};

#pragma unroll
    for (int ks = 0; ks < 2; ks++) {
#pragma unroll
        for (int nt = 0; nt < 4; nt++) {
            size_t boff = (size_t)(vbase + nt * 16 + lr) * NC + ks * 32 + lk * 8;
            short8 bh = *(const short8*)(hwh + boff);
            short8 bl = *(const short8*)(hwl + boff);
            acc[nt] = __builtin_amdgcn_mfma_f32_16x16x32_bf16(ah[ks], bh, acc[nt], 0, 0, 0);
            acc[nt] = __builtin_amdgcn_mfma_f32_16x16x32_bf16(ah[ks], bl, acc[nt], 0, 0, 0);
            acc[nt] = __builtin_amdgcn_mfma_f32_16x16x32_bf16(al[ks], bh, acc[nt], 0, 0, 0);
        }
    }

#pragma unroll
    for (int nt = 0; nt < 4; nt++)
#pragma unroll
        for (int r = 0; r < 4; r++)
            tile[(wave * 16 + lk * 4 + r) * 68 + nt * 16 + lr] = acc[nt][r];
    __syncthreads();

    int col4 = t & 15, rw = t >> 4;
    float4 bias4 = *(const float4*)(hb + vbase + col4 * 4);
#pragma unroll
    for (int iter = 0; iter < 4; iter++) {
        int row = iter * 16 + rw;
        float4 vv = *(const float4*)&tile[row * 68 + col4 * 4];
        f32x4 sv;
        sv[0] = vv.x + bias4.x; sv[1] = vv.y + bias4.y;
        sv[2] = vv.z + bias4.z; sv[3] = vv.w + bias4.w;
        __builtin_nontemporal_store(sv,
            (f32x4*)(out + (size_t)(blockIdx.y * 64 + row) * VOCAB + vbase + col4 * 4));
    }
}

extern "C" void kernel_launch(void* const* d_in, const int* in_sizes, int n_in,
                              void* d_out, int out_size, void* d_ws, size_t ws_size,
                              hipStream_t stream) {
    (void)in_sizes; (void)n_in; (void)out_size; (void)ws_size;
    const int*   tok      = (const int*)  d_in[0];
    const float* embed    = (const float*)d_in[1];
    const float* ln1_g    = (const float*)d_in[2];
    const float* ln2_g    = (const float*)d_in[3];
    const float* wq       = (const float*)d_in[4];
    const float* wk       = (const float*)d_in[5];
    const float* wv       = (const float*)d_in[6];
    const float* wo       = (const float*)d_in[7];
    const float* ffn_up   = (const float*)d_in[8];
    const float* ffn_down = (const float*)d_in[9];
    const float* rotor    = (const float*)d_in[10];
    const float* mixw     = (const float*)d_in[11];
    const float* out_ln_g = (const float*)d_in[12];
    const float* sel      = (const float*)d_in[13];
    const float* head_w   = (const float*)d_in[14];
    const float* head_b   = (const float*)d_in[15];
    float* out = (float*)d_out;

    float* ws  = (float*)d_ws;
    float* x    = ws;                         // 2,097,152 f
    float* o    = x + 2097152;                // 2,097,152 f
    float* vbuf = o + 2097152;                // 2,097,152 f
    float* Tmx  = vbuf + 2097152;             // 512 f
    ushort* qh   = (ushort*)(Tmx + 512);      // 2,097,152 us each
    ushort* ql   = qh + 2097152;
    ushort* kh   = ql + 2097152;
    ushort* kl   = kh + 2097152;
    ushort* vth  = kl + 2097152;
    ushort* vtl  = vth + 2097152;
    ushort* xmh  = vtl + 2097152;             // 2,097,152
    ushort* xml  = xmh + 2097152;
    ushort* g0h  = xml + 2097152;             // 131,072
    ushort* g0l  = g0h + 131072;
    ushort* hwh  = g0l + 131072;              // 2,048,000
    ushort* hwl  = hwh + 2048000;
    ushort* wsp  = hwl + 2048000;             // 196,608

    embed_pe_kernel<<<(BATCH * SEQ * NC + 255) / 256, 256, 0, stream>>>(tok, embed, x);
    tmix_kernel<<<NLAY, 256, 0, stream>>>(rotor, mixw, Tmx);
    split_hw<<<(VOCAB * NC + 255) / 256, 256, 0, stream>>>(head_w, hwh, hwl);
    split_lw<<<384, 256, 0, stream>>>(wq, wk, wv, wo, ffn_up, ffn_down, wsp);

    for (int l = 0; l < NLAY; l++) {
        int lo = l * 4096;
        int le = l * 16384;
        qkv_mfma_kernel<<<512, 256, 0, stream>>>(
            x, ln1_g + l * NC,
            wsp + lo, wsp + 8192 + lo, wsp + 16384 + lo, wsp + 24576 + lo,
            wsp + 32768 + lo, wsp + 40960 + lo,
            qh, ql, kh, kl, vbuf);
        dim3 vg(16, 16);
        vtrans_kernel<<<vg, 256, 0, stream>>>(vbuf, vth, vtl);
        dim3 ag(16, 16);
        attn_mfma_kernel<<<ag, 256, 0, stream>>>(qh, ql, kh, kl, vth, vtl, o);
        proj_rms_mix_kernel<<<512, 256, 0, stream>>>(
            o, wsp + 49152 + lo, wsp + 57344 + lo,
            ln2_g + l * NC, Tmx + l * 256, x, xmh, xml);
        ffn_mfma_kernel<<<512, 256, 0, stream>>>(
            xmh, xml,
            wsp + 65536 + le, wsp + 98304 + le,
            wsp + 131072 + le, wsp + 163840 + le, x);
    }

    g0_kernel<<<BATCH * SEQ, 256, 0, stream>>>(x, out_ln_g, sel, g0h, g0l);
    dim3 hg(VOCAB / 64, (BATCH * SEQ) / 64);   // (500, 32)
    head_mfma_kernel<<<hg, 256, 0, stream>>>(g0h, g0l, hwh, hwl, head_b, out);
}

// Round 12
// 426.531 us; speedup vs baseline: 2.8163x; 1.0488x over previous
//
#include <hip/hip_runtime.h>
#include <hip/hip_bf16.h>
#include <math.h>

#define D16   16
#define NC    64      // channels C
#define NH    8       // heads
#define CHD   128     // (C/H)*D = 8*16
#define NLAY  2
#define CEXP  256     // C*FM
#define NK    8       // rotors
#define SEQ   1024
#define BATCH 2
#define VOCAB 32000

typedef unsigned short ushort;
typedef __attribute__((ext_vector_type(8))) short short8;
typedef __attribute__((ext_vector_type(4))) short short4v;
typedef __attribute__((ext_vector_type(4))) float f32x4;

// ---- Cl(3,1) sign helpers --------------------------------------------------
__device__ __forceinline__ float gp_sign(int a, int b) {
    int t = a >> 1, tot = 0;
    while (t) { tot += __popc(t & b); t >>= 1; }
    int neg = tot & 1;
    if ((a & b) & 8) neg ^= 1;   // METRIC[3] = -1
    return neg ? -1.f : 1.f;
}
__device__ __forceinline__ float rev_sign(int j) {
    int g = __popc(j);
    return ((g * (g - 1) / 2) & 1) ? -1.f : 1.f;
}
__device__ __forceinline__ ushort f2bf(float f) {
    unsigned int u = __float_as_uint(f);
    unsigned int r = (u + 0x7FFFu + ((u >> 16) & 1u)) >> 16;
    return (ushort)r;
}
__device__ __forceinline__ float bf2f(ushort h) {
    return __uint_as_float((unsigned int)h << 16);
}

// ---- embed gather + rotary bivector PE -------------------------------------
__global__ void embed_pe_kernel(const int* __restrict__ tok,
                                const float* __restrict__ embed,
                                float* __restrict__ x) {
    int idx = blockIdx.x * blockDim.x + threadIdx.x;
    if (idx >= BATCH * SEQ * NC) return;
    int c  = idx & (NC - 1);
    int bl = idx / NC;
    int l  = bl & (SEQ - 1);
    int t  = tok[bl];

    const float* e = embed + ((size_t)t * NC + c) * D16;
    float v[D16];
#pragma unroll
    for (int j = 0; j < D16; j++) v[j] = e[j];

    float freq = exp2f(-(float)c * (13.287712379549449f / (float)NC));
    float theta = (float)l * freq;
    float sn, cs;
    __sincosf(theta, &sn, &cs);

    float tmp[D16], out[D16];
#pragma unroll
    for (int k = 0; k < D16; k++)
        tmp[k] = cs * v[k] + sn * gp_sign(3, 3 ^ k) * v[3 ^ k];
#pragma unroll
    for (int k = 0; k < D16; k++)
        out[k] = cs * tmp[k] - sn * gp_sign(k ^ 3, 3) * tmp[k ^ 3];

    float* xp = x + (size_t)idx * D16;
#pragma unroll
    for (int j = 0; j < D16; j++) xp[j] = out[j];
}

// ---- split layer weights into bf16 hi/lo -----------------------------------
__global__ void split_lw(const float* __restrict__ wq, const float* __restrict__ wk,
                         const float* __restrict__ wv, const float* __restrict__ wo,
                         const float* __restrict__ up, const float* __restrict__ dn,
                         ushort* __restrict__ wsp) {
    int idx = blockIdx.x * 256 + threadIdx.x;
    if (idx >= 98304) return;
    const float* src; ushort *dh, *dl; int off;
    if (idx < 8192)       { src = wq; off = idx;         dh = wsp;          dl = wsp + 8192; }
    else if (idx < 16384) { src = wk; off = idx - 8192;  dh = wsp + 16384;  dl = wsp + 24576; }
    else if (idx < 24576) { src = wv; off = idx - 16384; dh = wsp + 32768;  dl = wsp + 40960; }
    else if (idx < 32768) { src = wo; off = idx - 24576; dh = wsp + 49152;  dl = wsp + 57344; }
    else if (idx < 65536) { src = up; off = idx - 32768; dh = wsp + 65536;  dl = wsp + 98304; }
    else                  { src = dn; off = idx - 65536; dh = wsp + 131072; dl = wsp + 163840; }
    float f = src[off];
    ushort hi = f2bf(f);
    dh[off] = hi;
    dl[off] = f2bf(f - bf2f(hi));
}

// ---- MFMA qkv: per-token [64o x 64c] x [64c x 16d]; CLN fused --------------
__global__ __launch_bounds__(256) void qkv_mfma_kernel(
        const float* __restrict__ x, const float* __restrict__ g,
        const ushort* __restrict__ wqh, const ushort* __restrict__ wql,
        const ushort* __restrict__ wkh, const ushort* __restrict__ wkl,
        const ushort* __restrict__ wvh, const ushort* __restrict__ wvl,
        ushort* __restrict__ qh_, ushort* __restrict__ ql_,
        ushort* __restrict__ kh_, ushort* __restrict__ kl_,
        float* __restrict__ v) {
    __shared__ float xlds[4][1024];
    __shared__ float glds[64];
    int t = threadIdx.x, wave = t >> 6, lane = t & 63;
    int tok = blockIdx.x * 4 + wave;
    if (t < 64) glds[t] = g[t];
    float ssum = 0.f;
    {
        const float* src = x + (size_t)tok * 1024 + lane * 16;
        float* dst = &xlds[wave][lane * 16];
#pragma unroll
        for (int i = 0; i < 4; i++) {
            float4 vv = *(const float4*)(src + i * 4);
            *(float4*)(dst + i * 4) = vv;
            ssum += vv.x * vv.x + vv.y * vv.y + vv.z * vv.z + vv.w * vv.w;
        }
    }
#pragma unroll
    for (int off = 32; off > 0; off >>= 1) ssum += __shfl_xor(ssum, off);
    float inv = 1.f / sqrtf(ssum * (1.f / 1024.f) + 1e-6f);
    __syncthreads();

    int dn = lane & 15, kg = lane >> 4;
    short8 bfh[2], bfl[2];
#pragma unroll
    for (int ks = 0; ks < 2; ks++) {
        int c0 = ks * 32 + kg * 8;
#pragma unroll
        for (int i = 0; i < 8; i++) {
            float val = xlds[wave][(c0 + i) * 16 + dn] * inv * glds[c0 + i];
            ushort hi = f2bf(val);
            bfh[ks][i] = (short)hi;
            bfl[ks][i] = (short)f2bf(val - bf2f(hi));
        }
    }
    float gs = gp_sign(dn, dn) * 0.088388347648318447f;

    const ushort* Wh[3] = { wqh, wkh, wvh };
    const ushort* Wl[3] = { wql, wkl, wvl };
#pragma unroll
    for (int m = 0; m < 3; m++) {
#pragma unroll
        for (int Mt = 0; Mt < 4; Mt++) {
            f32x4 acc = (f32x4){0.f, 0.f, 0.f, 0.f};
#pragma unroll
            for (int ks = 0; ks < 2; ks++) {
                size_t aoff = (size_t)(Mt * 16 + dn) * 64 + ks * 32 + kg * 8;
                short8 ah = *(const short8*)(Wh[m] + aoff);
                short8 al = *(const short8*)(Wl[m] + aoff);
                acc = __builtin_amdgcn_mfma_f32_16x16x32_bf16(ah, bfh[ks], acc, 0, 0, 0);
                acc = __builtin_amdgcn_mfma_f32_16x16x32_bf16(ah, bfl[ks], acc, 0, 0, 0);
                acc = __builtin_amdgcn_mfma_f32_16x16x32_bf16(al, bfh[ks], acc, 0, 0, 0);
            }
#pragma unroll
            for (int j = 0; j < 4; j++) {
                int o = Mt * 16 + kg * 4 + j;
                size_t oi = (size_t)tok * 1024 + o * 16 + dn;
                if (m == 0) {
                    float qv = acc[j] * gs;
                    ushort hi = f2bf(qv);
                    qh_[oi] = hi; ql_[oi] = f2bf(qv - bf2f(hi));
                } else if (m == 1) {
                    ushort hi = f2bf(acc[j]);
                    kh_[oi] = hi; kl_[oi] = f2bf(acc[j] - bf2f(hi));
                } else {
                    v[oi] = acc[j];
                }
            }
        }
    }
}

// ---- V transpose + bf16 split ----------------------------------------------
__global__ __launch_bounds__(256) void vtrans_kernel(
        const float* __restrict__ v,
        ushort* __restrict__ vth, ushort* __restrict__ vtl) {
    int bh = blockIdx.x;
    int lt = blockIdx.y;
    int b = bh >> 3, h = bh & 7;
    int t = threadIdx.x;
    __shared__ float tile[64 * 132];

    {
        int r = t >> 2, cb = (t & 3) * 32;
        const float* src = v + (size_t)(b * SEQ + lt * 64 + r) * 1024 + h * CHD + cb;
#pragma unroll
        for (int j = 0; j < 8; j++)
            *(float4*)&tile[r * 132 + cb + j * 4] = *(const float4*)(src + j * 4);
    }
    __syncthreads();

    int j = t >> 1, ib = (t & 1) * 32;
    size_t dst = (size_t)((b * 8 + h) * 128 + j) * 1024 + lt * 64 + ib;
#pragma unroll
    for (int u = 0; u < 4; u++) {
        short8 sh, sl;
#pragma unroll
        for (int e = 0; e < 8; e++) {
            float f = tile[(ib + u * 8 + e) * 132 + j];
            ushort hi = f2bf(f);
            sh[e] = (short)hi;
            sl[e] = (short)f2bf(f - bf2f(hi));
        }
        *(short8*)(vth + dst + u * 8) = sh;
        *(short8*)(vtl + dst + u * 8) = sl;
    }
}

// ---- MFMA flash attention with T14 register prefetch of next K/V tile ------
__global__ __launch_bounds__(256, 1) void attn_mfma_kernel(
        const ushort* __restrict__ qh_, const ushort* __restrict__ ql_,
        const ushort* __restrict__ kh_, const ushort* __restrict__ kl_,
        const ushort* __restrict__ vth, const ushort* __restrict__ vtl,
        float* __restrict__ o) {
    int qi = blockIdx.x;
    int bh = blockIdx.y;
    int b = bh >> 3, h = bh & 7;
    int t = threadIdx.x;
    int wave = t >> 6, lane = t & 63;
    int lq = lane & 15, lk4 = lane >> 4;

    __shared__ __align__(16) ushort Kh[64 * 128], Kl[64 * 128];
    __shared__ __align__(16) ushort Vh[128 * 64], Vl[128 * 64];
    __shared__ __align__(16) ushort Ph[4][16 * 80], Pl[4][16 * 80];

    int qrow = qi * 64 + wave * 16 + lq;

    short8 qfh[4], qfl[4];
    {
        const ushort* qb = qh_ + (size_t)(b * SEQ + qrow) * 1024 + h * CHD;
        const ushort* qb2 = ql_ + (size_t)(b * SEQ + qrow) * 1024 + h * CHD;
#pragma unroll
        for (int ks = 0; ks < 4; ks++) {
            qfh[ks] = *(const short8*)(qb + ks * 32 + lk4 * 8);
            qfl[ks] = *(const short8*)(qb2 + ks * 32 + lk4 * 8);
        }
    }

    // staging thread-geometry
    int kr = t >> 2, kcb = (t & 3) * 32;      // K: row, col-base
    int vr = t >> 1, vcb = (t & 1) * 32;      // V^T: row, col-base
    int kswz = (kr & 7) << 3, vswz = (vr & 7) << 3;

    short8 pk_h[4], pk_l[4], pv_h[4], pv_l[4];   // prefetch regs

    // prefetch tile 0
    {
        const ushort* sh_ = kh_ + (size_t)(b * SEQ + kr) * 1024 + h * CHD + kcb;
        const ushort* sl_ = kl_ + (size_t)(b * SEQ + kr) * 1024 + h * CHD + kcb;
#pragma unroll
        for (int j = 0; j < 4; j++) {
            pk_h[j] = *(const short8*)(sh_ + j * 8);
            pk_l[j] = *(const short8*)(sl_ + j * 8);
        }
        const ushort* vh_ = vth + (size_t)((b * 8 + h) * 128 + vr) * 1024 + vcb;
        const ushort* vl_ = vtl + (size_t)((b * 8 + h) * 128 + vr) * 1024 + vcb;
#pragma unroll
        for (int j = 0; j < 4; j++) {
            pv_h[j] = *(const short8*)(vh_ + j * 8);
            pv_l[j] = *(const short8*)(vl_ + j * 8);
        }
    }

    float m_run = -1e30f, l_run = 0.f;
    f32x4 oacc[8];
#pragma unroll
    for (int m = 0; m < 8; m++) oacc[m] = (f32x4){0.f, 0.f, 0.f, 0.f};

    int T = qi + 1;
    for (int kti = 0; kti < T; kti++) {
        __syncthreads();   // prev tile's LDS consumers done
        // regs -> LDS (swizzled)
#pragma unroll
        for (int j = 0; j < 4; j++) {
            int c8 = kcb + j * 8;
            *(short8*)&Kh[kr * 128 + (c8 ^ kswz)] = pk_h[j];
            *(short8*)&Kl[kr * 128 + (c8 ^ kswz)] = pk_l[j];
        }
#pragma unroll
        for (int j = 0; j < 4; j++) {
            int c8 = vcb + j * 8;
            *(short8*)&Vh[vr * 64 + (c8 ^ vswz)] = pv_h[j];
            *(short8*)&Vl[vr * 64 + (c8 ^ vswz)] = pv_l[j];
        }
        __syncthreads();

        // prefetch next tile (overlaps with MFMA below)
        if (kti + 1 < T) {
            const ushort* sh_ = kh_ + (size_t)(b * SEQ + (kti + 1) * 64 + kr) * 1024 + h * CHD + kcb;
            const ushort* sl_ = kl_ + (size_t)(b * SEQ + (kti + 1) * 64 + kr) * 1024 + h * CHD + kcb;
#pragma unroll
            for (int j = 0; j < 4; j++) {
                pk_h[j] = *(const short8*)(sh_ + j * 8);
                pk_l[j] = *(const short8*)(sl_ + j * 8);
            }
            const ushort* vh_ = vth + (size_t)((b * 8 + h) * 128 + vr) * 1024 + (kti + 1) * 64 + vcb;
            const ushort* vl_ = vtl + (size_t)((b * 8 + h) * 128 + vr) * 1024 + (kti + 1) * 64 + vcb;
#pragma unroll
            for (int j = 0; j < 4; j++) {
                pv_h[j] = *(const short8*)(vh_ + j * 8);
                pv_l[j] = *(const short8*)(vl_ + j * 8);
            }
        }

        f32x4 s[4];
#pragma unroll
        for (int kt = 0; kt < 4; kt++) s[kt] = (f32x4){0.f, 0.f, 0.f, 0.f};
#pragma unroll
        for (int kt = 0; kt < 4; kt++) {
            int rr = kt * 16 + lq;
            int rswz = (rr & 7) << 3;
#pragma unroll
            for (int ks = 0; ks < 4; ks++) {
                int idx = rr * 128 + ((ks * 32 + lk4 * 8) ^ rswz);
                short8 kfh = *(const short8*)&Kh[idx];
                short8 kfl = *(const short8*)&Kl[idx];
                s[kt] = __builtin_amdgcn_mfma_f32_16x16x32_bf16(kfh, qfh[ks], s[kt], 0, 0, 0);
                s[kt] = __builtin_amdgcn_mfma_f32_16x16x32_bf16(kfl, qfh[ks], s[kt], 0, 0, 0);
                s[kt] = __builtin_amdgcn_mfma_f32_16x16x32_bf16(kfh, qfl[ks], s[kt], 0, 0, 0);
            }
        }

        if (kti == qi) {
#pragma unroll
            for (int kt = 0; kt < 4; kt++)
#pragma unroll
                for (int r = 0; r < 4; r++) {
                    int kg = kti * 64 + kt * 16 + lk4 * 4 + r;
                    if (kg > qrow) s[kt][r] = -1e30f;
                }
        }

        float tm = -1e30f;
#pragma unroll
        for (int kt = 0; kt < 4; kt++)
#pragma unroll
            for (int r = 0; r < 4; r++) tm = fmaxf(tm, s[kt][r]);
        tm = fmaxf(tm, __shfl_xor(tm, 16));
        tm = fmaxf(tm, __shfl_xor(tm, 32));
        float mnew = fmaxf(m_run, tm);
        float corr = __expf(m_run - mnew);
        float ts = 0.f;
#pragma unroll
        for (int kt = 0; kt < 4; kt++) {
            float p0 = __expf(s[kt][0] - mnew);
            float p1 = __expf(s[kt][1] - mnew);
            float p2 = __expf(s[kt][2] - mnew);
            float p3 = __expf(s[kt][3] - mnew);
            ts += (p0 + p1) + (p2 + p3);
            short4v hi4, lo4;
            ushort u0 = f2bf(p0); hi4[0] = (short)u0; lo4[0] = (short)f2bf(p0 - bf2f(u0));
            ushort u1 = f2bf(p1); hi4[1] = (short)u1; lo4[1] = (short)f2bf(p1 - bf2f(u1));
            ushort u2 = f2bf(p2); hi4[2] = (short)u2; lo4[2] = (short)f2bf(p2 - bf2f(u2));
            ushort u3 = f2bf(p3); hi4[3] = (short)u3; lo4[3] = (short)f2bf(p3 - bf2f(u3));
            int pidx = lq * 80 + kt * 16 + lk4 * 4;
            *(short4v*)&Ph[wave][pidx] = hi4;
            *(short4v*)&Pl[wave][pidx] = lo4;
        }
        ts += __shfl_xor(ts, 16);
        ts += __shfl_xor(ts, 32);
        l_run = l_run * corr + ts;
        m_run = mnew;
#pragma unroll
        for (int m = 0; m < 8; m++) oacc[m] *= corr;

        short8 pfh[2], pfl[2];
#pragma unroll
        for (int ks = 0; ks < 2; ks++) {
            int pidx = lq * 80 + ks * 32 + lk4 * 8;
            pfh[ks] = *(const short8*)&Ph[wave][pidx];
            pfl[ks] = *(const short8*)&Pl[wave][pidx];
        }
#pragma unroll
        for (int m = 0; m < 8; m++) {
            int vrr = m * 16 + lq;
            int vsw = (vrr & 7) << 3;
#pragma unroll
            for (int ks = 0; ks < 2; ks++) {
                int idx = vrr * 64 + ((ks * 32 + lk4 * 8) ^ vsw);
                short8 vfh = *(const short8*)&Vh[idx];
                short8 vfl = *(const short8*)&Vl[idx];
                oacc[m] = __builtin_amdgcn_mfma_f32_16x16x32_bf16(vfh, pfh[ks], oacc[m], 0, 0, 0);
                oacc[m] = __builtin_amdgcn_mfma_f32_16x16x32_bf16(vfl, pfh[ks], oacc[m], 0, 0, 0);
                oacc[m] = __builtin_amdgcn_mfma_f32_16x16x32_bf16(vfh, pfl[ks], oacc[m], 0, 0, 0);
            }
        }
    }

    float invl = 1.f / l_run;
    float* ob = o + (size_t)(b * SEQ + qrow) * 1024 + h * CHD;
#pragma unroll
    for (int m = 0; m < 8; m++) {
        float4 w;
        w.x = oacc[m][0] * invl; w.y = oacc[m][1] * invl;
        w.z = oacc[m][2] * invl; w.w = oacc[m][3] * invl;
        *(float4*)(ob + m * 16 + lk4 * 4) = w;
    }
}

// ---- fused MFMA: wo-proj + residual + rms2 + Tmix-fold + FFN + residual ----
// grid 512; block 256 = 4 waves = 4 tokens
__global__ __launch_bounds__(256) void proj_ffn_mfma_kernel(
        const float* __restrict__ o_in,
        const ushort* __restrict__ woh, const ushort* __restrict__ wol,
        const float* __restrict__ g2, const float* __restrict__ Tmix,
        const ushort* __restrict__ uph, const ushort* __restrict__ upl,
        const ushort* __restrict__ dnh, const ushort* __restrict__ dnl,
        float* __restrict__ x) {
    __shared__ float olds[4][1024];
    __shared__ float xnlds[4][1024];
    __shared__ float g2lds[64];
    __shared__ float Ttlds[256];   // Tt[p*16+j] = Tmix[j*16+p]
    __shared__ ushort xmh[4][16][72], xml[4][16][72];
    __shared__ ushort ghh[4][16][72], ghl[4][16][72];
    int t = threadIdx.x, wave = t >> 6, lane = t & 63;
    int tok = blockIdx.x * 4 + wave;
    if (t < 64) g2lds[t] = g2[t];
    Ttlds[t] = Tmix[(t & 15) * 16 + (t >> 4)];
    {
        const float* src = o_in + (size_t)tok * 1024 + lane * 16;
        float* dst = &olds[wave][lane * 16];
#pragma unroll
        for (int i = 0; i < 4; i++)
            *(float4*)(dst + i * 4) = *(const float4*)(src + i * 4);
    }
    __syncthreads();

    int dn = lane & 15, kg = lane >> 4;
    short8 bfh[2], bfl[2];
#pragma unroll
    for (int ks = 0; ks < 2; ks++) {
        int c0 = ks * 32 + kg * 8;
#pragma unroll
        for (int i = 0; i < 8; i++) {
            float val = olds[wave][(c0 + i) * 16 + dn];
            ushort hi = f2bf(val);
            bfh[ks][i] = (short)hi;
            bfl[ks][i] = (short)f2bf(val - bf2f(hi));
        }
    }

    f32x4 C1[4];
#pragma unroll
    for (int Mt = 0; Mt < 4; Mt++) {
        f32x4 acc = (f32x4){0.f, 0.f, 0.f, 0.f};
#pragma unroll
        for (int ks = 0; ks < 2; ks++) {
            size_t aoff = (size_t)(Mt * 16 + dn) * 64 + ks * 32 + kg * 8;
            short8 ah = *(const short8*)(woh + aoff);
            short8 al = *(const short8*)(wol + aoff);
            acc = __builtin_amdgcn_mfma_f32_16x16x32_bf16(ah, bfh[ks], acc, 0, 0, 0);
            acc = __builtin_amdgcn_mfma_f32_16x16x32_bf16(ah, bfl[ks], acc, 0, 0, 0);
            acc = __builtin_amdgcn_mfma_f32_16x16x32_bf16(al, bfh[ks], acc, 0, 0, 0);
        }
        C1[Mt] = acc;
    }

    float ssum = 0.f;
#pragma unroll
    for (int Mt = 0; Mt < 4; Mt++) {
#pragma unroll
        for (int j = 0; j < 4; j++) {
            int o = Mt * 16 + kg * 4 + j;
            int idx = o * 16 + dn;
            float r = x[(size_t)tok * 1024 + idx] + C1[Mt][j];
            x[(size_t)tok * 1024 + idx] = r;
            xnlds[wave][idx] = r;
            ssum += r * r;
        }
    }
#pragma unroll
    for (int off = 32; off > 0; off >>= 1) ssum += __shfl_xor(ssum, off);
    float inv2 = 1.f / sqrtf(ssum * (1.f / 1024.f) + 1e-6f);
    __syncthreads();

    // xmix[p][c] = inv2*g2[c]*sum_j xn[c][j]*T[j][p] -> LDS (bf16 hi/lo)
    const float4* tr = (const float4*)&Ttlds[dn * 16];
    float4 t0 = tr[0], t1 = tr[1], t2 = tr[2], t3 = tr[3];
#pragma unroll
    for (int half = 0; half < 2; half++) {
        short8 xh, xl;
#pragma unroll
        for (int cc = 0; cc < 8; cc++) {
            int c = kg * 16 + half * 8 + cc;
            const float4* xr = (const float4*)&xnlds[wave][c * 16];
            float4 x0 = xr[0], x1 = xr[1], x2 = xr[2], x3 = xr[3];
            float dot = x0.x * t0.x + x0.y * t0.y + x0.z * t0.z + x0.w * t0.w
                      + x1.x * t1.x + x1.y * t1.y + x1.z * t1.z + x1.w * t1.w
                      + x2.x * t2.x + x2.y * t2.y + x2.z * t2.z + x2.w * t2.w
                      + x3.x * t3.x + x3.y * t3.y + x3.z * t3.z + x3.w * t3.w;
            float xm = dot * inv2 * g2lds[c];
            ushort hi = f2bf(xm);
            xh[cc] = (short)hi;
            xl[cc] = (short)f2bf(xm - bf2f(hi));
        }
        *(short8*)&xmh[wave][dn][kg * 16 + half * 8] = xh;
        *(short8*)&xml[wave][dn][kg * 16 + half * 8] = xl;
    }
    __syncthreads();

    // ---- FFN: up + gelu + down, e-chunked ----
    int p = dn;
    short8 bxh[2], bxl[2];
#pragma unroll
    for (int ks = 0; ks < 2; ks++) {
        bxh[ks] = *(const short8*)&xmh[wave][p][ks * 32 + kg * 8];
        bxl[ks] = *(const short8*)&xml[wave][p][ks * 32 + kg * 8];
    }

    f32x4 Cout[4];
#pragma unroll
    for (int m = 0; m < 4; m++) Cout[m] = (f32x4){0.f, 0.f, 0.f, 0.f};

    const float kA = 0.7978845608028654f;
#pragma unroll
    for (int ec = 0; ec < 4; ec++) {
        f32x4 accU[4];
#pragma unroll
        for (int mt = 0; mt < 4; mt++) {
            f32x4 acc = (f32x4){0.f, 0.f, 0.f, 0.f};
#pragma unroll
            for (int ks = 0; ks < 2; ks++) {
                size_t aoff = (size_t)(ec * 64 + mt * 16 + p) * 64 + ks * 32 + kg * 8;
                short8 ah = *(const short8*)(uph + aoff);
                short8 al = *(const short8*)(upl + aoff);
                acc = __builtin_amdgcn_mfma_f32_16x16x32_bf16(ah, bxh[ks], acc, 0, 0, 0);
                acc = __builtin_amdgcn_mfma_f32_16x16x32_bf16(ah, bxl[ks], acc, 0, 0, 0);
                acc = __builtin_amdgcn_mfma_f32_16x16x32_bf16(al, bxh[ks], acc, 0, 0, 0);
            }
            accU[mt] = acc;
        }
        __syncthreads();
#pragma unroll
        for (int mt = 0; mt < 4; mt++) {
#pragma unroll
            for (int j = 0; j < 4; j++) {
                int eloc = mt * 16 + kg * 4 + j;
                float u = accU[mt][j];
                float z = kA * (u + 0.044715f * u * u * u);
                float ex = __expf(2.f * z);
                float gg = u - u * (1.f / (ex + 1.f));
                ushort hi = f2bf(gg);
                ghh[wave][p][eloc] = hi;
                ghl[wave][p][eloc] = f2bf(gg - bf2f(hi));
            }
        }
        __syncthreads();
#pragma unroll
        for (int mto = 0; mto < 4; mto++) {
#pragma unroll
            for (int ks2 = 0; ks2 < 2; ks2++) {
                size_t aoff = (size_t)(mto * 16 + p) * 256 + ec * 64 + ks2 * 32 + kg * 8;
                short8 ah = *(const short8*)(dnh + aoff);
                short8 al = *(const short8*)(dnl + aoff);
                short8 bgh = *(const short8*)&ghh[wave][p][ks2 * 32 + kg * 8];
                short8 bgl = *(const short8*)&ghl[wave][p][ks2 * 32 + kg * 8];
                Cout[mto] = __builtin_amdgcn_mfma_f32_16x16x32_bf16(ah, bgh, Cout[mto], 0, 0, 0);
                Cout[mto] = __builtin_amdgcn_mfma_f32_16x16x32_bf16(ah, bgl, Cout[mto], 0, 0, 0);
                Cout[mto] = __builtin_amdgcn_mfma_f32_16x16x32_bf16(al, bgh, Cout[mto], 0, 0, 0);
            }
        }
    }

#pragma unroll
    for (int mto = 0; mto < 4; mto++) {
#pragma unroll
        for (int j = 0; j < 4; j++) {
            int o = mto * 16 + kg * 4 + j;
            size_t idx = (size_t)tok * 1024 + o * 16 + p;
            x[idx] = x[idx] + Cout[mto][j];
        }
    }
}

// ---- per-layer mixed rotor sandwich matrix Tmix[16][16] --------------------
__global__ void tmix_kernel(const float* __restrict__ rotor_biv,
                            const float* __restrict__ mixw,
                            float* __restrict__ Tmix) {
    int lay = blockIdx.x;
    __shared__ float rot[NK][D16];
    __shared__ float w[NK];
    int t = threadIdx.x;
    if (t < NK) {
        const int BIV[6] = { 3, 5, 6, 9, 10, 12 };
        float r[D16];
#pragma unroll
        for (int j = 0; j < D16; j++) r[j] = 0.f;
        r[0] = 1.f;
        float nrm = 1.f;
        for (int i = 0; i < 6; i++) {
            float bv = rotor_biv[(lay * NK + t) * 6 + i];
            r[BIV[i]] = bv; nrm += bv * bv;
        }
        nrm = sqrtf(nrm);
        for (int j = 0; j < D16; j++) rot[t][j] = r[j] / nrm;
    }
    if (t == 0) {
        float mx = -INFINITY;
        for (int kk = 0; kk < NK; kk++) mx = fmaxf(mx, mixw[lay * NK + kk]);
        float s = 0.f, e[NK];
        for (int kk = 0; kk < NK; kk++) { e[kk] = expf(mixw[lay * NK + kk] - mx); s += e[kk]; }
        for (int kk = 0; kk < NK; kk++) w[kk] = e[kk] / s;
    }
    __syncthreads();
    int j = t >> 4, p = t & 15;
    float acc = 0.f;
    for (int kk = 0; kk < NK; kk++) {
        float tk = 0.f;
        for (int i = 0; i < D16; i++) {
            int n = i ^ j ^ p;
            float rn = rot[kk][n] * rev_sign(n);
            tk += rot[kk][i] * rn * gp_sign(i, j) * gp_sign(i ^ j, n);
        }
        acc += w[kk] * tk;
    }
    Tmix[lay * 256 + t] = acc;
}

// ---- final norm + blade gate + grade-0; emit bf16 hi/lo --------------------
__global__ void g0_kernel(const float* __restrict__ x,
                          const float* __restrict__ g,
                          const float* __restrict__ sel,
                          ushort* __restrict__ g0h,
                          ushort* __restrict__ g0l) {
    int bl = blockIdx.x;
    const float* xr = x + (size_t)bl * 1024;
    __shared__ float red[256];
    float s = 0.f;
    for (int i = threadIdx.x; i < 1024; i += 256) { float v = xr[i]; s += v * v; }
    red[threadIdx.x] = s; __syncthreads();
    for (int st = 128; st > 0; st >>= 1) {
        if (threadIdx.x < st) red[threadIdx.x] += red[threadIdx.x + st];
        __syncthreads();
    }
    float inv = 1.f / sqrtf(red[0] * (1.f / 1024.f) + 1e-6f);
    if (threadIdx.x < NC) {
        int c = threadIdx.x;
        float gate = 1.f / (1.f + expf(-sel[c * D16]));
        float val = xr[c * D16] * inv * g[c] * gate;
        ushort hi = f2bf(val);
        g0h[(size_t)bl * NC + c] = hi;
        g0l[(size_t)bl * NC + c] = f2bf(val - bf2f(hi));
    }
}

// ---- head_w split into bf16 hi/lo ------------------------------------------
__global__ void split_hw(const float* __restrict__ hw,
                         ushort* __restrict__ hwh,
                         ushort* __restrict__ hwl) {
    int idx = blockIdx.x * blockDim.x + threadIdx.x;
    if (idx >= VOCAB * NC) return;
    float f = hw[idx];
    ushort hi = f2bf(f);
    hwh[idx] = hi;
    hwl[idx] = f2bf(f - bf2f(hi));
}

// ---- head GEMM: 64 rows x 256 vocab cols per block; 1KB/wave stores --------
// grid (125, 32); block 256 = 4 waves; wave computes 16 rows x 256 cols
__global__ __launch_bounds__(256) void head_mfma_kernel(
        const ushort* __restrict__ g0h, const ushort* __restrict__ g0l,
        const ushort* __restrict__ hwh, const ushort* __restrict__ hwl,
        const float* __restrict__ hb, float* __restrict__ out) {
    int t = threadIdx.x;
    int wave = t >> 6, lane = t & 63;
    int lr = lane & 15, lk = lane >> 4;
    int rowbase = blockIdx.y * 64 + wave * 16;
    int vbase = blockIdx.x * 256;

    __shared__ float tile[64 * 264];

    short8 ah[2], al[2];
#pragma unroll
    for (int ks = 0; ks < 2; ks++) {
        size_t off = (size_t)(rowbase + lr) * NC + ks * 32 + lk * 8;
        ah[ks] = *(const short8*)(g0h + off);
        al[ks] = *(const short8*)(g0l + off);
    }
    f32x4 acc[16];
#pragma unroll
    for (int nt = 0; nt < 16; nt++) acc[nt] = (f32x4){0.f, 0.f, 0.f, 0.f};

#pragma unroll
    for (int ks = 0; ks < 2; ks++) {
#pragma unroll
        for (int nt = 0; nt < 16; nt++) {
            size_t boff = (size_t)(vbase + nt * 16 + lr) * NC + ks * 32 + lk * 8;
            short8 bh = *(const short8*)(hwh + boff);
            short8 bl = *(const short8*)(hwl + boff);
            acc[nt] = __builtin_amdgcn_mfma_f32_16x16x32_bf16(ah[ks], bh, acc[nt], 0, 0, 0);
            acc[nt] = __builtin_amdgcn_mfma_f32_16x16x32_bf16(ah[ks], bl, acc[nt], 0, 0, 0);
            acc[nt] = __builtin_amdgcn_mfma_f32_16x16x32_bf16(al[ks], bh, acc[nt], 0, 0, 0);
        }
    }

    // stage 64x256 tile: block-local row = wave*16 + lk*4 + r, col = nt*16+lr
#pragma unroll
    for (int nt = 0; nt < 16; nt++)
#pragma unroll
        for (int r = 0; r < 4; r++)
            tile[(wave * 16 + lk * 4 + r) * 264 + nt * 16 + lr] = acc[nt][r];
    __syncthreads();

    // write-out: each wave writes one full 1KB row segment per iter
    float4 bias4 = *(const float4*)(hb + vbase + lane * 4);
#pragma unroll
    for (int iter = 0; iter < 16; iter++) {
        int row = iter * 4 + wave;
        float4 vv = *(const float4*)&tile[row * 264 + lane * 4];
        f32x4 sv;
        sv[0] = vv.x + bias4.x; sv[1] = vv.y + bias4.y;
        sv[2] = vv.z + bias4.z; sv[3] = vv.w + bias4.w;
        __builtin_nontemporal_store(sv,
            (f32x4*)(out + (size_t)(blockIdx.y * 64 + row) * VOCAB + vbase + lane * 4));
    }
}

extern "C" void kernel_launch(void* const* d_in, const int* in_sizes, int n_in,
                              void* d_out, int out_size, void* d_ws, size_t ws_size,
                              hipStream_t stream) {
    (void)in_sizes; (void)n_in; (void)out_size; (void)ws_size;
    const int*   tok      = (const int*)  d_in[0];
    const float* embed    = (const float*)d_in[1];
    const float* ln1_g    = (const float*)d_in[2];
    const float* ln2_g    = (const float*)d_in[3];
    const float* wq       = (const float*)d_in[4];
    const float* wk       = (const float*)d_in[5];
    const float* wv       = (const float*)d_in[6];
    const float* wo       = (const float*)d_in[7];
    const float* ffn_up   = (const float*)d_in[8];
    const float* ffn_down = (const float*)d_in[9];
    const float* rotor    = (const float*)d_in[10];
    const float* mixw     = (const float*)d_in[11];
    const float* out_ln_g = (const float*)d_in[12];
    const float* sel      = (const float*)d_in[13];
    const float* head_w   = (const float*)d_in[14];
    const float* head_b   = (const float*)d_in[15];
    float* out = (float*)d_out;

    float* ws  = (float*)d_ws;
    float* x    = ws;                         // 2,097,152 f
    float* o    = x + 2097152;                // 2,097,152 f
    float* vbuf = o + 2097152;                // 2,097,152 f
    float* Tmx  = vbuf + 2097152;             // 512 f
    ushort* qh   = (ushort*)(Tmx + 512);      // 2,097,152 us each
    ushort* ql   = qh + 2097152;
    ushort* kh   = ql + 2097152;
    ushort* kl   = kh + 2097152;
    ushort* vth  = kl + 2097152;
    ushort* vtl  = vth + 2097152;
    ushort* g0h  = vtl + 2097152;             // 131,072
    ushort* g0l  = g0h + 131072;
    ushort* hwh  = g0l + 131072;              // 2,048,000
    ushort* hwl  = hwh + 2048000;
    ushort* wsp  = hwl + 2048000;             // 196,608

    embed_pe_kernel<<<(BATCH * SEQ * NC + 255) / 256, 256, 0, stream>>>(tok, embed, x);
    tmix_kernel<<<NLAY, 256, 0, stream>>>(rotor, mixw, Tmx);
    split_hw<<<(VOCAB * NC + 255) / 256, 256, 0, stream>>>(head_w, hwh, hwl);
    split_lw<<<384, 256, 0, stream>>>(wq, wk, wv, wo, ffn_up, ffn_down, wsp);

    for (int l = 0; l < NLAY; l++) {
        int lo = l * 4096;
        int le = l * 16384;
        qkv_mfma_kernel<<<512, 256, 0, stream>>>(
            x, ln1_g + l * NC,
            wsp + lo, wsp + 8192 + lo, wsp + 16384 + lo, wsp + 24576 + lo,
            wsp + 32768 + lo, wsp + 40960 + lo,
            qh, ql, kh, kl, vbuf);
        dim3 vg(16, 16);
        vtrans_kernel<<<vg, 256, 0, stream>>>(vbuf, vth, vtl);
        dim3 ag(16, 16);
        attn_mfma_kernel<<<ag, 256, 0, stream>>>(qh, ql, kh, kl, vth, vtl, o);
        proj_ffn_mfma_kernel<<<512, 256, 0, stream>>>(
            o, wsp + 49152 + lo, wsp + 57344 + lo,
            ln2_g + l * NC, Tmx + l * 256,
            wsp + 65536 + le, wsp + 98304 + le,
            wsp + 131072 + le, wsp + 163840 + le, x);
    }

    g0_kernel<<<BATCH * SEQ, 256, 0, stream>>>(x, out_ln_g, sel, g0h, g0l);
    dim3 hg(VOCAB / 256, (BATCH * SEQ) / 64);   // (125, 32)
    head_mfma_kernel<<<hg, 256, 0, stream>>>(g0h, g0l, hwh, hwl, head_b, out);
}